// Round 1
// baseline (1657.442 us; speedup 1.0000x reference)
//
#include <hip/hip_runtime.h>

// Problem constants (fixed by the reference)
constexpr int N_NODES = 100000;
constexpr int N_EDGES = 1600000;
constexpr int HDIM    = 128;
constexpr int N_CLUST = 25000;
constexpr int N_GRAPH = 64;
constexpr int NCLSN   = 10;

// ---------------------------------------------------------------------------
// CSR build: histogram of dst (node graph) and dst_p (cluster graph)
// ---------------------------------------------------------------------------
__global__ void hist_kernel(const int* __restrict__ ei, const int* __restrict__ cluster,
                            int* __restrict__ deg1, int* __restrict__ deg2){
  int e = blockIdx.x * blockDim.x + threadIdx.x;
  if (e >= N_EDGES) return;
  int dst = ei[N_EDGES + e];
  atomicAdd(&deg1[dst], 1);
  atomicAdd(&deg2[cluster[dst]], 1);
}

// single-block exclusive scan; also initializes the fill cursors
__global__ void scan_kernel(const int* __restrict__ cnt, int* __restrict__ rowptr,
                            int* __restrict__ cur, int n){
  __shared__ int part[1024];
  int t = threadIdx.x;
  int chunk = (n + 1023) >> 10;
  int lo = t * chunk; if (lo > n) lo = n;
  int hi = lo + chunk; if (hi > n) hi = n;
  int s = 0;
  for (int i = lo; i < hi; ++i) s += cnt[i];
  part[t] = s;
  __syncthreads();
  for (int off = 1; off < 1024; off <<= 1){
    int v = (t >= off) ? part[t - off] : 0;
    __syncthreads();
    part[t] += v;
    __syncthreads();
  }
  int run = (t == 0) ? 0 : part[t - 1];
  for (int i = lo; i < hi; ++i){ rowptr[i] = run; cur[i] = run; run += cnt[i]; }
  if (t == 1023) rowptr[n] = part[1023];
}

__global__ void dis_kernel(const int* __restrict__ cnt, float* __restrict__ dis, int n){
  int i = blockIdx.x * blockDim.x + threadIdx.x;
  if (i < n) dis[i] = rsqrtf((float)cnt[i] + 1.0f);  // deg = in-count + 1 (self loop)
}

// fill CSR edge lists; also stash dis[src] per edge so the gather loop has no
// dependent indirection for the weight
__global__ void fill_kernel(const int* __restrict__ ei, const int* __restrict__ cluster,
                            const float* __restrict__ dis1, const float* __restrict__ dis2,
                            int* __restrict__ cur1, int* __restrict__ esrc1, float* __restrict__ wsrc1,
                            int* __restrict__ cur2, int* __restrict__ esrcp, float* __restrict__ wsrcp){
  int e = blockIdx.x * blockDim.x + threadIdx.x;
  if (e >= N_EDGES) return;
  int src = ei[e];
  int dst = ei[N_EDGES + e];
  int p = atomicAdd(&cur1[dst], 1);
  esrc1[p] = src; wsrc1[p] = dis1[src];
  int sp = cluster[src], dp = cluster[dst];
  int q = atomicAdd(&cur2[dp], 1);
  esrcp[q] = sp; wsrcp[q] = dis2[sp];
}

// ---------------------------------------------------------------------------
// GEMM: C[M,128] = A[M,128] @ B[128,128]  (fp32, LDS-tiled, 4x4 register tile)
// block = 256 threads, tile = 64 rows x 64 cols, K=128
// ---------------------------------------------------------------------------
__launch_bounds__(256)
__global__ void gemm128(const float* __restrict__ A, const float* __restrict__ B,
                        float* __restrict__ Cmat, int M){
  __shared__ float As[128 * 64];  // As[k*64 + m] (transposed)
  __shared__ float Bs[128 * 64];  // Bs[k*64 + c]
  const int t   = threadIdx.x;
  const int bm  = blockIdx.x;
  const int bn  = blockIdx.y;         // 0 or 1 (64-col halves)
  const int row0 = bm * 64;

  // stage B tile (conflict-free stores; coalesced global reads)
  #pragma unroll
  for (int i = 0; i < 8; ++i){
    int idx4 = t + i * 256;           // float4 index: k*16 + c4
    int k  = idx4 >> 4;
    int c4 = idx4 & 15;
    float4 v = *(const float4*)&B[k * 128 + bn * 64 + c4 * 4];
    *(float4*)&Bs[k * 64 + c4 * 4] = v;
  }
  // stage A tile transposed (lanes -> consecutive m: conflict-free LDS stores)
  {
    int m  = t & 63;
    int kb = t >> 6;                  // 0..3
    int row = row0 + m; if (row >= M) row = M - 1;
    const float* Arow = A + (size_t)row * 128;
    #pragma unroll
    for (int i = 0; i < 8; ++i){
      int k4 = kb + i * 4;            // 0..31
      float4 v = *(const float4*)&Arow[k4 * 4];
      int k = k4 * 4;
      As[(k + 0) * 64 + m] = v.x;
      As[(k + 1) * 64 + m] = v.y;
      As[(k + 2) * 64 + m] = v.z;
      As[(k + 3) * 64 + m] = v.w;
    }
  }
  __syncthreads();

  const int tx = t & 15, ty = t >> 4;   // 16x16 threads, 4x4 micro-tile
  float acc[4][4] = {};
  #pragma unroll 4
  for (int k = 0; k < 128; ++k){
    float a[4], b[4];
    *(float4*)a = *(const float4*)&As[k * 64 + (ty << 2)];
    *(float4*)b = *(const float4*)&Bs[k * 64 + (tx << 2)];
    #pragma unroll
    for (int i = 0; i < 4; ++i)
      #pragma unroll
      for (int j = 0; j < 4; ++j)
        acc[i][j] = fmaf(a[i], b[j], acc[i][j]);
  }
  #pragma unroll
  for (int i = 0; i < 4; ++i){
    int row = row0 + (ty << 2) + i;
    if (row < M){
      float4 o = { acc[i][0], acc[i][1], acc[i][2], acc[i][3] };
      *(float4*)&Cmat[(size_t)row * 128 + bn * 64 + (tx << 2)] = o;
    }
  }
}

// ---------------------------------------------------------------------------
// GCN conv as CSR gather:  out[i] = relu( dis[i]*sum_e T[src_e]*dis[src_e]
//                                         + T[i]*dis[i]^2 + bias )
// one block (128 threads = feature dim) per destination row
// ---------------------------------------------------------------------------
__launch_bounds__(128)
__global__ void conv_gather(const float* __restrict__ T, const float* __restrict__ dis,
                            const int* __restrict__ rowptr, const int* __restrict__ esrc,
                            const float* __restrict__ wsrc, const float* __restrict__ bias,
                            float* __restrict__ Hout){
  int i = blockIdx.x;
  int f = threadIdx.x;
  int beg = rowptr[i], end = rowptr[i + 1];
  float acc = 0.f;
  for (int e = beg; e < end; ++e){
    int s   = esrc[e];
    float w = wsrc[e];
    acc = fmaf(T[(size_t)s * 128 + f], w, acc);
  }
  float di = dis[i];
  float v  = acc * di + T[(size_t)i * 128 + f] * di * di + bias[f];
  Hout[(size_t)i * 128 + f] = fmaxf(v, 0.f);
}

// ---------------------------------------------------------------------------
// batch (sorted) graph boundaries via binary search
// ---------------------------------------------------------------------------
__global__ void graph_bounds(const int* __restrict__ batch, int* __restrict__ gstart){
  int g = threadIdx.x;
  if (g > N_GRAPH) return;
  int lo = 0, hi = N_NODES;
  while (lo < hi){ int mid = (lo + hi) >> 1; if (batch[mid] < g) lo = mid + 1; else hi = mid; }
  gstart[g] = lo;
}

__device__ __forceinline__ void atomicMaxPosF(float* addr, float v){
  atomicMax((int*)addr, __float_as_int(v));  // valid for v >= 0, init 0
}

// pre-pool over sorted batch: run-length accumulate, flush on graph change
constexpr int PRE_CHUNK = 250;  // 400 blocks exactly cover N_NODES
__launch_bounds__(128)
__global__ void pre_pool(const float* __restrict__ h1, const int* __restrict__ batch,
                         float* __restrict__ psum, float* __restrict__ pmax){
  int f  = threadIdx.x;
  int i0 = blockIdx.x * PRE_CHUNK;
  int i1 = i0 + PRE_CHUNK; if (i1 > N_NODES) i1 = N_NODES;
  int g = batch[i0];
  float s = 0.f, m = 0.f;
  for (int i = i0; i < i1; ++i){
    int gb = batch[i];
    if (gb != g){
      atomicAdd(&psum[g * 128 + f], s);
      atomicMaxPosF(&pmax[g * 128 + f], m);
      g = gb; s = 0.f; m = 0.f;
    }
    float v = h1[(size_t)i * 128 + f];
    s += v; m = fmaxf(m, v);
  }
  atomicAdd(&psum[g * 128 + f], s);
  atomicMaxPosF(&pmax[g * 128 + f], m);
}

// cluster mean-pool accumulation + batch_p (segment_max) + cluster counts
__launch_bounds__(128)
__global__ void cluster_pool(const float* __restrict__ h1, const int* __restrict__ cluster,
                             const int* __restrict__ batch, float* __restrict__ hpsum,
                             float* __restrict__ cntc, int* __restrict__ batchp){
  int i = blockIdx.x;
  int f = threadIdx.x;
  int c = cluster[i];
  atomicAdd(&hpsum[(size_t)c * 128 + f], h1[(size_t)i * 128 + f]);
  if (f == 0){
    atomicAdd(&cntc[c], 1.0f);
    atomicMax(&batchp[c], batch[i]);
  }
}

__launch_bounds__(128)
__global__ void hp_finalize(float* __restrict__ hpsum, const float* __restrict__ cntc){
  int c = blockIdx.x, f = threadIdx.x;
  float inv = 1.0f / fmaxf(cntc[c], 1.0f);
  hpsum[(size_t)c * 128 + f] *= inv;
}

__global__ void cntp_kernel(const int* __restrict__ batchp, float* __restrict__ cntp){
  int c = blockIdx.x * blockDim.x + threadIdx.x;
  if (c < N_CLUST) atomicAdd(&cntp[batchp[c]], 1.0f);
}

__launch_bounds__(128)
__global__ void post_pool(const float* __restrict__ hp3, const int* __restrict__ batchp,
                          float* __restrict__ psum, float* __restrict__ pmax){
  int c = blockIdx.x, f = threadIdx.x;
  int g = batchp[c];
  float v = hp3[(size_t)c * 128 + f];
  atomicAdd(&psum[g * 128 + f], v);
  atomicMaxPosF(&pmax[g * 128 + f], v);
}

// ---------------------------------------------------------------------------
// head: z=[pre_mean|pre_max|post_mean|post_max] (512) -> lin1+relu -> lin2 ->
// log_softmax. one block per graph.
// ---------------------------------------------------------------------------
__launch_bounds__(128)
__global__ void head_kernel(const float* __restrict__ psum, const float* __restrict__ pmax,
                            const float* __restrict__ postsum, const float* __restrict__ postmax,
                            const int* __restrict__ gstart, const float* __restrict__ cntp,
                            const float* __restrict__ l1w, const float* __restrict__ l1b,
                            const float* __restrict__ l2w, const float* __restrict__ l2b,
                            float* __restrict__ out){
  int g = blockIdx.x, t = threadIdx.x;
  __shared__ float z[512];
  __shared__ float a[128];
  __shared__ float logits[16];
  __shared__ float lse_s;
  float cpre  = (float)max(gstart[g + 1] - gstart[g], 1);
  float cpost = fmaxf(cntp[g], 1.0f);
  z[t]       = psum[g * 128 + t] / cpre;
  z[128 + t] = pmax[g * 128 + t];
  z[256 + t] = postsum[g * 128 + t] / cpost;
  z[384 + t] = postmax[g * 128 + t];
  __syncthreads();
  float acc = l1b[t];
  #pragma unroll 8
  for (int k = 0; k < 512; ++k) acc = fmaf(z[k], l1w[k * 128 + t], acc);
  a[t] = fmaxf(acc, 0.f);
  __syncthreads();
  if (t < NCLSN){
    float s2 = l2b[t];
    for (int k = 0; k < 128; ++k) s2 = fmaf(a[k], l2w[k * NCLSN + t], s2);
    logits[t] = s2;
  }
  __syncthreads();
  if (t == 0){
    float m = logits[0];
    for (int c = 1; c < NCLSN; ++c) m = fmaxf(m, logits[c]);
    float s = 0.f;
    for (int c = 0; c < NCLSN; ++c) s += expf(logits[c] - m);
    lse_s = m + logf(s);
  }
  __syncthreads();
  if (t < NCLSN) out[g * NCLSN + t] = logits[t] - lse_s;
}

// ---------------------------------------------------------------------------
extern "C" void kernel_launch(void* const* d_in, const int* in_sizes, int n_in,
                              void* d_out, int out_size, void* d_ws, size_t ws_size,
                              hipStream_t stream){
  const float* x       = (const float*)d_in[0];
  const int*   ei      = (const int*)  d_in[1];
  const int*   batch   = (const int*)  d_in[2];
  const int*   cluster = (const int*)  d_in[3];
  const float* W1      = (const float*)d_in[6];
  const float* b1      = (const float*)d_in[7];
  const float* W2      = (const float*)d_in[8];
  const float* b2      = (const float*)d_in[9];
  const float* W3      = (const float*)d_in[10];
  const float* b3      = (const float*)d_in[11];
  const float* l1w     = (const float*)d_in[12];
  const float* l1b     = (const float*)d_in[13];
  const float* l2w     = (const float*)d_in[14];
  const float* l2b     = (const float*)d_in[15];
  float* out = (float*)d_out;

  // ---- workspace layout (bump allocator, 256B aligned) ----
  char* base = (char*)d_ws;
  size_t off = 0;
  auto alloc = [&](size_t bytes) -> char* {
    char* p = base + off;
    off += (bytes + 255) & ~size_t(255);
    return p;
  };
  // zero zone (single memset covers all accumulators)
  char*  zbase   = base + off;
  float* hpsum   = (float*)alloc((size_t)N_CLUST * 128 * 4);
  int*   deg1    = (int*)  alloc((size_t)N_NODES * 4);
  int*   deg2    = (int*)  alloc((size_t)N_CLUST * 4);
  float* cntc    = (float*)alloc((size_t)N_CLUST * 4);
  int*   batchp  = (int*)  alloc((size_t)N_CLUST * 4);
  float* cntp    = (float*)alloc((size_t)N_GRAPH * 4);
  float* pre_s   = (float*)alloc((size_t)N_GRAPH * 128 * 4);
  float* pre_m   = (float*)alloc((size_t)N_GRAPH * 128 * 4);
  float* post_s  = (float*)alloc((size_t)N_GRAPH * 128 * 4);
  float* post_m  = (float*)alloc((size_t)N_GRAPH * 128 * 4);
  size_t zsize = off;
  // non-zeroed buffers
  float* t1      = (float*)alloc((size_t)N_NODES * 128 * 4);
  float* h1      = (float*)alloc((size_t)N_NODES * 128 * 4);
  int*   rowptr1 = (int*)  alloc((size_t)(N_NODES + 1) * 4);
  int*   cur1    = (int*)  alloc((size_t)N_NODES * 4);
  int*   esrc1   = (int*)  alloc((size_t)N_EDGES * 4);
  float* wsrc1   = (float*)alloc((size_t)N_EDGES * 4);
  float* dis1    = (float*)alloc((size_t)N_NODES * 4);
  int*   rowptr2 = (int*)  alloc((size_t)(N_CLUST + 1) * 4);
  int*   cur2    = (int*)  alloc((size_t)N_CLUST * 4);
  int*   esrcp   = (int*)  alloc((size_t)N_EDGES * 4);
  float* wsrcp   = (float*)alloc((size_t)N_EDGES * 4);
  float* dis2    = (float*)alloc((size_t)N_CLUST * 4);
  int*   gstart  = (int*)  alloc((size_t)(N_GRAPH + 1) * 4);
  // aliases into the dead t1 region (t1 last read by conv_gather #1)
  float* t2  = t1;
  float* hp2 = t1 + (size_t)N_CLUST * 128;
  float* t3  = t1 + (size_t)2 * N_CLUST * 128;
  float* hp3 = t1 + (size_t)3 * N_CLUST * 128;

  (void)in_sizes; (void)n_in; (void)out_size; (void)ws_size;

  hipMemsetAsync(zbase, 0, zsize, stream);

  // CSR + degrees
  hist_kernel<<<(N_EDGES + 255) / 256, 256, 0, stream>>>(ei, cluster, deg1, deg2);
  scan_kernel<<<1, 1024, 0, stream>>>(deg1, rowptr1, cur1, N_NODES);
  scan_kernel<<<1, 1024, 0, stream>>>(deg2, rowptr2, cur2, N_CLUST);
  dis_kernel<<<(N_NODES + 255) / 256, 256, 0, stream>>>(deg1, dis1, N_NODES);
  dis_kernel<<<(N_CLUST + 255) / 256, 256, 0, stream>>>(deg2, dis2, N_CLUST);
  fill_kernel<<<(N_EDGES + 255) / 256, 256, 0, stream>>>(ei, cluster, dis1, dis2,
                                                         cur1, esrc1, wsrc1,
                                                         cur2, esrcp, wsrcp);
  // conv1
  gemm128<<<dim3((N_NODES + 63) / 64, 2), 256, 0, stream>>>(x, W1, t1, N_NODES);
  conv_gather<<<N_NODES, 128, 0, stream>>>(t1, dis1, rowptr1, esrc1, wsrc1, b1, h1);
  // pre pools
  graph_bounds<<<1, 128, 0, stream>>>(batch, gstart);
  pre_pool<<<(N_NODES + PRE_CHUNK - 1) / PRE_CHUNK, 128, 0, stream>>>(h1, batch, pre_s, pre_m);
  // cluster pooling
  cluster_pool<<<N_NODES, 128, 0, stream>>>(h1, cluster, batch, hpsum, cntc, batchp);
  hp_finalize<<<N_CLUST, 128, 0, stream>>>(hpsum, cntc);
  cntp_kernel<<<(N_CLUST + 255) / 256, 256, 0, stream>>>(batchp, cntp);
  // conv2
  gemm128<<<dim3((N_CLUST + 63) / 64, 2), 256, 0, stream>>>(hpsum, W2, t2, N_CLUST);
  conv_gather<<<N_CLUST, 128, 0, stream>>>(t2, dis2, rowptr2, esrcp, wsrcp, b2, hp2);
  // conv3
  gemm128<<<dim3((N_CLUST + 63) / 64, 2), 256, 0, stream>>>(hp2, W3, t3, N_CLUST);
  conv_gather<<<N_CLUST, 128, 0, stream>>>(t3, dis2, rowptr2, esrcp, wsrcp, b3, hp3);
  // post pools
  post_pool<<<N_CLUST, 128, 0, stream>>>(hp3, batchp, post_s, post_m);
  // head
  head_kernel<<<N_GRAPH, 128, 0, stream>>>(pre_s, pre_m, post_s, post_m, gstart, cntp,
                                           l1w, l1b, l2w, l2b, out);
}

// Round 2
// 1645.502 us; speedup vs baseline: 1.0073x; 1.0073x over previous
//
#include <hip/hip_runtime.h>

constexpr int N_NODES = 100000;
constexpr int N_EDGES = 1600000;
constexpr int N_CLUST = 25000;
constexpr int N_GRAPH = 64;
constexpr int NCLSN   = 10;

// ---------------------------------------------------------------------------
// in-degree histogram of dst (node graph only; cluster degrees derived later)
// ---------------------------------------------------------------------------
__global__ void hist_kernel(const int* __restrict__ ei, int* __restrict__ deg1){
  int e = blockIdx.x * blockDim.x + threadIdx.x;
  if (e < N_EDGES) atomicAdd(&deg1[ei[N_EDGES + e]], 1);
}

// per-node: cluster membership count + cluster in-degree (sum of member deg1)
__global__ void node_prep(const int* __restrict__ cluster, const int* __restrict__ deg1,
                          int* __restrict__ cntn, int* __restrict__ deg2){
  int v = blockIdx.x * blockDim.x + threadIdx.x;
  if (v < N_NODES){
    int c = cluster[v];
    atomicAdd(&cntn[c], 1);
    atomicAdd(&deg2[c], deg1[v]);
  }
}

// single-block exclusive scan (+ optional fused dis = rsqrt(cnt+1))
__device__ void scan_one(const int* __restrict__ cnt, int* __restrict__ rowptr,
                         int* __restrict__ cur, float* __restrict__ dis, int n){
  __shared__ int part[1024];
  int t = threadIdx.x;
  int chunk = (n + 1023) >> 10;
  int lo = min(t * chunk, n), hi = min(lo + chunk, n);
  int s = 0;
  for (int i = lo; i < hi; ++i){
    int c = cnt[i];
    s += c;
    if (dis) dis[i] = rsqrtf((float)c + 1.0f);
  }
  part[t] = s;
  __syncthreads();
  for (int off = 1; off < 1024; off <<= 1){
    int v = (t >= off) ? part[t - off] : 0;
    __syncthreads();
    part[t] += v;
    __syncthreads();
  }
  int run = (t == 0) ? 0 : part[t - 1];
  for (int i = lo; i < hi; ++i){ rowptr[i] = run; cur[i] = run; run += cnt[i]; }
  if (t == 1023) rowptr[n] = part[1023];
}

__global__ void scan2_kernel(const int* __restrict__ deg1, int* __restrict__ rowptr1,
                             int* __restrict__ cur1, float* __restrict__ dis1,
                             const int* __restrict__ cntn, int* __restrict__ rowptrn,
                             int* __restrict__ curn){
  if (blockIdx.x == 0) scan_one(deg1, rowptr1, cur1, dis1, N_NODES);
  else                 scan_one(cntn, rowptrn, curn, nullptr, N_CLUST);
}

__global__ void dis2_kernel(const int* __restrict__ deg2, float* __restrict__ dis2){
  int c = blockIdx.x * blockDim.x + threadIdx.x;
  if (c < N_CLUST) dis2[c] = rsqrtf((float)deg2[c] + 1.0f);
}

// CSR edge fill: ONE scattered 4B store per edge
__global__ void fill_e(const int* __restrict__ ei, int* __restrict__ cur1,
                       int* __restrict__ esrc1){
  int e = blockIdx.x * blockDim.x + threadIdx.x;
  if (e >= N_EDGES) return;
  int src = ei[e], dst = ei[N_EDGES + e];
  esrc1[atomicAdd(&cur1[dst], 1)] = src;
}

// node->cluster CSR fill
__global__ void fill_n(const int* __restrict__ cluster, int* __restrict__ curn,
                       int* __restrict__ nidx){
  int v = blockIdx.x * blockDim.x + threadIdx.x;
  if (v >= N_NODES) return;
  nidx[atomicAdd(&curn[cluster[v]], 1)] = v;
}

// pooled source cluster per (CSR-ordered) edge — fully coalesced build
__global__ void psrc_kernel(const int* __restrict__ esrc1, const int* __restrict__ cluster,
                            int* __restrict__ psrc){
  int e = blockIdx.x * blockDim.x + threadIdx.x;
  if (e < N_EDGES) psrc[e] = cluster[esrc1[e]];
}

// ---------------------------------------------------------------------------
// GEMM: C[M,128] = (A[M,128] @ B[128,128]) * scale[row]
// ---------------------------------------------------------------------------
__launch_bounds__(256)
__global__ void gemm128(const float* __restrict__ A, const float* __restrict__ B,
                        const float* __restrict__ scale, float* __restrict__ Cmat, int M){
  __shared__ float As[128 * 64];  // As[k*64 + m] (transposed)
  __shared__ float Bs[128 * 64];  // Bs[k*64 + c]
  const int t = threadIdx.x;
  const int bm = blockIdx.x, bn = blockIdx.y;
  const int row0 = bm * 64;

  #pragma unroll
  for (int i = 0; i < 8; ++i){
    int idx4 = t + i * 256;
    int k = idx4 >> 4, c4 = idx4 & 15;
    float4 v = *(const float4*)&B[k * 128 + bn * 64 + c4 * 4];
    *(float4*)&Bs[k * 64 + c4 * 4] = v;
  }
  {
    int m = t & 63, kb = t >> 6;
    int row = row0 + m; if (row >= M) row = M - 1;
    const float* Arow = A + (size_t)row * 128;
    #pragma unroll
    for (int i = 0; i < 8; ++i){
      int k4 = kb + i * 4;
      float4 v = *(const float4*)&Arow[k4 * 4];
      int k = k4 * 4;
      As[(k + 0) * 64 + m] = v.x;
      As[(k + 1) * 64 + m] = v.y;
      As[(k + 2) * 64 + m] = v.z;
      As[(k + 3) * 64 + m] = v.w;
    }
  }
  __syncthreads();

  const int tx = t & 15, ty = t >> 4;
  float acc[4][4] = {};
  #pragma unroll 4
  for (int k = 0; k < 128; ++k){
    float a[4], b[4];
    *(float4*)a = *(const float4*)&As[k * 64 + (ty << 2)];
    *(float4*)b = *(const float4*)&Bs[k * 64 + (tx << 2)];
    #pragma unroll
    for (int i = 0; i < 4; ++i)
      #pragma unroll
      for (int j = 0; j < 4; ++j)
        acc[i][j] = fmaf(a[i], b[j], acc[i][j]);
  }
  #pragma unroll
  for (int i = 0; i < 4; ++i){
    int row = row0 + (ty << 2) + i;
    if (row < M){
      float sc = scale[row];
      float4 o = { acc[i][0] * sc, acc[i][1] * sc, acc[i][2] * sc, acc[i][3] * sc };
      *(float4*)&Cmat[(size_t)row * 128 + bn * 64 + (tx << 2)] = o;
    }
  }
}

// ---------------------------------------------------------------------------
// conv over node graph: out[i] = relu( dis[i]*(sum_e Ts[src_e] + Ts[i]) + b )
// one wave per dst row, float2 per lane, 2-edge ILP
// ---------------------------------------------------------------------------
__launch_bounds__(256)
__global__ void conv_node(const float* __restrict__ Ts, const float* __restrict__ dis,
                          const int* __restrict__ rowptr, const int* __restrict__ esrc,
                          const float* __restrict__ bias, float* __restrict__ Hout){
  int w = blockIdx.x * 4 + (threadIdx.x >> 6);
  int l = threadIdx.x & 63;
  int beg = rowptr[w], end = rowptr[w + 1];
  float2 a0 = {0.f, 0.f}, a1 = {0.f, 0.f};
  int e = beg;
  for (; e + 1 < end; e += 2){
    int s0 = esrc[e], s1 = esrc[e + 1];
    float2 v0 = *(const float2*)&Ts[(size_t)s0 * 128 + l * 2];
    float2 v1 = *(const float2*)&Ts[(size_t)s1 * 128 + l * 2];
    a0.x += v0.x; a0.y += v0.y;
    a1.x += v1.x; a1.y += v1.y;
  }
  if (e < end){
    float2 v0 = *(const float2*)&Ts[(size_t)esrc[e] * 128 + l * 2];
    a0.x += v0.x; a0.y += v0.y;
  }
  float d = dis[w];
  float2 self = *(const float2*)&Ts[(size_t)w * 128 + l * 2];
  float2 bb   = *(const float2*)&bias[l * 2];
  float2 r;
  r.x = fmaxf(fmaf(d, a0.x + a1.x + self.x, bb.x), 0.f);
  r.y = fmaxf(fmaf(d, a0.y + a1.y + self.y, bb.y), 0.f);
  *(float2*)&Hout[(size_t)w * 128 + l * 2] = r;
}

// conv over pooled graph via two-level CSR (cluster -> member nodes -> in-edges)
__launch_bounds__(256)
__global__ void conv_pooled(const float* __restrict__ Ts, const float* __restrict__ dis,
                            const int* __restrict__ rowptrn, const int* __restrict__ nidx,
                            const int* __restrict__ rowptr1, const int* __restrict__ psrc,
                            const float* __restrict__ bias, float* __restrict__ Hout){
  int c = blockIdx.x * 4 + (threadIdx.x >> 6);
  int l = threadIdx.x & 63;
  int mb = rowptrn[c], me = rowptrn[c + 1];
  float2 a0 = {0.f, 0.f}, a1 = {0.f, 0.f};
  for (int m = mb; m < me; ++m){
    int v = nidx[m];
    int e = rowptr1[v], ee = rowptr1[v + 1];
    for (; e + 1 < ee; e += 2){
      int s0 = psrc[e], s1 = psrc[e + 1];
      float2 v0 = *(const float2*)&Ts[(size_t)s0 * 128 + l * 2];
      float2 v1 = *(const float2*)&Ts[(size_t)s1 * 128 + l * 2];
      a0.x += v0.x; a0.y += v0.y;
      a1.x += v1.x; a1.y += v1.y;
    }
    if (e < ee){
      float2 v0 = *(const float2*)&Ts[(size_t)psrc[e] * 128 + l * 2];
      a0.x += v0.x; a0.y += v0.y;
    }
  }
  float d = dis[c];
  float2 self = *(const float2*)&Ts[(size_t)c * 128 + l * 2];
  float2 bb   = *(const float2*)&bias[l * 2];
  float2 r;
  r.x = fmaxf(fmaf(d, a0.x + a1.x + self.x, bb.x), 0.f);
  r.y = fmaxf(fmaf(d, a0.y + a1.y + self.y, bb.y), 0.f);
  *(float2*)&Hout[(size_t)c * 128 + l * 2] = r;
}

// cluster mean pool + batch_p + cntp, atomic-free gather (one wave per cluster)
__launch_bounds__(256)
__global__ void cluster_gather(const float* __restrict__ h1, const int* __restrict__ rowptrn,
                               const int* __restrict__ nidx, const int* __restrict__ batch,
                               float* __restrict__ hp, int* __restrict__ batchp,
                               float* __restrict__ cntp){
  int c = blockIdx.x * 4 + (threadIdx.x >> 6);
  int l = threadIdx.x & 63;
  int mb = rowptrn[c], me = rowptrn[c + 1];
  float2 a = {0.f, 0.f};
  int bmax = 0;
  for (int m = mb; m < me; ++m){
    int v = nidx[m];
    float2 x = *(const float2*)&h1[(size_t)v * 128 + l * 2];
    a.x += x.x; a.y += x.y;
    bmax = max(bmax, batch[v]);
  }
  float inv = 1.0f / (float)max(me - mb, 1);
  float2 o = { a.x * inv, a.y * inv };
  *(float2*)&hp[(size_t)c * 128 + l * 2] = o;
  if (l == 0){
    batchp[c] = bmax;                 // empty cluster -> 0 (matches max(.,0))
    atomicAdd(&cntp[bmax], 1.0f);     // every cluster counts (empty -> graph 0)
  }
}

// ---------------------------------------------------------------------------
__global__ void graph_bounds(const int* __restrict__ batch, int* __restrict__ gstart){
  int g = threadIdx.x;
  if (g > N_GRAPH) return;
  int lo = 0, hi = N_NODES;
  while (lo < hi){ int mid = (lo + hi) >> 1; if (batch[mid] < g) lo = mid + 1; else hi = mid; }
  gstart[g] = lo;
}

__device__ __forceinline__ void atomicMaxPosF(float* addr, float v){
  atomicMax((int*)addr, __float_as_int(v));  // valid for v >= 0, init 0
}

constexpr int PRE_CHUNK = 250;
__launch_bounds__(128)
__global__ void pre_pool(const float* __restrict__ h1, const int* __restrict__ batch,
                         float* __restrict__ psum, float* __restrict__ pmax){
  int f  = threadIdx.x;
  int i0 = blockIdx.x * PRE_CHUNK;
  int i1 = min(i0 + PRE_CHUNK, N_NODES);
  int g = batch[i0];
  float s = 0.f, m = 0.f;
  for (int i = i0; i < i1; ++i){
    int gb = batch[i];
    if (gb != g){
      atomicAdd(&psum[g * 128 + f], s);
      atomicMaxPosF(&pmax[g * 128 + f], m);
      g = gb; s = 0.f; m = 0.f;
    }
    float v = h1[(size_t)i * 128 + f];
    s += v; m = fmaxf(m, v);
  }
  atomicAdd(&psum[g * 128 + f], s);
  atomicMaxPosF(&pmax[g * 128 + f], m);
}

__launch_bounds__(128)
__global__ void post_pool(const float* __restrict__ hp3, const int* __restrict__ batchp,
                          float* __restrict__ psum, float* __restrict__ pmax){
  int c = blockIdx.x, f = threadIdx.x;
  int g = batchp[c];
  float v = hp3[(size_t)c * 128 + f];
  atomicAdd(&psum[g * 128 + f], v);
  atomicMaxPosF(&pmax[g * 128 + f], v);
}

__launch_bounds__(128)
__global__ void head_kernel(const float* __restrict__ psum, const float* __restrict__ pmax,
                            const float* __restrict__ postsum, const float* __restrict__ postmax,
                            const int* __restrict__ gstart, const float* __restrict__ cntp,
                            const float* __restrict__ l1w, const float* __restrict__ l1b,
                            const float* __restrict__ l2w, const float* __restrict__ l2b,
                            float* __restrict__ out){
  int g = blockIdx.x, t = threadIdx.x;
  __shared__ float z[512];
  __shared__ float a[128];
  __shared__ float logits[16];
  __shared__ float lse_s;
  float cpre  = (float)max(gstart[g + 1] - gstart[g], 1);
  float cpost = fmaxf(cntp[g], 1.0f);
  z[t]       = psum[g * 128 + t] / cpre;
  z[128 + t] = pmax[g * 128 + t];
  z[256 + t] = postsum[g * 128 + t] / cpost;
  z[384 + t] = postmax[g * 128 + t];
  __syncthreads();
  float acc = l1b[t];
  #pragma unroll 8
  for (int k = 0; k < 512; ++k) acc = fmaf(z[k], l1w[k * 128 + t], acc);
  a[t] = fmaxf(acc, 0.f);
  __syncthreads();
  if (t < NCLSN){
    float s2 = l2b[t];
    for (int k = 0; k < 128; ++k) s2 = fmaf(a[k], l2w[k * NCLSN + t], s2);
    logits[t] = s2;
  }
  __syncthreads();
  if (t == 0){
    float m = logits[0];
    for (int c = 1; c < NCLSN; ++c) m = fmaxf(m, logits[c]);
    float s = 0.f;
    for (int c = 0; c < NCLSN; ++c) s += expf(logits[c] - m);
    lse_s = m + logf(s);
  }
  __syncthreads();
  if (t < NCLSN) out[g * NCLSN + t] = logits[t] - lse_s;
}

// ---------------------------------------------------------------------------
extern "C" void kernel_launch(void* const* d_in, const int* in_sizes, int n_in,
                              void* d_out, int out_size, void* d_ws, size_t ws_size,
                              hipStream_t stream){
  const float* x       = (const float*)d_in[0];
  const int*   ei      = (const int*)  d_in[1];
  const int*   batch   = (const int*)  d_in[2];
  const int*   cluster = (const int*)  d_in[3];
  const float* W1      = (const float*)d_in[6];
  const float* b1      = (const float*)d_in[7];
  const float* W2      = (const float*)d_in[8];
  const float* b2      = (const float*)d_in[9];
  const float* W3      = (const float*)d_in[10];
  const float* b3      = (const float*)d_in[11];
  const float* l1w     = (const float*)d_in[12];
  const float* l1b     = (const float*)d_in[13];
  const float* l2w     = (const float*)d_in[14];
  const float* l2b     = (const float*)d_in[15];
  float* out = (float*)d_out;

  char* base = (char*)d_ws;
  size_t off = 0;
  auto alloc = [&](size_t bytes) -> char* {
    char* p = base + off;
    off += (bytes + 255) & ~size_t(255);
    return p;
  };
  // ---- zero zone (one memset) ----
  char*  zbase  = base + off;
  int*   deg1   = (int*)  alloc((size_t)N_NODES * 4);
  int*   deg2   = (int*)  alloc((size_t)N_CLUST * 4);
  int*   cntn   = (int*)  alloc((size_t)N_CLUST * 4);
  float* cntp   = (float*)alloc((size_t)N_GRAPH * 4);
  float* pre_s  = (float*)alloc((size_t)N_GRAPH * 128 * 4);
  float* pre_m  = (float*)alloc((size_t)N_GRAPH * 128 * 4);
  float* post_s = (float*)alloc((size_t)N_GRAPH * 128 * 4);
  float* post_m = (float*)alloc((size_t)N_GRAPH * 128 * 4);
  size_t zsize = off;
  // ---- plain buffers ----
  float* Ts1     = (float*)alloc((size_t)N_NODES * 128 * 4);  // later aliased
  float* h1      = (float*)alloc((size_t)N_NODES * 128 * 4);
  int*   esrc1   = (int*)  alloc((size_t)N_EDGES * 4);
  int*   psrc    = (int*)  alloc((size_t)N_EDGES * 4);
  int*   rowptr1 = (int*)  alloc((size_t)(N_NODES + 1) * 4);
  int*   cur1    = (int*)  alloc((size_t)N_NODES * 4);
  int*   rowptrn = (int*)  alloc((size_t)(N_CLUST + 1) * 4);
  int*   curn    = (int*)  alloc((size_t)N_CLUST * 4);
  int*   nidx    = (int*)  alloc((size_t)N_NODES * 4);
  float* dis1    = (float*)alloc((size_t)N_NODES * 4);
  float* dis2    = (float*)alloc((size_t)N_CLUST * 4);
  int*   batchp  = (int*)  alloc((size_t)N_CLUST * 4);
  int*   gstart  = (int*)  alloc((size_t)(N_GRAPH + 1) * 4);
  // aliases into Ts1 (dead after conv_node): 4 x C*128 = exactly N_NODES*128
  float* hp  = Ts1;
  float* Ts2 = Ts1 + (size_t)N_CLUST * 128;
  float* hp2 = Ts1 + (size_t)2 * N_CLUST * 128;
  float* hp3 = Ts1 + (size_t)3 * N_CLUST * 128;
  float* Ts3 = Ts2;  // Ts2 dead after conv2

  (void)in_sizes; (void)n_in; (void)out_size; (void)ws_size;

  hipMemsetAsync(zbase, 0, zsize, stream);

  // graph prep
  hist_kernel<<<(N_EDGES + 255) / 256, 256, 0, stream>>>(ei, deg1);
  node_prep  <<<(N_NODES + 255) / 256, 256, 0, stream>>>(cluster, deg1, cntn, deg2);
  scan2_kernel<<<2, 1024, 0, stream>>>(deg1, rowptr1, cur1, dis1, cntn, rowptrn, curn);
  dis2_kernel<<<(N_CLUST + 255) / 256, 256, 0, stream>>>(deg2, dis2);
  fill_e<<<(N_EDGES + 255) / 256, 256, 0, stream>>>(ei, cur1, esrc1);
  fill_n<<<(N_NODES + 255) / 256, 256, 0, stream>>>(cluster, curn, nidx);
  psrc_kernel<<<(N_EDGES + 255) / 256, 256, 0, stream>>>(esrc1, cluster, psrc);

  // conv1
  gemm128<<<dim3((N_NODES + 63) / 64, 2), 256, 0, stream>>>(x, W1, dis1, Ts1, N_NODES);
  conv_node<<<N_NODES / 4, 256, 0, stream>>>(Ts1, dis1, rowptr1, esrc1, b1, h1);

  // pre pools
  graph_bounds<<<1, 128, 0, stream>>>(batch, gstart);
  pre_pool<<<(N_NODES + PRE_CHUNK - 1) / PRE_CHUNK, 128, 0, stream>>>(h1, batch, pre_s, pre_m);

  // cluster mean pool (atomic-free)
  cluster_gather<<<N_CLUST / 4, 256, 0, stream>>>(h1, rowptrn, nidx, batch, hp, batchp, cntp);

  // conv2
  gemm128<<<dim3((N_CLUST + 63) / 64, 2), 256, 0, stream>>>(hp, W2, dis2, Ts2, N_CLUST);
  conv_pooled<<<N_CLUST / 4, 256, 0, stream>>>(Ts2, dis2, rowptrn, nidx, rowptr1, psrc, b2, hp2);

  // conv3
  gemm128<<<dim3((N_CLUST + 63) / 64, 2), 256, 0, stream>>>(hp2, W3, dis2, Ts3, N_CLUST);
  conv_pooled<<<N_CLUST / 4, 256, 0, stream>>>(Ts3, dis2, rowptrn, nidx, rowptr1, psrc, b3, hp3);

  // post pools + head
  post_pool<<<N_CLUST, 128, 0, stream>>>(hp3, batchp, post_s, post_m);
  head_kernel<<<N_GRAPH, 128, 0, stream>>>(pre_s, pre_m, post_s, post_m, gstart, cntp,
                                           l1w, l1b, l2w, l2b, out);
}

// Round 3
// 1333.331 us; speedup vs baseline: 1.2431x; 1.2341x over previous
//
#include <hip/hip_runtime.h>

constexpr int N_NODES = 100000;
constexpr int N_EDGES = 1600000;
constexpr int N_CLUST = 25000;
constexpr int N_GRAPH = 64;
constexpr int NCLSN   = 10;

// scan partitioning: 1024 elements per block, two concatenated segments
constexpr int SCAN_BPB = 1024;
constexpr int NB1 = (N_NODES + SCAN_BPB - 1) / SCAN_BPB;  // 98
constexpr int NB2 = (N_CLUST + SCAN_BPB - 1) / SCAN_BPB;  // 25
constexpr int NBT = NB1 + NB2;                            // 123

// ---------------------------------------------------------------------------
// in-degree histogram of dst (node graph only; cluster degrees derived later)
// ---------------------------------------------------------------------------
__global__ void hist_kernel(const int* __restrict__ ei, int* __restrict__ deg1){
  int e = blockIdx.x * blockDim.x + threadIdx.x;
  if (e < N_EDGES) atomicAdd(&deg1[ei[N_EDGES + e]], 1);
}

// per-node: cluster membership count + cluster in-degree (sum of member deg1)
__global__ void node_prep(const int* __restrict__ cluster, const int* __restrict__ deg1,
                          int* __restrict__ cntn, int* __restrict__ deg2){
  int v = blockIdx.x * blockDim.x + threadIdx.x;
  if (v < N_NODES){
    int c = cluster[v];
    atomicAdd(&cntn[c], 1);
    atomicAdd(&deg2[c], deg1[v]);
  }
}

// ---------------------------------------------------------------------------
// device-wide segmented exclusive scan (deg1 -> rowptr1, cntn -> rowptrn)
// ---------------------------------------------------------------------------
__launch_bounds__(256)
__global__ void block_sums(const int* __restrict__ deg1, const int* __restrict__ cntn,
                           int* __restrict__ bsum){
  int b = blockIdx.x;
  const int* src; int n, base;
  if (b < NB1){ src = deg1; n = N_NODES; base = b * SCAN_BPB; }
  else        { src = cntn; n = N_CLUST; base = (b - NB1) * SCAN_BPB; }
  int t = threadIdx.x;
  int i0 = base + t * 4;
  int s = 0;
  if (i0 + 3 < n){ int4 v = *(const int4*)&src[i0]; s = v.x + v.y + v.z + v.w; }
  else { for (int j = 0; j < 4; ++j){ int i = i0 + j; if (i < n) s += src[i]; } }
  __shared__ int sh[256];
  sh[t] = s; __syncthreads();
  for (int off = 128; off > 0; off >>= 1){
    if (t < off) sh[t] += sh[t + off];
    __syncthreads();
  }
  if (t == 0) bsum[b] = sh[0];
}

__launch_bounds__(128)
__global__ void scan_bsums(const int* __restrict__ bsum, int* __restrict__ boff,
                           int* __restrict__ rowptr1, int* __restrict__ rowptrn){
  __shared__ int s[128];
  int t = threadIdx.x;
  int v = (t < NBT) ? bsum[t] : 0;
  s[t] = v; __syncthreads();
  int seg = (t < NB1) ? 0 : 1;
  for (int off = 1; off < 128; off <<= 1){
    int add = 0;
    if (t >= off){
      int u = t - off;
      if (((u < NB1) ? 0 : 1) == seg) add = s[u];
    }
    __syncthreads();
    s[t] += add;
    __syncthreads();
  }
  if (t < NBT) boff[t] = s[t] - v;       // exclusive block offset
  if (t == NB1 - 1) rowptr1[N_NODES] = s[t];
  if (t == NBT - 1) rowptrn[N_CLUST] = s[t];
}

__launch_bounds__(256)
__global__ void scan_final(const int* __restrict__ deg1, const int* __restrict__ cntn,
                           const int* __restrict__ boff,
                           int* __restrict__ rowptr1, int* __restrict__ cur1,
                           float* __restrict__ dis1,
                           int* __restrict__ rowptrn, int* __restrict__ curn){
  int b = blockIdx.x;
  const int* src; int n, base; int* rp; int* cur; float* dis;
  if (b < NB1){ src = deg1; n = N_NODES; base = b * SCAN_BPB; rp = rowptr1; cur = cur1; dis = dis1; }
  else { src = cntn; n = N_CLUST; base = (b - NB1) * SCAN_BPB; rp = rowptrn; cur = curn; dis = nullptr; }
  int t = threadIdx.x;
  int i0 = base + t * 4;
  int v[4]; int s = 0;
  #pragma unroll
  for (int j = 0; j < 4; ++j){ int i = i0 + j; v[j] = (i < n) ? src[i] : 0; s += v[j]; }
  __shared__ int sh[256];
  sh[t] = s; __syncthreads();
  for (int off = 1; off < 256; off <<= 1){
    int add = (t >= off) ? sh[t - off] : 0;
    __syncthreads();
    sh[t] += add;
    __syncthreads();
  }
  int run = sh[t] - s + boff[b];         // exclusive prefix for element i0
  #pragma unroll
  for (int j = 0; j < 4; ++j){
    int i = i0 + j;
    if (i < n){
      rp[i] = run; cur[i] = run;
      if (dis) dis[i] = rsqrtf((float)v[j] + 1.0f);
      run += v[j];
    }
  }
}

__global__ void dis2_kernel(const int* __restrict__ deg2, float* __restrict__ dis2){
  int c = blockIdx.x * blockDim.x + threadIdx.x;
  if (c < N_CLUST) dis2[c] = rsqrtf((float)deg2[c] + 1.0f);
}

// CSR edge fill: ONE scattered 4B store per edge
__global__ void fill_e(const int* __restrict__ ei, int* __restrict__ cur1,
                       int* __restrict__ esrc1){
  int e = blockIdx.x * blockDim.x + threadIdx.x;
  if (e >= N_EDGES) return;
  int src = ei[e], dst = ei[N_EDGES + e];
  esrc1[atomicAdd(&cur1[dst], 1)] = src;
}

// node->cluster CSR fill
__global__ void fill_n(const int* __restrict__ cluster, int* __restrict__ curn,
                       int* __restrict__ nidx){
  int v = blockIdx.x * blockDim.x + threadIdx.x;
  if (v >= N_NODES) return;
  nidx[atomicAdd(&curn[cluster[v]], 1)] = v;
}

// pooled source cluster per (CSR-ordered) edge — fully coalesced build
__global__ void psrc_kernel(const int* __restrict__ esrc1, const int* __restrict__ cluster,
                            int* __restrict__ psrc){
  int e = blockIdx.x * blockDim.x + threadIdx.x;
  if (e < N_EDGES) psrc[e] = cluster[esrc1[e]];
}

// ---------------------------------------------------------------------------
// GEMM: C[M,128] = (A[M,128] @ B[128,128]) * scale[row]
// ---------------------------------------------------------------------------
__launch_bounds__(256)
__global__ void gemm128(const float* __restrict__ A, const float* __restrict__ B,
                        const float* __restrict__ scale, float* __restrict__ Cmat, int M){
  __shared__ float As[128 * 64];  // As[k*64 + m] (transposed)
  __shared__ float Bs[128 * 64];  // Bs[k*64 + c]
  const int t = threadIdx.x;
  const int bm = blockIdx.x, bn = blockIdx.y;
  const int row0 = bm * 64;

  #pragma unroll
  for (int i = 0; i < 8; ++i){
    int idx4 = t + i * 256;
    int k = idx4 >> 4, c4 = idx4 & 15;
    float4 v = *(const float4*)&B[k * 128 + bn * 64 + c4 * 4];
    *(float4*)&Bs[k * 64 + c4 * 4] = v;
  }
  {
    int m = t & 63, kb = t >> 6;
    int row = row0 + m; if (row >= M) row = M - 1;
    const float* Arow = A + (size_t)row * 128;
    #pragma unroll
    for (int i = 0; i < 8; ++i){
      int k4 = kb + i * 4;
      float4 v = *(const float4*)&Arow[k4 * 4];
      int k = k4 * 4;
      As[(k + 0) * 64 + m] = v.x;
      As[(k + 1) * 64 + m] = v.y;
      As[(k + 2) * 64 + m] = v.z;
      As[(k + 3) * 64 + m] = v.w;
    }
  }
  __syncthreads();

  const int tx = t & 15, ty = t >> 4;
  float acc[4][4] = {};
  #pragma unroll 4
  for (int k = 0; k < 128; ++k){
    float a[4], b[4];
    *(float4*)a = *(const float4*)&As[k * 64 + (ty << 2)];
    *(float4*)b = *(const float4*)&Bs[k * 64 + (tx << 2)];
    #pragma unroll
    for (int i = 0; i < 4; ++i)
      #pragma unroll
      for (int j = 0; j < 4; ++j)
        acc[i][j] = fmaf(a[i], b[j], acc[i][j]);
  }
  #pragma unroll
  for (int i = 0; i < 4; ++i){
    int row = row0 + (ty << 2) + i;
    if (row < M){
      float sc = scale[row];
      float4 o = { acc[i][0] * sc, acc[i][1] * sc, acc[i][2] * sc, acc[i][3] * sc };
      *(float4*)&Cmat[(size_t)row * 128 + bn * 64 + (tx << 2)] = o;
    }
  }
}

// ---------------------------------------------------------------------------
// conv over node graph: out[i] = relu( dis[i]*(sum_e Ts[src_e] + Ts[i]) + b )
// ---------------------------------------------------------------------------
__launch_bounds__(256)
__global__ void conv_node(const float* __restrict__ Ts, const float* __restrict__ dis,
                          const int* __restrict__ rowptr, const int* __restrict__ esrc,
                          const float* __restrict__ bias, float* __restrict__ Hout){
  int w = blockIdx.x * 4 + (threadIdx.x >> 6);
  int l = threadIdx.x & 63;
  int beg = rowptr[w], end = rowptr[w + 1];
  float2 a0 = {0.f, 0.f}, a1 = {0.f, 0.f};
  int e = beg;
  for (; e + 1 < end; e += 2){
    int s0 = esrc[e], s1 = esrc[e + 1];
    float2 v0 = *(const float2*)&Ts[(size_t)s0 * 128 + l * 2];
    float2 v1 = *(const float2*)&Ts[(size_t)s1 * 128 + l * 2];
    a0.x += v0.x; a0.y += v0.y;
    a1.x += v1.x; a1.y += v1.y;
  }
  if (e < end){
    float2 v0 = *(const float2*)&Ts[(size_t)esrc[e] * 128 + l * 2];
    a0.x += v0.x; a0.y += v0.y;
  }
  float d = dis[w];
  float2 self = *(const float2*)&Ts[(size_t)w * 128 + l * 2];
  float2 bb   = *(const float2*)&bias[l * 2];
  float2 r;
  r.x = fmaxf(fmaf(d, a0.x + a1.x + self.x, bb.x), 0.f);
  r.y = fmaxf(fmaf(d, a0.y + a1.y + self.y, bb.y), 0.f);
  *(float2*)&Hout[(size_t)w * 128 + l * 2] = r;
}

// conv over pooled graph via two-level CSR (cluster -> member nodes -> in-edges)
__launch_bounds__(256)
__global__ void conv_pooled(const float* __restrict__ Ts, const float* __restrict__ dis,
                            const int* __restrict__ rowptrn, const int* __restrict__ nidx,
                            const int* __restrict__ rowptr1, const int* __restrict__ psrc,
                            const float* __restrict__ bias, float* __restrict__ Hout){
  int c = blockIdx.x * 4 + (threadIdx.x >> 6);
  int l = threadIdx.x & 63;
  int mb = rowptrn[c], me = rowptrn[c + 1];
  float2 a0 = {0.f, 0.f}, a1 = {0.f, 0.f};
  for (int m = mb; m < me; ++m){
    int v = nidx[m];
    int e = rowptr1[v], ee = rowptr1[v + 1];
    for (; e + 1 < ee; e += 2){
      int s0 = psrc[e], s1 = psrc[e + 1];
      float2 v0 = *(const float2*)&Ts[(size_t)s0 * 128 + l * 2];
      float2 v1 = *(const float2*)&Ts[(size_t)s1 * 128 + l * 2];
      a0.x += v0.x; a0.y += v0.y;
      a1.x += v1.x; a1.y += v1.y;
    }
    if (e < ee){
      float2 v0 = *(const float2*)&Ts[(size_t)psrc[e] * 128 + l * 2];
      a0.x += v0.x; a0.y += v0.y;
    }
  }
  float d = dis[c];
  float2 self = *(const float2*)&Ts[(size_t)c * 128 + l * 2];
  float2 bb   = *(const float2*)&bias[l * 2];
  float2 r;
  r.x = fmaxf(fmaf(d, a0.x + a1.x + self.x, bb.x), 0.f);
  r.y = fmaxf(fmaf(d, a0.y + a1.y + self.y, bb.y), 0.f);
  *(float2*)&Hout[(size_t)c * 128 + l * 2] = r;
}

// cluster mean pool + batch_p + cntp, atomic-free gather (one wave per cluster)
__launch_bounds__(256)
__global__ void cluster_gather(const float* __restrict__ h1, const int* __restrict__ rowptrn,
                               const int* __restrict__ nidx, const int* __restrict__ batch,
                               float* __restrict__ hp, int* __restrict__ batchp,
                               float* __restrict__ cntp){
  int c = blockIdx.x * 4 + (threadIdx.x >> 6);
  int l = threadIdx.x & 63;
  int mb = rowptrn[c], me = rowptrn[c + 1];
  float2 a = {0.f, 0.f};
  int bmax = 0;
  for (int m = mb; m < me; ++m){
    int v = nidx[m];
    float2 x = *(const float2*)&h1[(size_t)v * 128 + l * 2];
    a.x += x.x; a.y += x.y;
    bmax = max(bmax, batch[v]);
  }
  float inv = 1.0f / (float)max(me - mb, 1);
  float2 o = { a.x * inv, a.y * inv };
  *(float2*)&hp[(size_t)c * 128 + l * 2] = o;
  if (l == 0){
    batchp[c] = bmax;
    atomicAdd(&cntp[bmax], 1.0f);
  }
}

// ---------------------------------------------------------------------------
__global__ void graph_bounds(const int* __restrict__ batch, int* __restrict__ gstart){
  int g = threadIdx.x;
  if (g > N_GRAPH) return;
  int lo = 0, hi = N_NODES;
  while (lo < hi){ int mid = (lo + hi) >> 1; if (batch[mid] < g) lo = mid + 1; else hi = mid; }
  gstart[g] = lo;
}

__device__ __forceinline__ void atomicMaxPosF(float* addr, float v){
  atomicMax((int*)addr, __float_as_int(v));
}

constexpr int PRE_CHUNK = 250;
__launch_bounds__(128)
__global__ void pre_pool(const float* __restrict__ h1, const int* __restrict__ batch,
                         float* __restrict__ psum, float* __restrict__ pmax){
  int f  = threadIdx.x;
  int i0 = blockIdx.x * PRE_CHUNK;
  int i1 = min(i0 + PRE_CHUNK, N_NODES);
  int g = batch[i0];
  float s = 0.f, m = 0.f;
  for (int i = i0; i < i1; ++i){
    int gb = batch[i];
    if (gb != g){
      atomicAdd(&psum[g * 128 + f], s);
      atomicMaxPosF(&pmax[g * 128 + f], m);
      g = gb; s = 0.f; m = 0.f;
    }
    float v = h1[(size_t)i * 128 + f];
    s += v; m = fmaxf(m, v);
  }
  atomicAdd(&psum[g * 128 + f], s);
  atomicMaxPosF(&pmax[g * 128 + f], m);
}

__launch_bounds__(128)
__global__ void post_pool(const float* __restrict__ hp3, const int* __restrict__ batchp,
                          float* __restrict__ psum, float* __restrict__ pmax){
  int c = blockIdx.x, f = threadIdx.x;
  int g = batchp[c];
  float v = hp3[(size_t)c * 128 + f];
  atomicAdd(&psum[g * 128 + f], v);
  atomicMaxPosF(&pmax[g * 128 + f], v);
}

__launch_bounds__(128)
__global__ void head_kernel(const float* __restrict__ psum, const float* __restrict__ pmax,
                            const float* __restrict__ postsum, const float* __restrict__ postmax,
                            const int* __restrict__ gstart, const float* __restrict__ cntp,
                            const float* __restrict__ l1w, const float* __restrict__ l1b,
                            const float* __restrict__ l2w, const float* __restrict__ l2b,
                            float* __restrict__ out){
  int g = blockIdx.x, t = threadIdx.x;
  __shared__ float z[512];
  __shared__ float a[128];
  __shared__ float logits[16];
  __shared__ float lse_s;
  float cpre  = (float)max(gstart[g + 1] - gstart[g], 1);
  float cpost = fmaxf(cntp[g], 1.0f);
  z[t]       = psum[g * 128 + t] / cpre;
  z[128 + t] = pmax[g * 128 + t];
  z[256 + t] = postsum[g * 128 + t] / cpost;
  z[384 + t] = postmax[g * 128 + t];
  __syncthreads();
  float acc = l1b[t];
  #pragma unroll 8
  for (int k = 0; k < 512; ++k) acc = fmaf(z[k], l1w[k * 128 + t], acc);
  a[t] = fmaxf(acc, 0.f);
  __syncthreads();
  if (t < NCLSN){
    float s2 = l2b[t];
    for (int k = 0; k < 128; ++k) s2 = fmaf(a[k], l2w[k * NCLSN + t], s2);
    logits[t] = s2;
  }
  __syncthreads();
  if (t == 0){
    float m = logits[0];
    for (int c = 1; c < NCLSN; ++c) m = fmaxf(m, logits[c]);
    float s = 0.f;
    for (int c = 0; c < NCLSN; ++c) s += expf(logits[c] - m);
    lse_s = m + logf(s);
  }
  __syncthreads();
  if (t < NCLSN) out[g * NCLSN + t] = logits[t] - lse_s;
}

// ---------------------------------------------------------------------------
extern "C" void kernel_launch(void* const* d_in, const int* in_sizes, int n_in,
                              void* d_out, int out_size, void* d_ws, size_t ws_size,
                              hipStream_t stream){
  const float* x       = (const float*)d_in[0];
  const int*   ei      = (const int*)  d_in[1];
  const int*   batch   = (const int*)  d_in[2];
  const int*   cluster = (const int*)  d_in[3];
  const float* W1      = (const float*)d_in[6];
  const float* b1      = (const float*)d_in[7];
  const float* W2      = (const float*)d_in[8];
  const float* b2      = (const float*)d_in[9];
  const float* W3      = (const float*)d_in[10];
  const float* b3      = (const float*)d_in[11];
  const float* l1w     = (const float*)d_in[12];
  const float* l1b     = (const float*)d_in[13];
  const float* l2w     = (const float*)d_in[14];
  const float* l2b     = (const float*)d_in[15];
  float* out = (float*)d_out;

  char* base = (char*)d_ws;
  size_t off = 0;
  auto alloc = [&](size_t bytes) -> char* {
    char* p = base + off;
    off += (bytes + 255) & ~size_t(255);
    return p;
  };
  // ---- zero zone (one memset) ----
  char*  zbase  = base + off;
  int*   deg1   = (int*)  alloc((size_t)N_NODES * 4);
  int*   deg2   = (int*)  alloc((size_t)N_CLUST * 4);
  int*   cntn   = (int*)  alloc((size_t)N_CLUST * 4);
  float* cntp   = (float*)alloc((size_t)N_GRAPH * 4);
  float* pre_s  = (float*)alloc((size_t)N_GRAPH * 128 * 4);
  float* pre_m  = (float*)alloc((size_t)N_GRAPH * 128 * 4);
  float* post_s = (float*)alloc((size_t)N_GRAPH * 128 * 4);
  float* post_m = (float*)alloc((size_t)N_GRAPH * 128 * 4);
  size_t zsize = off;
  // ---- plain buffers ----
  float* Ts1     = (float*)alloc((size_t)N_NODES * 128 * 4);  // later aliased
  float* h1      = (float*)alloc((size_t)N_NODES * 128 * 4);
  int*   esrc1   = (int*)  alloc((size_t)N_EDGES * 4);
  int*   psrc    = (int*)  alloc((size_t)N_EDGES * 4);
  int*   rowptr1 = (int*)  alloc((size_t)(N_NODES + 1) * 4);
  int*   cur1    = (int*)  alloc((size_t)N_NODES * 4);
  int*   rowptrn = (int*)  alloc((size_t)(N_CLUST + 1) * 4);
  int*   curn    = (int*)  alloc((size_t)N_CLUST * 4);
  int*   nidx    = (int*)  alloc((size_t)N_NODES * 4);
  float* dis1    = (float*)alloc((size_t)N_NODES * 4);
  float* dis2    = (float*)alloc((size_t)N_CLUST * 4);
  int*   batchp  = (int*)  alloc((size_t)N_CLUST * 4);
  int*   gstart  = (int*)  alloc((size_t)(N_GRAPH + 1) * 4);
  int*   bsum    = (int*)  alloc((size_t)NBT * 4);
  int*   boff    = (int*)  alloc((size_t)NBT * 4);
  // aliases into Ts1 (dead after conv_node)
  float* hp  = Ts1;
  float* Ts2 = Ts1 + (size_t)N_CLUST * 128;
  float* hp2 = Ts1 + (size_t)2 * N_CLUST * 128;
  float* hp3 = Ts1 + (size_t)3 * N_CLUST * 128;
  float* Ts3 = Ts2;

  (void)in_sizes; (void)n_in; (void)out_size; (void)ws_size;

  hipMemsetAsync(zbase, 0, zsize, stream);

  // graph prep
  hist_kernel<<<(N_EDGES + 255) / 256, 256, 0, stream>>>(ei, deg1);
  node_prep  <<<(N_NODES + 255) / 256, 256, 0, stream>>>(cluster, deg1, cntn, deg2);
  block_sums <<<NBT, 256, 0, stream>>>(deg1, cntn, bsum);
  scan_bsums <<<1, 128, 0, stream>>>(bsum, boff, rowptr1, rowptrn);
  scan_final <<<NBT, 256, 0, stream>>>(deg1, cntn, boff, rowptr1, cur1, dis1, rowptrn, curn);
  dis2_kernel<<<(N_CLUST + 255) / 256, 256, 0, stream>>>(deg2, dis2);
  fill_e<<<(N_EDGES + 255) / 256, 256, 0, stream>>>(ei, cur1, esrc1);
  fill_n<<<(N_NODES + 255) / 256, 256, 0, stream>>>(cluster, curn, nidx);
  psrc_kernel<<<(N_EDGES + 255) / 256, 256, 0, stream>>>(esrc1, cluster, psrc);

  // conv1
  gemm128<<<dim3((N_NODES + 63) / 64, 2), 256, 0, stream>>>(x, W1, dis1, Ts1, N_NODES);
  conv_node<<<N_NODES / 4, 256, 0, stream>>>(Ts1, dis1, rowptr1, esrc1, b1, h1);

  // pre pools
  graph_bounds<<<1, 128, 0, stream>>>(batch, gstart);
  pre_pool<<<(N_NODES + PRE_CHUNK - 1) / PRE_CHUNK, 128, 0, stream>>>(h1, batch, pre_s, pre_m);

  // cluster mean pool (atomic-free)
  cluster_gather<<<N_CLUST / 4, 256, 0, stream>>>(h1, rowptrn, nidx, batch, hp, batchp, cntp);

  // conv2
  gemm128<<<dim3((N_CLUST + 63) / 64, 2), 256, 0, stream>>>(hp, W2, dis2, Ts2, N_CLUST);
  conv_pooled<<<N_CLUST / 4, 256, 0, stream>>>(Ts2, dis2, rowptrn, nidx, rowptr1, psrc, b2, hp2);

  // conv3
  gemm128<<<dim3((N_CLUST + 63) / 64, 2), 256, 0, stream>>>(hp2, W3, dis2, Ts3, N_CLUST);
  conv_pooled<<<N_CLUST / 4, 256, 0, stream>>>(Ts3, dis2, rowptrn, nidx, rowptr1, psrc, b3, hp3);

  // post pools + head
  post_pool<<<N_CLUST, 128, 0, stream>>>(hp3, batchp, post_s, post_m);
  head_kernel<<<N_GRAPH, 128, 0, stream>>>(pre_s, pre_m, post_s, post_m, gstart, cntp,
                                           l1w, l1b, l2w, l2b, out);
}

// Round 4
// 1076.430 us; speedup vs baseline: 1.5398x; 1.2387x over previous
//
#include <hip/hip_runtime.h>

constexpr int N_NODES = 100000;
constexpr int N_EDGES = 1600000;
constexpr int N_CLUST = 25000;
constexpr int N_GRAPH = 64;
constexpr int NCLSN   = 10;

// scan partitioning: 1024 elements per block, three concatenated segments
constexpr int SCAN_BPB = 1024;
constexpr int NB1 = (N_NODES + SCAN_BPB - 1) / SCAN_BPB;  // 98
constexpr int NB2 = (N_CLUST + SCAN_BPB - 1) / SCAN_BPB;  // 25
constexpr int NB3 = (N_CLUST + SCAN_BPB - 1) / SCAN_BPB;  // 25
constexpr int NBT = NB1 + NB2 + NB3;                      // 148

// ---------------------------------------------------------------------------
// histograms: node in-degree + cluster in-degree (cluster table is L2-resident)
// ---------------------------------------------------------------------------
__global__ void hist_kernel(const int* __restrict__ ei, const int* __restrict__ cluster,
                            int* __restrict__ deg1, int* __restrict__ deg2){
  int e = blockIdx.x * blockDim.x + threadIdx.x;
  if (e >= N_EDGES) return;
  int dst = ei[N_EDGES + e];
  atomicAdd(&deg1[dst], 1);
  atomicAdd(&deg2[cluster[dst]], 1);
}

// cluster membership counts
__global__ void cntn_kernel(const int* __restrict__ cluster, int* __restrict__ cntn){
  int v = blockIdx.x * blockDim.x + threadIdx.x;
  if (v < N_NODES) atomicAdd(&cntn[cluster[v]], 1);
}

// ---------------------------------------------------------------------------
// device-wide 3-segment exclusive scan:
//   deg1 -> rowptr1/cur1 (+dis1), cntn -> rowptrn/curn, deg2 -> rowptr2/cur2 (+dis2)
// ---------------------------------------------------------------------------
__device__ __forceinline__ void seg_select(int b, const int* deg1, const int* cntn,
                                           const int* deg2, const int*& src, int& n, int& base){
  if (b < NB1){ src = deg1; n = N_NODES; base = b * SCAN_BPB; }
  else if (b < NB1 + NB2){ src = cntn; n = N_CLUST; base = (b - NB1) * SCAN_BPB; }
  else { src = deg2; n = N_CLUST; base = (b - NB1 - NB2) * SCAN_BPB; }
}

__launch_bounds__(256)
__global__ void block_sums(const int* __restrict__ deg1, const int* __restrict__ cntn,
                           const int* __restrict__ deg2, int* __restrict__ bsum){
  int b = blockIdx.x;
  const int* src; int n, base;
  seg_select(b, deg1, cntn, deg2, src, n, base);
  int t = threadIdx.x;
  int i0 = base + t * 4;
  int s = 0;
  if (i0 + 3 < n){ int4 v = *(const int4*)&src[i0]; s = v.x + v.y + v.z + v.w; }
  else { for (int j = 0; j < 4; ++j){ int i = i0 + j; if (i < n) s += src[i]; } }
  __shared__ int sh[256];
  sh[t] = s; __syncthreads();
  for (int off = 128; off > 0; off >>= 1){
    if (t < off) sh[t] += sh[t + off];
    __syncthreads();
  }
  if (t == 0) bsum[b] = sh[0];
}

__launch_bounds__(256)
__global__ void scan_bsums(const int* __restrict__ bsum, int* __restrict__ boff,
                           int* __restrict__ rowptr1, int* __restrict__ rowptrn,
                           int* __restrict__ rowptr2){
  __shared__ int s[256];
  int t = threadIdx.x;
  int v = (t < NBT) ? bsum[t] : 0;
  s[t] = v; __syncthreads();
  int seg = (t < NB1) ? 0 : (t < NB1 + NB2 ? 1 : 2);
  for (int off = 1; off < 256; off <<= 1){
    int add = 0;
    if (t >= off){
      int u = t - off;
      int useg = (u < NB1) ? 0 : (u < NB1 + NB2 ? 1 : 2);
      if (useg == seg) add = s[u];
    }
    __syncthreads();
    s[t] += add;
    __syncthreads();
  }
  if (t < NBT) boff[t] = s[t] - v;
  if (t == NB1 - 1)       rowptr1[N_NODES] = s[t];
  if (t == NB1 + NB2 - 1) rowptrn[N_CLUST] = s[t];
  if (t == NBT - 1)       rowptr2[N_CLUST] = s[t];
}

__launch_bounds__(256)
__global__ void scan_final(const int* __restrict__ deg1, const int* __restrict__ cntn,
                           const int* __restrict__ deg2, const int* __restrict__ boff,
                           int* __restrict__ rowptr1, int* __restrict__ cur1, float* __restrict__ dis1,
                           int* __restrict__ rowptrn, int* __restrict__ curn,
                           int* __restrict__ rowptr2, int* __restrict__ cur2, float* __restrict__ dis2){
  int b = blockIdx.x;
  const int* src; int n, base;
  seg_select(b, deg1, cntn, deg2, src, n, base);
  int* rp; int* cur; float* dis;
  if (b < NB1){ rp = rowptr1; cur = cur1; dis = dis1; }
  else if (b < NB1 + NB2){ rp = rowptrn; cur = curn; dis = nullptr; }
  else { rp = rowptr2; cur = cur2; dis = dis2; }
  int t = threadIdx.x;
  int i0 = base + t * 4;
  int v[4]; int s = 0;
  #pragma unroll
  for (int j = 0; j < 4; ++j){ int i = i0 + j; v[j] = (i < n) ? src[i] : 0; s += v[j]; }
  __shared__ int sh[256];
  sh[t] = s; __syncthreads();
  for (int off = 1; off < 256; off <<= 1){
    int add = (t >= off) ? sh[t - off] : 0;
    __syncthreads();
    sh[t] += add;
    __syncthreads();
  }
  int run = sh[t] - s + boff[b];
  #pragma unroll
  for (int j = 0; j < 4; ++j){
    int i = i0 + j;
    if (i < n){
      rp[i] = run; cur[i] = run;
      if (dis) dis[i] = rsqrtf((float)v[j] + 1.0f);
      run += v[j];
    }
  }
}

// ---------------------------------------------------------------------------
// CSR fills (one scattered 4B store each)
// ---------------------------------------------------------------------------
__global__ void fill_e(const int* __restrict__ ei, int* __restrict__ cur1,
                       int* __restrict__ esrc1){
  int e = blockIdx.x * blockDim.x + threadIdx.x;
  if (e >= N_EDGES) return;
  esrc1[atomicAdd(&cur1[ei[N_EDGES + e]], 1)] = ei[e];
}

__global__ void fill_n(const int* __restrict__ cluster, int* __restrict__ curn,
                       int* __restrict__ nidx){
  int v = blockIdx.x * blockDim.x + threadIdx.x;
  if (v >= N_NODES) return;
  nidx[atomicAdd(&curn[cluster[v]], 1)] = v;
}

// cluster-level CSR: source-cluster id per edge, grouped by dst cluster
__global__ void fill_p(const int* __restrict__ ei, const int* __restrict__ cluster,
                       int* __restrict__ cur2, int* __restrict__ psrcC){
  int e = blockIdx.x * blockDim.x + threadIdx.x;
  if (e >= N_EDGES) return;
  int sc = cluster[ei[e]];
  int dc = cluster[ei[N_EDGES + e]];
  psrcC[atomicAdd(&cur2[dc], 1)] = sc;
}

// ---------------------------------------------------------------------------
// GEMM: C[M,128] = (A[M,128] @ B[128,128]) * scale[row]
// ---------------------------------------------------------------------------
__launch_bounds__(256)
__global__ void gemm128(const float* __restrict__ A, const float* __restrict__ B,
                        const float* __restrict__ scale, float* __restrict__ Cmat, int M){
  __shared__ float As[128 * 64];
  __shared__ float Bs[128 * 64];
  const int t = threadIdx.x;
  const int bm = blockIdx.x, bn = blockIdx.y;
  const int row0 = bm * 64;

  #pragma unroll
  for (int i = 0; i < 8; ++i){
    int idx4 = t + i * 256;
    int k = idx4 >> 4, c4 = idx4 & 15;
    float4 v = *(const float4*)&B[k * 128 + bn * 64 + c4 * 4];
    *(float4*)&Bs[k * 64 + c4 * 4] = v;
  }
  {
    int m = t & 63, kb = t >> 6;
    int row = row0 + m; if (row >= M) row = M - 1;
    const float* Arow = A + (size_t)row * 128;
    #pragma unroll
    for (int i = 0; i < 8; ++i){
      int k4 = kb + i * 4;
      float4 v = *(const float4*)&Arow[k4 * 4];
      int k = k4 * 4;
      As[(k + 0) * 64 + m] = v.x;
      As[(k + 1) * 64 + m] = v.y;
      As[(k + 2) * 64 + m] = v.z;
      As[(k + 3) * 64 + m] = v.w;
    }
  }
  __syncthreads();

  const int tx = t & 15, ty = t >> 4;
  float acc[4][4] = {};
  #pragma unroll 4
  for (int k = 0; k < 128; ++k){
    float a[4], b[4];
    *(float4*)a = *(const float4*)&As[k * 64 + (ty << 2)];
    *(float4*)b = *(const float4*)&Bs[k * 64 + (tx << 2)];
    #pragma unroll
    for (int i = 0; i < 4; ++i)
      #pragma unroll
      for (int j = 0; j < 4; ++j)
        acc[i][j] = fmaf(a[i], b[j], acc[i][j]);
  }
  #pragma unroll
  for (int i = 0; i < 4; ++i){
    int row = row0 + (ty << 2) + i;
    if (row < M){
      float sc = scale[row];
      float4 o = { acc[i][0] * sc, acc[i][1] * sc, acc[i][2] * sc, acc[i][3] * sc };
      *(float4*)&Cmat[(size_t)row * 128 + bn * 64 + (tx << 2)] = o;
    }
  }
}

// ---------------------------------------------------------------------------
// CSR conv, chunked + ILP: out[i] = relu( dis[i]*(sum_e Ts[src_e] + Ts[i]) + b )
// one wave per row; 64 edge ids loaded coalesced per chunk, rows fetched 4-wide
// ---------------------------------------------------------------------------
__launch_bounds__(256)
__global__ void conv_csr(const float* __restrict__ Ts, const float* __restrict__ dis,
                         const int* __restrict__ rowptr, const int* __restrict__ esrc,
                         const float* __restrict__ bias, float* __restrict__ Hout){
  int w = blockIdx.x * 4 + (threadIdx.x >> 6);
  int l = threadIdx.x & 63;
  int beg = rowptr[w], end = rowptr[w + 1];
  float2 a0{0.f,0.f}, a1{0.f,0.f}, a2{0.f,0.f}, a3{0.f,0.f};
  for (int base = beg; base < end; base += 64){
    int n = min(64, end - base);
    int eid = esrc[base + min(l, n - 1)];
    int j = 0;
    for (; j + 4 <= n; j += 4){
      int s0 = __shfl(eid, j);
      int s1 = __shfl(eid, j + 1);
      int s2 = __shfl(eid, j + 2);
      int s3 = __shfl(eid, j + 3);
      float2 v0 = *(const float2*)&Ts[(size_t)s0 * 128 + l * 2];
      float2 v1 = *(const float2*)&Ts[(size_t)s1 * 128 + l * 2];
      float2 v2 = *(const float2*)&Ts[(size_t)s2 * 128 + l * 2];
      float2 v3 = *(const float2*)&Ts[(size_t)s3 * 128 + l * 2];
      a0.x += v0.x; a0.y += v0.y;
      a1.x += v1.x; a1.y += v1.y;
      a2.x += v2.x; a2.y += v2.y;
      a3.x += v3.x; a3.y += v3.y;
    }
    for (; j < n; ++j){
      int s = __shfl(eid, j);
      float2 v = *(const float2*)&Ts[(size_t)s * 128 + l * 2];
      a0.x += v.x; a0.y += v.y;
    }
  }
  float d = dis[w];
  float2 self = *(const float2*)&Ts[(size_t)w * 128 + l * 2];
  float2 bb   = *(const float2*)&bias[l * 2];
  float2 r;
  r.x = fmaxf(fmaf(d, a0.x + a1.x + a2.x + a3.x + self.x, bb.x), 0.f);
  r.y = fmaxf(fmaf(d, a0.y + a1.y + a2.y + a3.y + self.y, bb.y), 0.f);
  *(float2*)&Hout[(size_t)w * 128 + l * 2] = r;
}

// cluster mean pool + batch_p, chunked + ILP, no per-member batch loads
__launch_bounds__(256)
__global__ void cluster_gather(const float* __restrict__ h1, const int* __restrict__ rowptrn,
                               const int* __restrict__ nidx, const int* __restrict__ batch,
                               float* __restrict__ hp, int* __restrict__ batchp){
  int c = blockIdx.x * 4 + (threadIdx.x >> 6);
  int l = threadIdx.x & 63;
  int mb = rowptrn[c], me = rowptrn[c + 1];
  float2 a0{0.f,0.f}, a1{0.f,0.f}, a2{0.f,0.f}, a3{0.f,0.f};
  int vmax = -1;
  for (int base = mb; base < me; base += 64){
    int n = min(64, me - base);
    int vid = nidx[base + min(l, n - 1)];
    if (l < n) vmax = max(vmax, vid);
    int j = 0;
    for (; j + 4 <= n; j += 4){
      int s0 = __shfl(vid, j);
      int s1 = __shfl(vid, j + 1);
      int s2 = __shfl(vid, j + 2);
      int s3 = __shfl(vid, j + 3);
      float2 v0 = *(const float2*)&h1[(size_t)s0 * 128 + l * 2];
      float2 v1 = *(const float2*)&h1[(size_t)s1 * 128 + l * 2];
      float2 v2 = *(const float2*)&h1[(size_t)s2 * 128 + l * 2];
      float2 v3 = *(const float2*)&h1[(size_t)s3 * 128 + l * 2];
      a0.x += v0.x; a0.y += v0.y;
      a1.x += v1.x; a1.y += v1.y;
      a2.x += v2.x; a2.y += v2.y;
      a3.x += v3.x; a3.y += v3.y;
    }
    for (; j < n; ++j){
      int s = __shfl(vid, j);
      float2 v = *(const float2*)&h1[(size_t)s * 128 + l * 2];
      a0.x += v.x; a0.y += v.y;
    }
  }
  #pragma unroll
  for (int off = 32; off > 0; off >>= 1) vmax = max(vmax, __shfl_xor(vmax, off));
  float inv = 1.0f / (float)max(me - mb, 1);
  float2 o = { (a0.x + a1.x + a2.x + a3.x) * inv, (a0.y + a1.y + a2.y + a3.y) * inv };
  *(float2*)&hp[(size_t)c * 128 + l * 2] = o;
  if (l == 0) batchp[c] = (vmax >= 0) ? batch[vmax] : 0;  // batch sorted by node id
}

// clusters-per-graph counts (int atomics, wave-coalesced)
__global__ void cntp_kernel(const int* __restrict__ batchp, int* __restrict__ cntp){
  int c = blockIdx.x * blockDim.x + threadIdx.x;
  if (c < N_CLUST) atomicAdd(&cntp[batchp[c]], 1);
}

// ---------------------------------------------------------------------------
__global__ void graph_bounds(const int* __restrict__ batch, int* __restrict__ gstart){
  int g = threadIdx.x;
  if (g > N_GRAPH) return;
  int lo = 0, hi = N_NODES;
  while (lo < hi){ int mid = (lo + hi) >> 1; if (batch[mid] < g) lo = mid + 1; else hi = mid; }
  gstart[g] = lo;
}

__device__ __forceinline__ void atomicMaxPosF(float* addr, float v){
  atomicMax((int*)addr, __float_as_int(v));
}

constexpr int PRE_CHUNK = 100;
__launch_bounds__(128)
__global__ void pre_pool(const float* __restrict__ h1, const int* __restrict__ batch,
                         float* __restrict__ psum, float* __restrict__ pmax){
  int f  = threadIdx.x;
  int i0 = blockIdx.x * PRE_CHUNK;
  int i1 = min(i0 + PRE_CHUNK, N_NODES);
  int g = batch[i0];
  float s = 0.f, m = 0.f;
  for (int i = i0; i < i1; ++i){
    int gb = batch[i];
    if (gb != g){
      atomicAdd(&psum[g * 128 + f], s);
      atomicMaxPosF(&pmax[g * 128 + f], m);
      g = gb; s = 0.f; m = 0.f;
    }
    float v = h1[(size_t)i * 128 + f];
    s += v; m = fmaxf(m, v);
  }
  atomicAdd(&psum[g * 128 + f], s);
  atomicMaxPosF(&pmax[g * 128 + f], m);
}

__launch_bounds__(128)
__global__ void post_pool(const float* __restrict__ hp3, const int* __restrict__ batchp,
                          float* __restrict__ psum, float* __restrict__ pmax){
  int c = blockIdx.x, f = threadIdx.x;
  int g = batchp[c];
  float v = hp3[(size_t)c * 128 + f];
  atomicAdd(&psum[g * 128 + f], v);
  atomicMaxPosF(&pmax[g * 128 + f], v);
}

__launch_bounds__(128)
__global__ void head_kernel(const float* __restrict__ psum, const float* __restrict__ pmax,
                            const float* __restrict__ postsum, const float* __restrict__ postmax,
                            const int* __restrict__ gstart, const int* __restrict__ cntp,
                            const float* __restrict__ l1w, const float* __restrict__ l1b,
                            const float* __restrict__ l2w, const float* __restrict__ l2b,
                            float* __restrict__ out){
  int g = blockIdx.x, t = threadIdx.x;
  __shared__ float z[512];
  __shared__ float a[128];
  __shared__ float logits[16];
  __shared__ float lse_s;
  float cpre  = (float)max(gstart[g + 1] - gstart[g], 1);
  float cpost = fmaxf((float)cntp[g], 1.0f);
  z[t]       = psum[g * 128 + t] / cpre;
  z[128 + t] = pmax[g * 128 + t];
  z[256 + t] = postsum[g * 128 + t] / cpost;
  z[384 + t] = postmax[g * 128 + t];
  __syncthreads();
  float acc = l1b[t];
  #pragma unroll 8
  for (int k = 0; k < 512; ++k) acc = fmaf(z[k], l1w[k * 128 + t], acc);
  a[t] = fmaxf(acc, 0.f);
  __syncthreads();
  if (t < NCLSN){
    float s2 = l2b[t];
    for (int k = 0; k < 128; ++k) s2 = fmaf(a[k], l2w[k * NCLSN + t], s2);
    logits[t] = s2;
  }
  __syncthreads();
  if (t == 0){
    float m = logits[0];
    for (int c = 1; c < NCLSN; ++c) m = fmaxf(m, logits[c]);
    float s = 0.f;
    for (int c = 0; c < NCLSN; ++c) s += expf(logits[c] - m);
    lse_s = m + logf(s);
  }
  __syncthreads();
  if (t < NCLSN) out[g * NCLSN + t] = logits[t] - lse_s;
}

// ---------------------------------------------------------------------------
extern "C" void kernel_launch(void* const* d_in, const int* in_sizes, int n_in,
                              void* d_out, int out_size, void* d_ws, size_t ws_size,
                              hipStream_t stream){
  const float* x       = (const float*)d_in[0];
  const int*   ei      = (const int*)  d_in[1];
  const int*   batch   = (const int*)  d_in[2];
  const int*   cluster = (const int*)  d_in[3];
  const float* W1      = (const float*)d_in[6];
  const float* b1      = (const float*)d_in[7];
  const float* W2      = (const float*)d_in[8];
  const float* b2      = (const float*)d_in[9];
  const float* W3      = (const float*)d_in[10];
  const float* b3      = (const float*)d_in[11];
  const float* l1w     = (const float*)d_in[12];
  const float* l1b     = (const float*)d_in[13];
  const float* l2w     = (const float*)d_in[14];
  const float* l2b     = (const float*)d_in[15];
  float* out = (float*)d_out;

  char* base = (char*)d_ws;
  size_t off = 0;
  auto alloc = [&](size_t bytes) -> char* {
    char* p = base + off;
    off += (bytes + 255) & ~size_t(255);
    return p;
  };
  // ---- zero zone (one memset) ----
  char*  zbase  = base + off;
  int*   deg1   = (int*)  alloc((size_t)N_NODES * 4);
  int*   deg2   = (int*)  alloc((size_t)N_CLUST * 4);
  int*   cntn   = (int*)  alloc((size_t)N_CLUST * 4);
  int*   cntp   = (int*)  alloc((size_t)N_GRAPH * 4);
  float* pre_s  = (float*)alloc((size_t)N_GRAPH * 128 * 4);
  float* pre_m  = (float*)alloc((size_t)N_GRAPH * 128 * 4);
  float* post_s = (float*)alloc((size_t)N_GRAPH * 128 * 4);
  float* post_m = (float*)alloc((size_t)N_GRAPH * 128 * 4);
  size_t zsize = off;
  // ---- plain buffers ----
  float* Ts1     = (float*)alloc((size_t)N_NODES * 128 * 4);  // later aliased
  float* h1      = (float*)alloc((size_t)N_NODES * 128 * 4);
  int*   esrc1   = (int*)  alloc((size_t)N_EDGES * 4);
  int*   psrcC   = (int*)  alloc((size_t)N_EDGES * 4);
  int*   rowptr1 = (int*)  alloc((size_t)(N_NODES + 1) * 4);
  int*   cur1    = (int*)  alloc((size_t)N_NODES * 4);
  int*   rowptrn = (int*)  alloc((size_t)(N_CLUST + 1) * 4);
  int*   curn    = (int*)  alloc((size_t)N_CLUST * 4);
  int*   rowptr2 = (int*)  alloc((size_t)(N_CLUST + 1) * 4);
  int*   cur2    = (int*)  alloc((size_t)N_CLUST * 4);
  int*   nidx    = (int*)  alloc((size_t)N_NODES * 4);
  float* dis1    = (float*)alloc((size_t)N_NODES * 4);
  float* dis2    = (float*)alloc((size_t)N_CLUST * 4);
  int*   batchp  = (int*)  alloc((size_t)N_CLUST * 4);
  int*   gstart  = (int*)  alloc((size_t)(N_GRAPH + 1) * 4);
  int*   bsum    = (int*)  alloc((size_t)NBT * 4);
  int*   boff    = (int*)  alloc((size_t)NBT * 4);
  // aliases into Ts1 (dead after conv1)
  float* hp  = Ts1;
  float* Ts2 = Ts1 + (size_t)N_CLUST * 128;
  float* hp2 = Ts1 + (size_t)2 * N_CLUST * 128;
  float* hp3 = Ts1 + (size_t)3 * N_CLUST * 128;
  float* Ts3 = Ts2;

  (void)in_sizes; (void)n_in; (void)out_size; (void)ws_size;

  hipMemsetAsync(zbase, 0, zsize, stream);

  // graph prep
  hist_kernel<<<(N_EDGES + 255) / 256, 256, 0, stream>>>(ei, cluster, deg1, deg2);
  cntn_kernel<<<(N_NODES + 255) / 256, 256, 0, stream>>>(cluster, cntn);
  block_sums <<<NBT, 256, 0, stream>>>(deg1, cntn, deg2, bsum);
  scan_bsums <<<1, 256, 0, stream>>>(bsum, boff, rowptr1, rowptrn, rowptr2);
  scan_final <<<NBT, 256, 0, stream>>>(deg1, cntn, deg2, boff,
                                       rowptr1, cur1, dis1, rowptrn, curn, rowptr2, cur2, dis2);
  fill_e<<<(N_EDGES + 255) / 256, 256, 0, stream>>>(ei, cur1, esrc1);
  fill_n<<<(N_NODES + 255) / 256, 256, 0, stream>>>(cluster, curn, nidx);
  fill_p<<<(N_EDGES + 255) / 256, 256, 0, stream>>>(ei, cluster, cur2, psrcC);

  // conv1
  gemm128<<<dim3((N_NODES + 63) / 64, 2), 256, 0, stream>>>(x, W1, dis1, Ts1, N_NODES);
  conv_csr<<<N_NODES / 4, 256, 0, stream>>>(Ts1, dis1, rowptr1, esrc1, b1, h1);

  // pre pools
  graph_bounds<<<1, 128, 0, stream>>>(batch, gstart);
  pre_pool<<<(N_NODES + PRE_CHUNK - 1) / PRE_CHUNK, 128, 0, stream>>>(h1, batch, pre_s, pre_m);

  // cluster mean pool + batch_p + cntp
  cluster_gather<<<N_CLUST / 4, 256, 0, stream>>>(h1, rowptrn, nidx, batch, hp, batchp);
  cntp_kernel<<<(N_CLUST + 255) / 256, 256, 0, stream>>>(batchp, cntp);

  // conv2
  gemm128<<<dim3((N_CLUST + 63) / 64, 2), 256, 0, stream>>>(hp, W2, dis2, Ts2, N_CLUST);
  conv_csr<<<N_CLUST / 4, 256, 0, stream>>>(Ts2, dis2, rowptr2, psrcC, b2, hp2);

  // conv3
  gemm128<<<dim3((N_CLUST + 63) / 64, 2), 256, 0, stream>>>(hp2, W3, dis2, Ts3, N_CLUST);
  conv_csr<<<N_CLUST / 4, 256, 0, stream>>>(Ts3, dis2, rowptr2, psrcC, b3, hp3);

  // post pools + head
  post_pool<<<N_CLUST, 128, 0, stream>>>(hp3, batchp, post_s, post_m);
  head_kernel<<<N_GRAPH, 128, 0, stream>>>(pre_s, pre_m, post_s, post_m, gstart, cntp,
                                           l1w, l1b, l2w, l2b, out);
}

// Round 5
// 831.985 us; speedup vs baseline: 1.9922x; 1.2938x over previous
//
#include <hip/hip_runtime.h>

constexpr int N_NODES = 100000;
constexpr int N_EDGES = 1600000;
constexpr int N_CLUST = 25000;
constexpr int N_GRAPH = 64;
constexpr int NCLSN   = 10;

// bucket decomposition for the sort-based CSR builds
constexpr int BKT1_SHIFT = 9;                       // node-dst buckets of 512 ids
constexpr int NBKT1 = (N_NODES + 511) / 512;        // 196
constexpr int BKT2_SHIFT = 7;                       // cluster-dst buckets of 128 ids
constexpr int NBKT2 = (N_CLUST + 127) / 128;        // 196
constexpr int EPB = 4096;                           // edges per block (count/scatter)
constexpr int NEB = (N_EDGES + EPB - 1) / EPB;      // 391
constexpr int SORT_CAP = 12288;                     // LDS staging cap (mean 8163, sd ~90)

// scan partitioning: 1024 elements per block, three concatenated segments
constexpr int SCAN_BPB = 1024;
constexpr int NB1 = (N_NODES + SCAN_BPB - 1) / SCAN_BPB;  // 98
constexpr int NB2 = (N_CLUST + SCAN_BPB - 1) / SCAN_BPB;  // 25
constexpr int NB3 = (N_CLUST + SCAN_BPB - 1) / SCAN_BPB;  // 25
constexpr int NBT = NB1 + NB2 + NB3;                      // 148

// ---------------------------------------------------------------------------
// bucket-sort CSR build, phase 1: LDS-aggregated bucket counts
// ---------------------------------------------------------------------------
__launch_bounds__(256)
__global__ void count_kernel(const int* __restrict__ ei, const int* __restrict__ cluster,
                             int* __restrict__ gcnt1, int* __restrict__ gcnt2){
  __shared__ int h1c[NBKT1], h2c[NBKT2];
  int t = threadIdx.x;
  for (int i = t; i < NBKT1; i += 256) h1c[i] = 0;
  for (int i = t; i < NBKT2; i += 256) h2c[i] = 0;
  __syncthreads();
  int e0 = blockIdx.x * EPB;
  #pragma unroll
  for (int i = 0; i < EPB / 256; ++i){
    int e = e0 + i * 256 + t;
    if (e < N_EDGES){
      int dst = ei[N_EDGES + e];
      int cd  = cluster[dst];
      atomicAdd(&h1c[dst >> BKT1_SHIFT], 1);
      atomicAdd(&h2c[cd  >> BKT2_SHIFT], 1);
    }
  }
  __syncthreads();
  for (int i = t; i < NBKT1; i += 256) if (h1c[i]) atomicAdd(&gcnt1[i], h1c[i]);
  for (int i = t; i < NBKT2; i += 256) if (h2c[i]) atomicAdd(&gcnt2[i], h2c[i]);
}

// phase 2: bucket bases (exclusive scan of the 196-entry count arrays)
__launch_bounds__(256)
__global__ void bucket_scan(const int* __restrict__ gcnt1, const int* __restrict__ gcnt2,
                            int* __restrict__ gbase1, int* __restrict__ gcur1,
                            int* __restrict__ gbase2, int* __restrict__ gcur2){
  __shared__ int s[256];
  int t = threadIdx.x;
  int v = (t < NBKT1) ? gcnt1[t] : 0;
  s[t] = v; __syncthreads();
  for (int off = 1; off < 256; off <<= 1){
    int a = (t >= off) ? s[t - off] : 0;
    __syncthreads(); s[t] += a; __syncthreads();
  }
  if (t < NBKT1){ gbase1[t] = s[t] - v; gcur1[t] = s[t] - v; }
  __syncthreads();
  v = (t < NBKT2) ? gcnt2[t] : 0;
  s[t] = v; __syncthreads();
  for (int off = 1; off < 256; off <<= 1){
    int a = (t >= off) ? s[t - off] : 0;
    __syncthreads(); s[t] += a; __syncthreads();
  }
  if (t < NBKT2){ gbase2[t] = s[t] - v; gcur2[t] = s[t] - v; }
}

// phase 3: scatter packed words into bucket regions (per-block reserved runs)
__launch_bounds__(256)
__global__ void scatter_kernel(const int* __restrict__ ei, const int* __restrict__ cluster,
                               int* __restrict__ gcur1, int* __restrict__ gcur2,
                               unsigned int* __restrict__ stage1, unsigned int* __restrict__ stage2){
  __shared__ int h1c[NBKT1], h2c[NBKT2];
  __shared__ int gb1[NBKT1], gb2[NBKT2];
  int t = threadIdx.x;
  for (int i = t; i < NBKT1; i += 256) h1c[i] = 0;
  for (int i = t; i < NBKT2; i += 256) h2c[i] = 0;
  __syncthreads();
  int e0 = blockIdx.x * EPB;
  #pragma unroll
  for (int i = 0; i < EPB / 256; ++i){
    int e = e0 + i * 256 + t;
    if (e < N_EDGES){
      int dst = ei[N_EDGES + e];
      int cd  = cluster[dst];
      atomicAdd(&h1c[dst >> BKT1_SHIFT], 1);
      atomicAdd(&h2c[cd  >> BKT2_SHIFT], 1);
    }
  }
  __syncthreads();
  for (int i = t; i < NBKT1; i += 256){ int c = h1c[i]; gb1[i] = c ? atomicAdd(&gcur1[i], c) : 0; }
  for (int i = t; i < NBKT2; i += 256){ int c = h2c[i]; gb2[i] = c ? atomicAdd(&gcur2[i], c) : 0; }
  __syncthreads();
  for (int i = t; i < NBKT1; i += 256) h1c[i] = 0;   // reuse as local cursors
  for (int i = t; i < NBKT2; i += 256) h2c[i] = 0;
  __syncthreads();
  #pragma unroll
  for (int i = 0; i < EPB / 256; ++i){
    int e = e0 + i * 256 + t;
    if (e < N_EDGES){
      int src = ei[e], dst = ei[N_EDGES + e];
      int cs = cluster[src], cd = cluster[dst];
      int b1 = dst >> BKT1_SHIFT, b2 = cd >> BKT2_SHIFT;
      int r1 = atomicAdd(&h1c[b1], 1);
      int r2 = atomicAdd(&h2c[b2], 1);
      stage1[gb1[b1] + r1] = ((unsigned)(dst & 511) << 17) | (unsigned)src;
      stage2[gb2[b2] + r2] = ((unsigned)(cd & 127) << 15) | (unsigned)cs;
    }
  }
}

// phase 4: per-bucket LDS counting sort -> payload grouped by dst id,
// plus coalesced non-atomic degree writes
template<int NBINS, int PSHIFT>
__launch_bounds__(256)
__global__ void bucket_sort(const unsigned int* __restrict__ stage, const int* __restrict__ gbase,
                            const int* __restrict__ gcnt, int* __restrict__ outpay,
                            int* __restrict__ deg, int ntot){
  __shared__ int cnt[NBINS], off[NBINS];
  __shared__ int sorted[SORT_CAP];
  int b = blockIdx.x, t = threadIdx.x;
  int base = gbase[b], n = gcnt[b];
  for (int i = t; i < NBINS; i += 256) cnt[i] = 0;
  __syncthreads();
  for (int i = t; i < n; i += 256) atomicAdd(&cnt[stage[base + i] >> PSHIFT], 1);
  __syncthreads();
  for (int i = t; i < NBINS; i += 256){
    int idx = b * NBINS + i;
    if (idx < ntot) deg[idx] = cnt[i];
    off[i] = cnt[i];
  }
  __syncthreads();
  for (int s = 1; s < NBINS; s <<= 1){
    int v0 = 0, v1 = 0;
    if (t < NBINS && t >= s) v0 = off[t - s];
    if (NBINS > 256 && t + 256 < NBINS && t + 256 >= s) v1 = off[t + 256 - s];
    __syncthreads();
    if (t < NBINS) off[t] += v0;
    if (NBINS > 256 && t + 256 < NBINS) off[t + 256] += v1;
    __syncthreads();
  }
  for (int i = t; i < NBINS; i += 256) off[i] -= cnt[i];   // exclusive cursors
  __syncthreads();
  constexpr unsigned PMASK = (1u << PSHIFT) - 1u;
  if (n <= SORT_CAP){
    for (int i = t; i < n; i += 256){
      unsigned w = stage[base + i];
      int r = atomicAdd(&off[w >> PSHIFT], 1);
      sorted[r] = (int)(w & PMASK);
    }
    __syncthreads();
    for (int i = t; i < n; i += 256) outpay[base + i] = sorted[i];
  } else {  // never expected; correct fallback
    for (int i = t; i < n; i += 256){
      unsigned w = stage[base + i];
      int r = atomicAdd(&off[w >> PSHIFT], 1);
      outpay[base + r] = (int)(w & PMASK);
    }
  }
}

// cluster membership counts
__global__ void cntn_kernel(const int* __restrict__ cluster, int* __restrict__ cntn){
  int v = blockIdx.x * blockDim.x + threadIdx.x;
  if (v < N_NODES) atomicAdd(&cntn[cluster[v]], 1);
}

// ---------------------------------------------------------------------------
// device-wide 3-segment exclusive scan:
//   deg1 -> rowptr1 (+dis1), cntn -> rowptrn/curn, deg2 -> rowptr2 (+dis2)
// ---------------------------------------------------------------------------
__device__ __forceinline__ void seg_select(int b, const int* deg1, const int* cntn,
                                           const int* deg2, const int*& src, int& n, int& base){
  if (b < NB1){ src = deg1; n = N_NODES; base = b * SCAN_BPB; }
  else if (b < NB1 + NB2){ src = cntn; n = N_CLUST; base = (b - NB1) * SCAN_BPB; }
  else { src = deg2; n = N_CLUST; base = (b - NB1 - NB2) * SCAN_BPB; }
}

__launch_bounds__(256)
__global__ void block_sums(const int* __restrict__ deg1, const int* __restrict__ cntn,
                           const int* __restrict__ deg2, int* __restrict__ bsum){
  int b = blockIdx.x;
  const int* src; int n, base;
  seg_select(b, deg1, cntn, deg2, src, n, base);
  int t = threadIdx.x;
  int i0 = base + t * 4;
  int s = 0;
  if (i0 + 3 < n){ int4 v = *(const int4*)&src[i0]; s = v.x + v.y + v.z + v.w; }
  else { for (int j = 0; j < 4; ++j){ int i = i0 + j; if (i < n) s += src[i]; } }
  __shared__ int sh[256];
  sh[t] = s; __syncthreads();
  for (int off = 128; off > 0; off >>= 1){
    if (t < off) sh[t] += sh[t + off];
    __syncthreads();
  }
  if (t == 0) bsum[b] = sh[0];
}

__launch_bounds__(256)
__global__ void scan_bsums(const int* __restrict__ bsum, int* __restrict__ boff,
                           int* __restrict__ rowptr1, int* __restrict__ rowptrn,
                           int* __restrict__ rowptr2){
  __shared__ int s[256];
  int t = threadIdx.x;
  int v = (t < NBT) ? bsum[t] : 0;
  s[t] = v; __syncthreads();
  int seg = (t < NB1) ? 0 : (t < NB1 + NB2 ? 1 : 2);
  for (int off = 1; off < 256; off <<= 1){
    int add = 0;
    if (t >= off){
      int u = t - off;
      int useg = (u < NB1) ? 0 : (u < NB1 + NB2 ? 1 : 2);
      if (useg == seg) add = s[u];
    }
    __syncthreads();
    s[t] += add;
    __syncthreads();
  }
  if (t < NBT) boff[t] = s[t] - v;
  if (t == NB1 - 1)       rowptr1[N_NODES] = s[t];
  if (t == NB1 + NB2 - 1) rowptrn[N_CLUST] = s[t];
  if (t == NBT - 1)       rowptr2[N_CLUST] = s[t];
}

__launch_bounds__(256)
__global__ void scan_final(const int* __restrict__ deg1, const int* __restrict__ cntn,
                           const int* __restrict__ deg2, const int* __restrict__ boff,
                           int* __restrict__ rowptr1, float* __restrict__ dis1,
                           int* __restrict__ rowptrn, int* __restrict__ curn,
                           int* __restrict__ rowptr2, float* __restrict__ dis2){
  int b = blockIdx.x;
  const int* src; int n, base;
  seg_select(b, deg1, cntn, deg2, src, n, base);
  int* rp; int* cur; float* dis;
  if (b < NB1){ rp = rowptr1; cur = nullptr; dis = dis1; }
  else if (b < NB1 + NB2){ rp = rowptrn; cur = curn; dis = nullptr; }
  else { rp = rowptr2; cur = nullptr; dis = dis2; }
  int t = threadIdx.x;
  int i0 = base + t * 4;
  int v[4]; int s = 0;
  #pragma unroll
  for (int j = 0; j < 4; ++j){ int i = i0 + j; v[j] = (i < n) ? src[i] : 0; s += v[j]; }
  __shared__ int sh[256];
  sh[t] = s; __syncthreads();
  for (int off = 1; off < 256; off <<= 1){
    int add = (t >= off) ? sh[t - off] : 0;
    __syncthreads();
    sh[t] += add;
    __syncthreads();
  }
  int run = sh[t] - s + boff[b];
  #pragma unroll
  for (int j = 0; j < 4; ++j){
    int i = i0 + j;
    if (i < n){
      rp[i] = run;
      if (cur) cur[i] = run;
      if (dis) dis[i] = rsqrtf((float)v[j] + 1.0f);
      run += v[j];
    }
  }
}

// node->cluster CSR fill
__global__ void fill_n(const int* __restrict__ cluster, int* __restrict__ curn,
                       int* __restrict__ nidx){
  int v = blockIdx.x * blockDim.x + threadIdx.x;
  if (v >= N_NODES) return;
  nidx[atomicAdd(&curn[cluster[v]], 1)] = v;
}

// ---------------------------------------------------------------------------
// GEMM: C[M,128] = (A[M,128] @ B[128,128]) * scale[row]
// ---------------------------------------------------------------------------
__launch_bounds__(256)
__global__ void gemm128(const float* __restrict__ A, const float* __restrict__ B,
                        const float* __restrict__ scale, float* __restrict__ Cmat, int M){
  __shared__ float As[128 * 64];
  __shared__ float Bs[128 * 64];
  const int t = threadIdx.x;
  const int bm = blockIdx.x, bn = blockIdx.y;
  const int row0 = bm * 64;

  #pragma unroll
  for (int i = 0; i < 8; ++i){
    int idx4 = t + i * 256;
    int k = idx4 >> 4, c4 = idx4 & 15;
    float4 v = *(const float4*)&B[k * 128 + bn * 64 + c4 * 4];
    *(float4*)&Bs[k * 64 + c4 * 4] = v;
  }
  {
    int m = t & 63, kb = t >> 6;
    int row = row0 + m; if (row >= M) row = M - 1;
    const float* Arow = A + (size_t)row * 128;
    #pragma unroll
    for (int i = 0; i < 8; ++i){
      int k4 = kb + i * 4;
      float4 v = *(const float4*)&Arow[k4 * 4];
      int k = k4 * 4;
      As[(k + 0) * 64 + m] = v.x;
      As[(k + 1) * 64 + m] = v.y;
      As[(k + 2) * 64 + m] = v.z;
      As[(k + 3) * 64 + m] = v.w;
    }
  }
  __syncthreads();

  const int tx = t & 15, ty = t >> 4;
  float acc[4][4] = {};
  #pragma unroll 4
  for (int k = 0; k < 128; ++k){
    float a[4], b[4];
    *(float4*)a = *(const float4*)&As[k * 64 + (ty << 2)];
    *(float4*)b = *(const float4*)&Bs[k * 64 + (tx << 2)];
    #pragma unroll
    for (int i = 0; i < 4; ++i)
      #pragma unroll
      for (int j = 0; j < 4; ++j)
        acc[i][j] = fmaf(a[i], b[j], acc[i][j]);
  }
  #pragma unroll
  for (int i = 0; i < 4; ++i){
    int row = row0 + (ty << 2) + i;
    if (row < M){
      float sc = scale[row];
      float4 o = { acc[i][0] * sc, acc[i][1] * sc, acc[i][2] * sc, acc[i][3] * sc };
      *(float4*)&Cmat[(size_t)row * 128 + bn * 64 + (tx << 2)] = o;
    }
  }
}

// ---------------------------------------------------------------------------
// CSR conv, chunked + ILP: out[i] = relu( dis[i]*(sum_e Ts[src_e] + Ts[i]) + b )
// ---------------------------------------------------------------------------
__launch_bounds__(256)
__global__ void conv_csr(const float* __restrict__ Ts, const float* __restrict__ dis,
                         const int* __restrict__ rowptr, const int* __restrict__ esrc,
                         const float* __restrict__ bias, float* __restrict__ Hout){
  int w = blockIdx.x * 4 + (threadIdx.x >> 6);
  int l = threadIdx.x & 63;
  int beg = rowptr[w], end = rowptr[w + 1];
  float2 a0{0.f,0.f}, a1{0.f,0.f}, a2{0.f,0.f}, a3{0.f,0.f};
  for (int base = beg; base < end; base += 64){
    int n = min(64, end - base);
    int eid = esrc[base + min(l, n - 1)];
    int j = 0;
    for (; j + 4 <= n; j += 4){
      int s0 = __shfl(eid, j);
      int s1 = __shfl(eid, j + 1);
      int s2 = __shfl(eid, j + 2);
      int s3 = __shfl(eid, j + 3);
      float2 v0 = *(const float2*)&Ts[(size_t)s0 * 128 + l * 2];
      float2 v1 = *(const float2*)&Ts[(size_t)s1 * 128 + l * 2];
      float2 v2 = *(const float2*)&Ts[(size_t)s2 * 128 + l * 2];
      float2 v3 = *(const float2*)&Ts[(size_t)s3 * 128 + l * 2];
      a0.x += v0.x; a0.y += v0.y;
      a1.x += v1.x; a1.y += v1.y;
      a2.x += v2.x; a2.y += v2.y;
      a3.x += v3.x; a3.y += v3.y;
    }
    for (; j < n; ++j){
      int s = __shfl(eid, j);
      float2 v = *(const float2*)&Ts[(size_t)s * 128 + l * 2];
      a0.x += v.x; a0.y += v.y;
    }
  }
  float d = dis[w];
  float2 self = *(const float2*)&Ts[(size_t)w * 128 + l * 2];
  float2 bb   = *(const float2*)&bias[l * 2];
  float2 r;
  r.x = fmaxf(fmaf(d, a0.x + a1.x + a2.x + a3.x + self.x, bb.x), 0.f);
  r.y = fmaxf(fmaf(d, a0.y + a1.y + a2.y + a3.y + self.y, bb.y), 0.f);
  *(float2*)&Hout[(size_t)w * 128 + l * 2] = r;
}

// cluster mean pool + batch_p, chunked + ILP
__launch_bounds__(256)
__global__ void cluster_gather(const float* __restrict__ h1, const int* __restrict__ rowptrn,
                               const int* __restrict__ nidx, const int* __restrict__ batch,
                               float* __restrict__ hp, int* __restrict__ batchp){
  int c = blockIdx.x * 4 + (threadIdx.x >> 6);
  int l = threadIdx.x & 63;
  int mb = rowptrn[c], me = rowptrn[c + 1];
  float2 a0{0.f,0.f}, a1{0.f,0.f}, a2{0.f,0.f}, a3{0.f,0.f};
  int vmax = -1;
  for (int base = mb; base < me; base += 64){
    int n = min(64, me - base);
    int vid = nidx[base + min(l, n - 1)];
    if (l < n) vmax = max(vmax, vid);
    int j = 0;
    for (; j + 4 <= n; j += 4){
      int s0 = __shfl(vid, j);
      int s1 = __shfl(vid, j + 1);
      int s2 = __shfl(vid, j + 2);
      int s3 = __shfl(vid, j + 3);
      float2 v0 = *(const float2*)&h1[(size_t)s0 * 128 + l * 2];
      float2 v1 = *(const float2*)&h1[(size_t)s1 * 128 + l * 2];
      float2 v2 = *(const float2*)&h1[(size_t)s2 * 128 + l * 2];
      float2 v3 = *(const float2*)&h1[(size_t)s3 * 128 + l * 2];
      a0.x += v0.x; a0.y += v0.y;
      a1.x += v1.x; a1.y += v1.y;
      a2.x += v2.x; a2.y += v2.y;
      a3.x += v3.x; a3.y += v3.y;
    }
    for (; j < n; ++j){
      int s = __shfl(vid, j);
      float2 v = *(const float2*)&h1[(size_t)s * 128 + l * 2];
      a0.x += v.x; a0.y += v.y;
    }
  }
  #pragma unroll
  for (int off = 32; off > 0; off >>= 1) vmax = max(vmax, __shfl_xor(vmax, off));
  float inv = 1.0f / (float)max(me - mb, 1);
  float2 o = { (a0.x + a1.x + a2.x + a3.x) * inv, (a0.y + a1.y + a2.y + a3.y) * inv };
  *(float2*)&hp[(size_t)c * 128 + l * 2] = o;
  if (l == 0) batchp[c] = (vmax >= 0) ? batch[vmax] : 0;  // batch sorted by node id
}

__global__ void cntp_kernel(const int* __restrict__ batchp, int* __restrict__ cntp){
  int c = blockIdx.x * blockDim.x + threadIdx.x;
  if (c < N_CLUST) atomicAdd(&cntp[batchp[c]], 1);
}

// ---------------------------------------------------------------------------
__global__ void graph_bounds(const int* __restrict__ batch, int* __restrict__ gstart){
  int g = threadIdx.x;
  if (g > N_GRAPH) return;
  int lo = 0, hi = N_NODES;
  while (lo < hi){ int mid = (lo + hi) >> 1; if (batch[mid] < g) lo = mid + 1; else hi = mid; }
  gstart[g] = lo;
}

__device__ __forceinline__ void atomicMaxPosF(float* addr, float v){
  atomicMax((int*)addr, __float_as_int(v));
}

constexpr int PRE_CHUNK = 100;
__launch_bounds__(128)
__global__ void pre_pool(const float* __restrict__ h1, const int* __restrict__ batch,
                         float* __restrict__ psum, float* __restrict__ pmax){
  int f  = threadIdx.x;
  int i0 = blockIdx.x * PRE_CHUNK;
  int i1 = min(i0 + PRE_CHUNK, N_NODES);
  int g = batch[i0];
  float s = 0.f, m = 0.f;
  for (int i = i0; i < i1; ++i){
    int gb = batch[i];
    if (gb != g){
      atomicAdd(&psum[g * 128 + f], s);
      atomicMaxPosF(&pmax[g * 128 + f], m);
      g = gb; s = 0.f; m = 0.f;
    }
    float v = h1[(size_t)i * 128 + f];
    s += v; m = fmaxf(m, v);
  }
  atomicAdd(&psum[g * 128 + f], s);
  atomicMaxPosF(&pmax[g * 128 + f], m);
}

__launch_bounds__(128)
__global__ void post_pool(const float* __restrict__ hp3, const int* __restrict__ batchp,
                          float* __restrict__ psum, float* __restrict__ pmax){
  int c = blockIdx.x, f = threadIdx.x;
  int g = batchp[c];
  float v = hp3[(size_t)c * 128 + f];
  atomicAdd(&psum[g * 128 + f], v);
  atomicMaxPosF(&pmax[g * 128 + f], v);
}

__launch_bounds__(128)
__global__ void head_kernel(const float* __restrict__ psum, const float* __restrict__ pmax,
                            const float* __restrict__ postsum, const float* __restrict__ postmax,
                            const int* __restrict__ gstart, const int* __restrict__ cntp,
                            const float* __restrict__ l1w, const float* __restrict__ l1b,
                            const float* __restrict__ l2w, const float* __restrict__ l2b,
                            float* __restrict__ out){
  int g = blockIdx.x, t = threadIdx.x;
  __shared__ float z[512];
  __shared__ float a[128];
  __shared__ float logits[16];
  __shared__ float lse_s;
  float cpre  = (float)max(gstart[g + 1] - gstart[g], 1);
  float cpost = fmaxf((float)cntp[g], 1.0f);
  z[t]       = psum[g * 128 + t] / cpre;
  z[128 + t] = pmax[g * 128 + t];
  z[256 + t] = postsum[g * 128 + t] / cpost;
  z[384 + t] = postmax[g * 128 + t];
  __syncthreads();
  float acc = l1b[t];
  #pragma unroll 8
  for (int k = 0; k < 512; ++k) acc = fmaf(z[k], l1w[k * 128 + t], acc);
  a[t] = fmaxf(acc, 0.f);
  __syncthreads();
  if (t < NCLSN){
    float s2 = l2b[t];
    for (int k = 0; k < 128; ++k) s2 = fmaf(a[k], l2w[k * NCLSN + t], s2);
    logits[t] = s2;
  }
  __syncthreads();
  if (t == 0){
    float m = logits[0];
    for (int c = 1; c < NCLSN; ++c) m = fmaxf(m, logits[c]);
    float s = 0.f;
    for (int c = 0; c < NCLSN; ++c) s += expf(logits[c] - m);
    lse_s = m + logf(s);
  }
  __syncthreads();
  if (t < NCLSN) out[g * NCLSN + t] = logits[t] - lse_s;
}

// ---------------------------------------------------------------------------
extern "C" void kernel_launch(void* const* d_in, const int* in_sizes, int n_in,
                              void* d_out, int out_size, void* d_ws, size_t ws_size,
                              hipStream_t stream){
  const float* x       = (const float*)d_in[0];
  const int*   ei      = (const int*)  d_in[1];
  const int*   batch   = (const int*)  d_in[2];
  const int*   cluster = (const int*)  d_in[3];
  const float* W1      = (const float*)d_in[6];
  const float* b1      = (const float*)d_in[7];
  const float* W2      = (const float*)d_in[8];
  const float* b2      = (const float*)d_in[9];
  const float* W3      = (const float*)d_in[10];
  const float* b3      = (const float*)d_in[11];
  const float* l1w     = (const float*)d_in[12];
  const float* l1b     = (const float*)d_in[13];
  const float* l2w     = (const float*)d_in[14];
  const float* l2b     = (const float*)d_in[15];
  float* out = (float*)d_out;

  char* base = (char*)d_ws;
  size_t off = 0;
  auto alloc = [&](size_t bytes) -> char* {
    char* p = base + off;
    off += (bytes + 255) & ~size_t(255);
    return p;
  };
  // ---- zero zone (one memset) ----
  char*  zbase  = base + off;
  int*   gcnt1  = (int*)  alloc((size_t)NBKT1 * 4);
  int*   gcnt2  = (int*)  alloc((size_t)NBKT2 * 4);
  int*   cntn   = (int*)  alloc((size_t)N_CLUST * 4);
  int*   cntp   = (int*)  alloc((size_t)N_GRAPH * 4);
  float* pre_s  = (float*)alloc((size_t)N_GRAPH * 128 * 4);
  float* pre_m  = (float*)alloc((size_t)N_GRAPH * 128 * 4);
  float* post_s = (float*)alloc((size_t)N_GRAPH * 128 * 4);
  float* post_m = (float*)alloc((size_t)N_GRAPH * 128 * 4);
  size_t zsize = off;
  // ---- plain buffers ----
  float* Ts1     = (float*)alloc((size_t)N_NODES * 128 * 4);  // later aliased
  float* h1      = (float*)alloc((size_t)N_NODES * 128 * 4);  // stage bufs alias here
  int*   esrc1   = (int*)  alloc((size_t)N_EDGES * 4);
  int*   psrcC   = (int*)  alloc((size_t)N_EDGES * 4);
  int*   deg1    = (int*)  alloc((size_t)N_NODES * 4);
  int*   deg2    = (int*)  alloc((size_t)N_CLUST * 4);
  int*   rowptr1 = (int*)  alloc((size_t)(N_NODES + 1) * 4);
  int*   rowptrn = (int*)  alloc((size_t)(N_CLUST + 1) * 4);
  int*   curn    = (int*)  alloc((size_t)N_CLUST * 4);
  int*   rowptr2 = (int*)  alloc((size_t)(N_CLUST + 1) * 4);
  int*   nidx    = (int*)  alloc((size_t)N_NODES * 4);
  float* dis1    = (float*)alloc((size_t)N_NODES * 4);
  float* dis2    = (float*)alloc((size_t)N_CLUST * 4);
  int*   batchp  = (int*)  alloc((size_t)N_CLUST * 4);
  int*   gstart  = (int*)  alloc((size_t)(N_GRAPH + 1) * 4);
  int*   bsum    = (int*)  alloc((size_t)NBT * 4);
  int*   boff    = (int*)  alloc((size_t)NBT * 4);
  int*   gbase1  = (int*)  alloc((size_t)NBKT1 * 4);
  int*   gcur1   = (int*)  alloc((size_t)NBKT1 * 4);
  int*   gbase2  = (int*)  alloc((size_t)NBKT2 * 4);
  int*   gcur2   = (int*)  alloc((size_t)NBKT2 * 4);
  // stage buffers alias the (not-yet-written) h1 region
  unsigned int* stage1 = (unsigned int*)h1;
  unsigned int* stage2 = stage1 + N_EDGES;
  // aliases into Ts1 (dead after conv1)
  float* hp  = Ts1;
  float* Ts2 = Ts1 + (size_t)N_CLUST * 128;
  float* hp2 = Ts1 + (size_t)2 * N_CLUST * 128;
  float* hp3 = Ts1 + (size_t)3 * N_CLUST * 128;
  float* Ts3 = Ts2;

  (void)in_sizes; (void)n_in; (void)out_size; (void)ws_size;

  hipMemsetAsync(zbase, 0, zsize, stream);

  // ---- sort-based CSR build ----
  count_kernel  <<<NEB, 256, 0, stream>>>(ei, cluster, gcnt1, gcnt2);
  cntn_kernel   <<<(N_NODES + 255) / 256, 256, 0, stream>>>(cluster, cntn);
  bucket_scan   <<<1, 256, 0, stream>>>(gcnt1, gcnt2, gbase1, gcur1, gbase2, gcur2);
  scatter_kernel<<<NEB, 256, 0, stream>>>(ei, cluster, gcur1, gcur2, stage1, stage2);
  bucket_sort<512, 17><<<NBKT1, 256, 0, stream>>>(stage1, gbase1, gcnt1, esrc1, deg1, N_NODES);
  bucket_sort<128, 15><<<NBKT2, 256, 0, stream>>>(stage2, gbase2, gcnt2, psrcC, deg2, N_CLUST);
  block_sums <<<NBT, 256, 0, stream>>>(deg1, cntn, deg2, bsum);
  scan_bsums <<<1, 256, 0, stream>>>(bsum, boff, rowptr1, rowptrn, rowptr2);
  scan_final <<<NBT, 256, 0, stream>>>(deg1, cntn, deg2, boff,
                                       rowptr1, dis1, rowptrn, curn, rowptr2, dis2);
  fill_n<<<(N_NODES + 255) / 256, 256, 0, stream>>>(cluster, curn, nidx);

  // conv1
  gemm128<<<dim3((N_NODES + 63) / 64, 2), 256, 0, stream>>>(x, W1, dis1, Ts1, N_NODES);
  conv_csr<<<N_NODES / 4, 256, 0, stream>>>(Ts1, dis1, rowptr1, esrc1, b1, h1);

  // pre pools
  graph_bounds<<<1, 128, 0, stream>>>(batch, gstart);
  pre_pool<<<(N_NODES + PRE_CHUNK - 1) / PRE_CHUNK, 128, 0, stream>>>(h1, batch, pre_s, pre_m);

  // cluster mean pool + batch_p + cntp
  cluster_gather<<<N_CLUST / 4, 256, 0, stream>>>(h1, rowptrn, nidx, batch, hp, batchp);
  cntp_kernel<<<(N_CLUST + 255) / 256, 256, 0, stream>>>(batchp, cntp);

  // conv2
  gemm128<<<dim3((N_CLUST + 63) / 64, 2), 256, 0, stream>>>(hp, W2, dis2, Ts2, N_CLUST);
  conv_csr<<<N_CLUST / 4, 256, 0, stream>>>(Ts2, dis2, rowptr2, psrcC, b2, hp2);

  // conv3
  gemm128<<<dim3((N_CLUST + 63) / 64, 2), 256, 0, stream>>>(hp2, W3, dis2, Ts3, N_CLUST);
  conv_csr<<<N_CLUST / 4, 256, 0, stream>>>(Ts3, dis2, rowptr2, psrcC, b3, hp3);

  // post pools + head
  post_pool<<<N_CLUST, 128, 0, stream>>>(hp3, batchp, post_s, post_m);
  head_kernel<<<N_GRAPH, 128, 0, stream>>>(pre_s, pre_m, post_s, post_m, gstart, cntp,
                                           l1w, l1b, l2w, l2b, out);
}

// Round 6
// 763.406 us; speedup vs baseline: 2.1711x; 1.0898x over previous
//
#include <hip/hip_runtime.h>

constexpr int N_NODES = 100000;
constexpr int N_EDGES = 1600000;
constexpr int N_CLUST = 25000;
constexpr int N_GRAPH = 64;
constexpr int NCLSN   = 10;

// bucket decomposition for the sort-based CSR builds
constexpr int BKT1_SHIFT = 9;                       // node-dst buckets of 512 ids
constexpr int NBKT1 = (N_NODES + 511) / 512;        // 196
constexpr int BKT2_SHIFT = 7;                       // cluster-dst buckets of 128 ids
constexpr int NBKT2 = (N_CLUST + 127) / 128;        // 196
constexpr int EPB = 4096;                           // edges per block (count/scatter)
constexpr int NEB = (N_EDGES + EPB - 1) / EPB;      // 391
constexpr int SORT_CAP = 12288;                     // LDS staging cap (mean 8163, sd ~90)

// scan partitioning: 1024 elements per block, three concatenated segments
constexpr int SCAN_BPB = 1024;
constexpr int NB1 = (N_NODES + SCAN_BPB - 1) / SCAN_BPB;  // 98
constexpr int NB2 = (N_CLUST + SCAN_BPB - 1) / SCAN_BPB;  // 25
constexpr int NB3 = (N_CLUST + SCAN_BPB - 1) / SCAN_BPB;  // 25
constexpr int NBT = NB1 + NB2 + NB3;                      // 148

// ---- bf16 pack/unpack helpers (features stored as packed pairs in uint) ----
__device__ __forceinline__ float bf16lo(unsigned u){ return __uint_as_float(u << 16); }
__device__ __forceinline__ float bf16hi(unsigned u){ return __uint_as_float(u & 0xffff0000u); }
__device__ __forceinline__ unsigned bf16_rne(float f){
  unsigned u = __float_as_uint(f);
  return (u + 0x7fffu + ((u >> 16) & 1u)) >> 16;
}
__device__ __forceinline__ unsigned pack2(float lo, float hi){
  return bf16_rne(lo) | (bf16_rne(hi) << 16);
}

// ---------------------------------------------------------------------------
// bucket-sort CSR build, phase 1: LDS-aggregated bucket counts
// ---------------------------------------------------------------------------
__launch_bounds__(256)
__global__ void count_kernel(const int* __restrict__ ei, const int* __restrict__ cluster,
                             int* __restrict__ gcnt1, int* __restrict__ gcnt2){
  __shared__ int h1c[NBKT1], h2c[NBKT2];
  int t = threadIdx.x;
  for (int i = t; i < NBKT1; i += 256) h1c[i] = 0;
  for (int i = t; i < NBKT2; i += 256) h2c[i] = 0;
  __syncthreads();
  int e0 = blockIdx.x * EPB;
  #pragma unroll
  for (int i = 0; i < EPB / 256; ++i){
    int e = e0 + i * 256 + t;
    if (e < N_EDGES){
      int dst = ei[N_EDGES + e];
      int cd  = cluster[dst];
      atomicAdd(&h1c[dst >> BKT1_SHIFT], 1);
      atomicAdd(&h2c[cd  >> BKT2_SHIFT], 1);
    }
  }
  __syncthreads();
  for (int i = t; i < NBKT1; i += 256) if (h1c[i]) atomicAdd(&gcnt1[i], h1c[i]);
  for (int i = t; i < NBKT2; i += 256) if (h2c[i]) atomicAdd(&gcnt2[i], h2c[i]);
}

// phase 2: bucket bases
__launch_bounds__(256)
__global__ void bucket_scan(const int* __restrict__ gcnt1, const int* __restrict__ gcnt2,
                            int* __restrict__ gbase1, int* __restrict__ gcur1,
                            int* __restrict__ gbase2, int* __restrict__ gcur2){
  __shared__ int s[256];
  int t = threadIdx.x;
  int v = (t < NBKT1) ? gcnt1[t] : 0;
  s[t] = v; __syncthreads();
  for (int off = 1; off < 256; off <<= 1){
    int a = (t >= off) ? s[t - off] : 0;
    __syncthreads(); s[t] += a; __syncthreads();
  }
  if (t < NBKT1){ gbase1[t] = s[t] - v; gcur1[t] = s[t] - v; }
  __syncthreads();
  v = (t < NBKT2) ? gcnt2[t] : 0;
  s[t] = v; __syncthreads();
  for (int off = 1; off < 256; off <<= 1){
    int a = (t >= off) ? s[t - off] : 0;
    __syncthreads(); s[t] += a; __syncthreads();
  }
  if (t < NBKT2){ gbase2[t] = s[t] - v; gcur2[t] = s[t] - v; }
}

// phase 3: scatter packed words into bucket regions (per-block reserved runs)
__launch_bounds__(256)
__global__ void scatter_kernel(const int* __restrict__ ei, const int* __restrict__ cluster,
                               int* __restrict__ gcur1, int* __restrict__ gcur2,
                               unsigned int* __restrict__ stage1, unsigned int* __restrict__ stage2){
  __shared__ int h1c[NBKT1], h2c[NBKT2];
  __shared__ int gb1[NBKT1], gb2[NBKT2];
  int t = threadIdx.x;
  for (int i = t; i < NBKT1; i += 256) h1c[i] = 0;
  for (int i = t; i < NBKT2; i += 256) h2c[i] = 0;
  __syncthreads();
  int e0 = blockIdx.x * EPB;
  #pragma unroll
  for (int i = 0; i < EPB / 256; ++i){
    int e = e0 + i * 256 + t;
    if (e < N_EDGES){
      int dst = ei[N_EDGES + e];
      int cd  = cluster[dst];
      atomicAdd(&h1c[dst >> BKT1_SHIFT], 1);
      atomicAdd(&h2c[cd  >> BKT2_SHIFT], 1);
    }
  }
  __syncthreads();
  for (int i = t; i < NBKT1; i += 256){ int c = h1c[i]; gb1[i] = c ? atomicAdd(&gcur1[i], c) : 0; }
  for (int i = t; i < NBKT2; i += 256){ int c = h2c[i]; gb2[i] = c ? atomicAdd(&gcur2[i], c) : 0; }
  __syncthreads();
  for (int i = t; i < NBKT1; i += 256) h1c[i] = 0;   // reuse as local cursors
  for (int i = t; i < NBKT2; i += 256) h2c[i] = 0;
  __syncthreads();
  #pragma unroll
  for (int i = 0; i < EPB / 256; ++i){
    int e = e0 + i * 256 + t;
    if (e < N_EDGES){
      int src = ei[e], dst = ei[N_EDGES + e];
      int cs = cluster[src], cd = cluster[dst];
      int b1 = dst >> BKT1_SHIFT, b2 = cd >> BKT2_SHIFT;
      int r1 = atomicAdd(&h1c[b1], 1);
      int r2 = atomicAdd(&h2c[b2], 1);
      stage1[gb1[b1] + r1] = ((unsigned)(dst & 511) << 17) | (unsigned)src;
      stage2[gb2[b2] + r2] = ((unsigned)(cd & 127) << 15) | (unsigned)cs;
    }
  }
}

// phase 4: per-bucket LDS counting sort + coalesced degree writes
template<int NBINS, int PSHIFT>
__launch_bounds__(256)
__global__ void bucket_sort(const unsigned int* __restrict__ stage, const int* __restrict__ gbase,
                            const int* __restrict__ gcnt, int* __restrict__ outpay,
                            int* __restrict__ deg, int ntot){
  __shared__ int cnt[NBINS], off[NBINS];
  __shared__ int sorted[SORT_CAP];
  int b = blockIdx.x, t = threadIdx.x;
  int base = gbase[b], n = gcnt[b];
  for (int i = t; i < NBINS; i += 256) cnt[i] = 0;
  __syncthreads();
  for (int i = t; i < n; i += 256) atomicAdd(&cnt[stage[base + i] >> PSHIFT], 1);
  __syncthreads();
  for (int i = t; i < NBINS; i += 256){
    int idx = b * NBINS + i;
    if (idx < ntot) deg[idx] = cnt[i];
    off[i] = cnt[i];
  }
  __syncthreads();
  for (int s = 1; s < NBINS; s <<= 1){
    int v0 = 0, v1 = 0;
    if (t < NBINS && t >= s) v0 = off[t - s];
    if (NBINS > 256 && t + 256 < NBINS && t + 256 >= s) v1 = off[t + 256 - s];
    __syncthreads();
    if (t < NBINS) off[t] += v0;
    if (NBINS > 256 && t + 256 < NBINS) off[t + 256] += v1;
    __syncthreads();
  }
  for (int i = t; i < NBINS; i += 256) off[i] -= cnt[i];   // exclusive cursors
  __syncthreads();
  constexpr unsigned PMASK = (1u << PSHIFT) - 1u;
  if (n <= SORT_CAP){
    for (int i = t; i < n; i += 256){
      unsigned w = stage[base + i];
      int r = atomicAdd(&off[w >> PSHIFT], 1);
      sorted[r] = (int)(w & PMASK);
    }
    __syncthreads();
    for (int i = t; i < n; i += 256) outpay[base + i] = sorted[i];
  } else {
    for (int i = t; i < n; i += 256){
      unsigned w = stage[base + i];
      int r = atomicAdd(&off[w >> PSHIFT], 1);
      outpay[base + r] = (int)(w & PMASK);
    }
  }
}

// cluster membership counts
__global__ void cntn_kernel(const int* __restrict__ cluster, int* __restrict__ cntn){
  int v = blockIdx.x * blockDim.x + threadIdx.x;
  if (v < N_NODES) atomicAdd(&cntn[cluster[v]], 1);
}

// ---------------------------------------------------------------------------
// device-wide 3-segment exclusive scan
// ---------------------------------------------------------------------------
__device__ __forceinline__ void seg_select(int b, const int* deg1, const int* cntn,
                                           const int* deg2, const int*& src, int& n, int& base){
  if (b < NB1){ src = deg1; n = N_NODES; base = b * SCAN_BPB; }
  else if (b < NB1 + NB2){ src = cntn; n = N_CLUST; base = (b - NB1) * SCAN_BPB; }
  else { src = deg2; n = N_CLUST; base = (b - NB1 - NB2) * SCAN_BPB; }
}

__launch_bounds__(256)
__global__ void block_sums(const int* __restrict__ deg1, const int* __restrict__ cntn,
                           const int* __restrict__ deg2, int* __restrict__ bsum){
  int b = blockIdx.x;
  const int* src; int n, base;
  seg_select(b, deg1, cntn, deg2, src, n, base);
  int t = threadIdx.x;
  int i0 = base + t * 4;
  int s = 0;
  if (i0 + 3 < n){ int4 v = *(const int4*)&src[i0]; s = v.x + v.y + v.z + v.w; }
  else { for (int j = 0; j < 4; ++j){ int i = i0 + j; if (i < n) s += src[i]; } }
  __shared__ int sh[256];
  sh[t] = s; __syncthreads();
  for (int off = 128; off > 0; off >>= 1){
    if (t < off) sh[t] += sh[t + off];
    __syncthreads();
  }
  if (t == 0) bsum[b] = sh[0];
}

__launch_bounds__(256)
__global__ void scan_bsums(const int* __restrict__ bsum, int* __restrict__ boff,
                           int* __restrict__ rowptr1, int* __restrict__ rowptrn,
                           int* __restrict__ rowptr2){
  __shared__ int s[256];
  int t = threadIdx.x;
  int v = (t < NBT) ? bsum[t] : 0;
  s[t] = v; __syncthreads();
  int seg = (t < NB1) ? 0 : (t < NB1 + NB2 ? 1 : 2);
  for (int off = 1; off < 256; off <<= 1){
    int add = 0;
    if (t >= off){
      int u = t - off;
      int useg = (u < NB1) ? 0 : (u < NB1 + NB2 ? 1 : 2);
      if (useg == seg) add = s[u];
    }
    __syncthreads();
    s[t] += add;
    __syncthreads();
  }
  if (t < NBT) boff[t] = s[t] - v;
  if (t == NB1 - 1)       rowptr1[N_NODES] = s[t];
  if (t == NB1 + NB2 - 1) rowptrn[N_CLUST] = s[t];
  if (t == NBT - 1)       rowptr2[N_CLUST] = s[t];
}

__launch_bounds__(256)
__global__ void scan_final(const int* __restrict__ deg1, const int* __restrict__ cntn,
                           const int* __restrict__ deg2, const int* __restrict__ boff,
                           int* __restrict__ rowptr1, float* __restrict__ dis1,
                           int* __restrict__ rowptrn, int* __restrict__ curn,
                           int* __restrict__ rowptr2, float* __restrict__ dis2){
  int b = blockIdx.x;
  const int* src; int n, base;
  seg_select(b, deg1, cntn, deg2, src, n, base);
  int* rp; int* cur; float* dis;
  if (b < NB1){ rp = rowptr1; cur = nullptr; dis = dis1; }
  else if (b < NB1 + NB2){ rp = rowptrn; cur = curn; dis = nullptr; }
  else { rp = rowptr2; cur = nullptr; dis = dis2; }
  int t = threadIdx.x;
  int i0 = base + t * 4;
  int v[4]; int s = 0;
  #pragma unroll
  for (int j = 0; j < 4; ++j){ int i = i0 + j; v[j] = (i < n) ? src[i] : 0; s += v[j]; }
  __shared__ int sh[256];
  sh[t] = s; __syncthreads();
  for (int off = 1; off < 256; off <<= 1){
    int add = (t >= off) ? sh[t - off] : 0;
    __syncthreads();
    sh[t] += add;
    __syncthreads();
  }
  int run = sh[t] - s + boff[b];
  #pragma unroll
  for (int j = 0; j < 4; ++j){
    int i = i0 + j;
    if (i < n){
      rp[i] = run;
      if (cur) cur[i] = run;
      if (dis) dis[i] = rsqrtf((float)v[j] + 1.0f);
      run += v[j];
    }
  }
}

// node->cluster CSR fill
__global__ void fill_n(const int* __restrict__ cluster, int* __restrict__ curn,
                       int* __restrict__ nidx){
  int v = blockIdx.x * blockDim.x + threadIdx.x;
  if (v >= N_NODES) return;
  nidx[atomicAdd(&curn[cluster[v]], 1)] = v;
}

// ---------------------------------------------------------------------------
// GEMMs: C[M,128] = (A[M,128] @ B[128,128]) * scale[row], output packed bf16
// ---------------------------------------------------------------------------
__launch_bounds__(256)
__global__ void gemm128_f32(const float* __restrict__ A, const float* __restrict__ B,
                            const float* __restrict__ scale, unsigned* __restrict__ Cmat, int M){
  __shared__ float As[128 * 64];
  __shared__ float Bs[128 * 64];
  const int t = threadIdx.x;
  const int bm = blockIdx.x, bn = blockIdx.y;
  const int row0 = bm * 64;

  #pragma unroll
  for (int i = 0; i < 8; ++i){
    int idx4 = t + i * 256;
    int k = idx4 >> 4, c4 = idx4 & 15;
    float4 v = *(const float4*)&B[k * 128 + bn * 64 + c4 * 4];
    *(float4*)&Bs[k * 64 + c4 * 4] = v;
  }
  {
    int m = t & 63, kb = t >> 6;
    int row = row0 + m; if (row >= M) row = M - 1;
    const float* Arow = A + (size_t)row * 128;
    #pragma unroll
    for (int i = 0; i < 8; ++i){
      int k4 = kb + i * 4;
      float4 v = *(const float4*)&Arow[k4 * 4];
      int k = k4 * 4;
      As[(k + 0) * 64 + m] = v.x;
      As[(k + 1) * 64 + m] = v.y;
      As[(k + 2) * 64 + m] = v.z;
      As[(k + 3) * 64 + m] = v.w;
    }
  }
  __syncthreads();

  const int tx = t & 15, ty = t >> 4;
  float acc[4][4] = {};
  #pragma unroll 4
  for (int k = 0; k < 128; ++k){
    float a[4], b[4];
    *(float4*)a = *(const float4*)&As[k * 64 + (ty << 2)];
    *(float4*)b = *(const float4*)&Bs[k * 64 + (tx << 2)];
    #pragma unroll
    for (int i = 0; i < 4; ++i)
      #pragma unroll
      for (int j = 0; j < 4; ++j)
        acc[i][j] = fmaf(a[i], b[j], acc[i][j]);
  }
  #pragma unroll
  for (int i = 0; i < 4; ++i){
    int row = row0 + (ty << 2) + i;
    if (row < M){
      float sc = scale[row];
      uint2 o;
      o.x = pack2(acc[i][0] * sc, acc[i][1] * sc);
      o.y = pack2(acc[i][2] * sc, acc[i][3] * sc);
      *(uint2*)&Cmat[(size_t)row * 64 + bn * 32 + tx * 2] = o;
    }
  }
}

__launch_bounds__(256)
__global__ void gemm128_bf16(const unsigned* __restrict__ A, const float* __restrict__ B,
                             const float* __restrict__ scale, unsigned* __restrict__ Cmat, int M){
  __shared__ float As[128 * 64];
  __shared__ float Bs[128 * 64];
  const int t = threadIdx.x;
  const int bm = blockIdx.x, bn = blockIdx.y;
  const int row0 = bm * 64;

  #pragma unroll
  for (int i = 0; i < 8; ++i){
    int idx4 = t + i * 256;
    int k = idx4 >> 4, c4 = idx4 & 15;
    float4 v = *(const float4*)&B[k * 128 + bn * 64 + c4 * 4];
    *(float4*)&Bs[k * 64 + c4 * 4] = v;
  }
  {
    int m = t & 63, kb = t >> 6;
    int row = row0 + m; if (row >= M) row = M - 1;
    const unsigned* Arow = A + (size_t)row * 64;
    #pragma unroll
    for (int i = 0; i < 8; ++i){
      int k4 = kb + i * 4;
      uint2 v = *(const uint2*)&Arow[k4 * 2];
      int k = k4 * 4;
      As[(k + 0) * 64 + m] = bf16lo(v.x);
      As[(k + 1) * 64 + m] = bf16hi(v.x);
      As[(k + 2) * 64 + m] = bf16lo(v.y);
      As[(k + 3) * 64 + m] = bf16hi(v.y);
    }
  }
  __syncthreads();

  const int tx = t & 15, ty = t >> 4;
  float acc[4][4] = {};
  #pragma unroll 4
  for (int k = 0; k < 128; ++k){
    float a[4], b[4];
    *(float4*)a = *(const float4*)&As[k * 64 + (ty << 2)];
    *(float4*)b = *(const float4*)&Bs[k * 64 + (tx << 2)];
    #pragma unroll
    for (int i = 0; i < 4; ++i)
      #pragma unroll
      for (int j = 0; j < 4; ++j)
        acc[i][j] = fmaf(a[i], b[j], acc[i][j]);
  }
  #pragma unroll
  for (int i = 0; i < 4; ++i){
    int row = row0 + (ty << 2) + i;
    if (row < M){
      float sc = scale[row];
      uint2 o;
      o.x = pack2(acc[i][0] * sc, acc[i][1] * sc);
      o.y = pack2(acc[i][2] * sc, acc[i][3] * sc);
      *(uint2*)&Cmat[(size_t)row * 64 + bn * 32 + tx * 2] = o;
    }
  }
}

// ---------------------------------------------------------------------------
// CSR conv over bf16 rows: out[i] = relu( dis[i]*(sum_e Ts[src_e] + Ts[i]) + b )
// one wave per row; lane l owns feature pair (2l, 2l+1)
// ---------------------------------------------------------------------------
__launch_bounds__(256)
__global__ void conv_csr(const unsigned* __restrict__ Ts, const float* __restrict__ dis,
                         const int* __restrict__ rowptr, const int* __restrict__ esrc,
                         const float* __restrict__ bias, unsigned* __restrict__ Hout){
  int w = blockIdx.x * 4 + (threadIdx.x >> 6);
  int l = threadIdx.x & 63;
  int beg = rowptr[w], end = rowptr[w + 1];
  float2 a0{0.f,0.f}, a1{0.f,0.f}, a2{0.f,0.f}, a3{0.f,0.f};
  for (int base = beg; base < end; base += 64){
    int n = min(64, end - base);
    int eid = esrc[base + min(l, n - 1)];
    int j = 0;
    for (; j + 4 <= n; j += 4){
      int s0 = __shfl(eid, j);
      int s1 = __shfl(eid, j + 1);
      int s2 = __shfl(eid, j + 2);
      int s3 = __shfl(eid, j + 3);
      unsigned u0 = Ts[(size_t)s0 * 64 + l];
      unsigned u1 = Ts[(size_t)s1 * 64 + l];
      unsigned u2 = Ts[(size_t)s2 * 64 + l];
      unsigned u3 = Ts[(size_t)s3 * 64 + l];
      a0.x += bf16lo(u0); a0.y += bf16hi(u0);
      a1.x += bf16lo(u1); a1.y += bf16hi(u1);
      a2.x += bf16lo(u2); a2.y += bf16hi(u2);
      a3.x += bf16lo(u3); a3.y += bf16hi(u3);
    }
    for (; j < n; ++j){
      int s = __shfl(eid, j);
      unsigned u = Ts[(size_t)s * 64 + l];
      a0.x += bf16lo(u); a0.y += bf16hi(u);
    }
  }
  float d = dis[w];
  unsigned us = Ts[(size_t)w * 64 + l];
  float2 bb = *(const float2*)&bias[l * 2];
  float rx = fmaxf(fmaf(d, a0.x + a1.x + a2.x + a3.x + bf16lo(us), bb.x), 0.f);
  float ry = fmaxf(fmaf(d, a0.y + a1.y + a2.y + a3.y + bf16hi(us), bb.y), 0.f);
  Hout[(size_t)w * 64 + l] = pack2(rx, ry);
}

// cluster mean pool + batch_p over bf16 rows
__launch_bounds__(256)
__global__ void cluster_gather(const unsigned* __restrict__ h1, const int* __restrict__ rowptrn,
                               const int* __restrict__ nidx, const int* __restrict__ batch,
                               unsigned* __restrict__ hp, int* __restrict__ batchp){
  int c = blockIdx.x * 4 + (threadIdx.x >> 6);
  int l = threadIdx.x & 63;
  int mb = rowptrn[c], me = rowptrn[c + 1];
  float2 a0{0.f,0.f}, a1{0.f,0.f}, a2{0.f,0.f}, a3{0.f,0.f};
  int vmax = -1;
  for (int base = mb; base < me; base += 64){
    int n = min(64, me - base);
    int vid = nidx[base + min(l, n - 1)];
    if (l < n) vmax = max(vmax, vid);
    int j = 0;
    for (; j + 4 <= n; j += 4){
      int s0 = __shfl(vid, j);
      int s1 = __shfl(vid, j + 1);
      int s2 = __shfl(vid, j + 2);
      int s3 = __shfl(vid, j + 3);
      unsigned u0 = h1[(size_t)s0 * 64 + l];
      unsigned u1 = h1[(size_t)s1 * 64 + l];
      unsigned u2 = h1[(size_t)s2 * 64 + l];
      unsigned u3 = h1[(size_t)s3 * 64 + l];
      a0.x += bf16lo(u0); a0.y += bf16hi(u0);
      a1.x += bf16lo(u1); a1.y += bf16hi(u1);
      a2.x += bf16lo(u2); a2.y += bf16hi(u2);
      a3.x += bf16lo(u3); a3.y += bf16hi(u3);
    }
    for (; j < n; ++j){
      int s = __shfl(vid, j);
      unsigned u = h1[(size_t)s * 64 + l];
      a0.x += bf16lo(u); a0.y += bf16hi(u);
    }
  }
  #pragma unroll
  for (int off = 32; off > 0; off >>= 1) vmax = max(vmax, __shfl_xor(vmax, off));
  float inv = 1.0f / (float)max(me - mb, 1);
  float ox = (a0.x + a1.x + a2.x + a3.x) * inv;
  float oy = (a0.y + a1.y + a2.y + a3.y) * inv;
  hp[(size_t)c * 64 + l] = pack2(ox, oy);
  if (l == 0) batchp[c] = (vmax >= 0) ? batch[vmax] : 0;  // batch sorted by node id
}

__global__ void cntp_kernel(const int* __restrict__ batchp, int* __restrict__ cntp){
  int c = blockIdx.x * blockDim.x + threadIdx.x;
  if (c < N_CLUST) atomicAdd(&cntp[batchp[c]], 1);
}

// ---------------------------------------------------------------------------
__global__ void graph_bounds(const int* __restrict__ batch, int* __restrict__ gstart){
  int g = threadIdx.x;
  if (g > N_GRAPH) return;
  int lo = 0, hi = N_NODES;
  while (lo < hi){ int mid = (lo + hi) >> 1; if (batch[mid] < g) lo = mid + 1; else hi = mid; }
  gstart[g] = lo;
}

__device__ __forceinline__ void atomicMaxPosF(float* addr, float v){
  atomicMax((int*)addr, __float_as_int(v));
}

constexpr int PRE_CHUNK = 100;
__launch_bounds__(64)
__global__ void pre_pool(const unsigned* __restrict__ h1, const int* __restrict__ batch,
                         float* __restrict__ psum, float* __restrict__ pmax){
  int f  = threadIdx.x;              // feature pair 2f, 2f+1
  int i0 = blockIdx.x * PRE_CHUNK;
  int i1 = min(i0 + PRE_CHUNK, N_NODES);
  int g = batch[i0];
  float s0 = 0.f, s1 = 0.f, m0 = 0.f, m1 = 0.f;
  for (int i = i0; i < i1; ++i){
    int gb = batch[i];
    if (gb != g){
      atomicAdd(&psum[g * 128 + 2 * f], s0);
      atomicAdd(&psum[g * 128 + 2 * f + 1], s1);
      atomicMaxPosF(&pmax[g * 128 + 2 * f], m0);
      atomicMaxPosF(&pmax[g * 128 + 2 * f + 1], m1);
      g = gb; s0 = s1 = m0 = m1 = 0.f;
    }
    unsigned u = h1[(size_t)i * 64 + f];
    float v0 = bf16lo(u), v1 = bf16hi(u);
    s0 += v0; s1 += v1; m0 = fmaxf(m0, v0); m1 = fmaxf(m1, v1);
  }
  atomicAdd(&psum[g * 128 + 2 * f], s0);
  atomicAdd(&psum[g * 128 + 2 * f + 1], s1);
  atomicMaxPosF(&pmax[g * 128 + 2 * f], m0);
  atomicMaxPosF(&pmax[g * 128 + 2 * f + 1], m1);
}

__launch_bounds__(64)
__global__ void post_pool(const unsigned* __restrict__ hp3, const int* __restrict__ batchp,
                          float* __restrict__ psum, float* __restrict__ pmax){
  int c = blockIdx.x, f = threadIdx.x;
  int g = batchp[c];
  unsigned u = hp3[(size_t)c * 64 + f];
  float v0 = bf16lo(u), v1 = bf16hi(u);
  atomicAdd(&psum[g * 128 + 2 * f], v0);
  atomicAdd(&psum[g * 128 + 2 * f + 1], v1);
  atomicMaxPosF(&pmax[g * 128 + 2 * f], v0);
  atomicMaxPosF(&pmax[g * 128 + 2 * f + 1], v1);
}

__launch_bounds__(128)
__global__ void head_kernel(const float* __restrict__ psum, const float* __restrict__ pmax,
                            const float* __restrict__ postsum, const float* __restrict__ postmax,
                            const int* __restrict__ gstart, const int* __restrict__ cntp,
                            const float* __restrict__ l1w, const float* __restrict__ l1b,
                            const float* __restrict__ l2w, const float* __restrict__ l2b,
                            float* __restrict__ out){
  int g = blockIdx.x, t = threadIdx.x;
  __shared__ float z[512];
  __shared__ float a[128];
  __shared__ float logits[16];
  __shared__ float lse_s;
  float cpre  = (float)max(gstart[g + 1] - gstart[g], 1);
  float cpost = fmaxf((float)cntp[g], 1.0f);
  z[t]       = psum[g * 128 + t] / cpre;
  z[128 + t] = pmax[g * 128 + t];
  z[256 + t] = postsum[g * 128 + t] / cpost;
  z[384 + t] = postmax[g * 128 + t];
  __syncthreads();
  float acc = l1b[t];
  #pragma unroll 8
  for (int k = 0; k < 512; ++k) acc = fmaf(z[k], l1w[k * 128 + t], acc);
  a[t] = fmaxf(acc, 0.f);
  __syncthreads();
  if (t < NCLSN){
    float s2 = l2b[t];
    for (int k = 0; k < 128; ++k) s2 = fmaf(a[k], l2w[k * NCLSN + t], s2);
    logits[t] = s2;
  }
  __syncthreads();
  if (t == 0){
    float m = logits[0];
    for (int c = 1; c < NCLSN; ++c) m = fmaxf(m, logits[c]);
    float s = 0.f;
    for (int c = 0; c < NCLSN; ++c) s += expf(logits[c] - m);
    lse_s = m + logf(s);
  }
  __syncthreads();
  if (t < NCLSN) out[g * NCLSN + t] = logits[t] - lse_s;
}

// ---------------------------------------------------------------------------
extern "C" void kernel_launch(void* const* d_in, const int* in_sizes, int n_in,
                              void* d_out, int out_size, void* d_ws, size_t ws_size,
                              hipStream_t stream){
  const float* x       = (const float*)d_in[0];
  const int*   ei      = (const int*)  d_in[1];
  const int*   batch   = (const int*)  d_in[2];
  const int*   cluster = (const int*)  d_in[3];
  const float* W1      = (const float*)d_in[6];
  const float* b1      = (const float*)d_in[7];
  const float* W2      = (const float*)d_in[8];
  const float* b2      = (const float*)d_in[9];
  const float* W3      = (const float*)d_in[10];
  const float* b3      = (const float*)d_in[11];
  const float* l1w     = (const float*)d_in[12];
  const float* l1b     = (const float*)d_in[13];
  const float* l2w     = (const float*)d_in[14];
  const float* l2b     = (const float*)d_in[15];
  float* out = (float*)d_out;

  char* base = (char*)d_ws;
  size_t off = 0;
  auto alloc = [&](size_t bytes) -> char* {
    char* p = base + off;
    off += (bytes + 255) & ~size_t(255);
    return p;
  };
  // ---- zero zone (one memset) ----
  char*  zbase  = base + off;
  int*   gcnt1  = (int*)  alloc((size_t)NBKT1 * 4);
  int*   gcnt2  = (int*)  alloc((size_t)NBKT2 * 4);
  int*   cntn   = (int*)  alloc((size_t)N_CLUST * 4);
  int*   cntp   = (int*)  alloc((size_t)N_GRAPH * 4);
  float* pre_s  = (float*)alloc((size_t)N_GRAPH * 128 * 4);
  float* pre_m  = (float*)alloc((size_t)N_GRAPH * 128 * 4);
  float* post_s = (float*)alloc((size_t)N_GRAPH * 128 * 4);
  float* post_m = (float*)alloc((size_t)N_GRAPH * 128 * 4);
  size_t zsize = off;
  // ---- plain buffers (bf16 feature rows: 64 uints per row) ----
  unsigned* Ts1   = (unsigned*)alloc((size_t)N_NODES * 64 * 4);  // later aliased
  unsigned* h1    = (unsigned*)alloc((size_t)N_NODES * 64 * 4);  // stage bufs alias here
  int*   esrc1   = (int*)  alloc((size_t)N_EDGES * 4);
  int*   psrcC   = (int*)  alloc((size_t)N_EDGES * 4);
  int*   deg1    = (int*)  alloc((size_t)N_NODES * 4);
  int*   deg2    = (int*)  alloc((size_t)N_CLUST * 4);
  int*   rowptr1 = (int*)  alloc((size_t)(N_NODES + 1) * 4);
  int*   rowptrn = (int*)  alloc((size_t)(N_CLUST + 1) * 4);
  int*   curn    = (int*)  alloc((size_t)N_CLUST * 4);
  int*   rowptr2 = (int*)  alloc((size_t)(N_CLUST + 1) * 4);
  int*   nidx    = (int*)  alloc((size_t)N_NODES * 4);
  float* dis1    = (float*)alloc((size_t)N_NODES * 4);
  float* dis2    = (float*)alloc((size_t)N_CLUST * 4);
  int*   batchp  = (int*)  alloc((size_t)N_CLUST * 4);
  int*   gstart  = (int*)  alloc((size_t)(N_GRAPH + 1) * 4);
  int*   bsum    = (int*)  alloc((size_t)NBT * 4);
  int*   boff    = (int*)  alloc((size_t)NBT * 4);
  int*   gbase1  = (int*)  alloc((size_t)NBKT1 * 4);
  int*   gcur1   = (int*)  alloc((size_t)NBKT1 * 4);
  int*   gbase2  = (int*)  alloc((size_t)NBKT2 * 4);
  int*   gcur2   = (int*)  alloc((size_t)NBKT2 * 4);
  // stage buffers alias the (not-yet-written) h1 region (12.8 MB <= 25.6 MB)
  unsigned int* stage1 = (unsigned int*)h1;
  unsigned int* stage2 = stage1 + N_EDGES;
  // aliases into Ts1 (dead after conv1): 4 x 25000*64 uints = exactly Ts1 size
  unsigned* hp  = Ts1;
  unsigned* Ts2 = Ts1 + (size_t)N_CLUST * 64;
  unsigned* hp2 = Ts1 + (size_t)2 * N_CLUST * 64;
  unsigned* hp3 = Ts1 + (size_t)3 * N_CLUST * 64;
  unsigned* Ts3 = Ts2;

  (void)in_sizes; (void)n_in; (void)out_size; (void)ws_size;

  hipMemsetAsync(zbase, 0, zsize, stream);

  // ---- sort-based CSR build ----
  count_kernel  <<<NEB, 256, 0, stream>>>(ei, cluster, gcnt1, gcnt2);
  cntn_kernel   <<<(N_NODES + 255) / 256, 256, 0, stream>>>(cluster, cntn);
  bucket_scan   <<<1, 256, 0, stream>>>(gcnt1, gcnt2, gbase1, gcur1, gbase2, gcur2);
  scatter_kernel<<<NEB, 256, 0, stream>>>(ei, cluster, gcur1, gcur2, stage1, stage2);
  bucket_sort<512, 17><<<NBKT1, 256, 0, stream>>>(stage1, gbase1, gcnt1, esrc1, deg1, N_NODES);
  bucket_sort<128, 15><<<NBKT2, 256, 0, stream>>>(stage2, gbase2, gcnt2, psrcC, deg2, N_CLUST);
  block_sums <<<NBT, 256, 0, stream>>>(deg1, cntn, deg2, bsum);
  scan_bsums <<<1, 256, 0, stream>>>(bsum, boff, rowptr1, rowptrn, rowptr2);
  scan_final <<<NBT, 256, 0, stream>>>(deg1, cntn, deg2, boff,
                                       rowptr1, dis1, rowptrn, curn, rowptr2, dis2);
  fill_n<<<(N_NODES + 255) / 256, 256, 0, stream>>>(cluster, curn, nidx);

  // conv1
  gemm128_f32<<<dim3((N_NODES + 63) / 64, 2), 256, 0, stream>>>(x, W1, dis1, Ts1, N_NODES);
  conv_csr<<<N_NODES / 4, 256, 0, stream>>>(Ts1, dis1, rowptr1, esrc1, b1, h1);

  // pre pools
  graph_bounds<<<1, 128, 0, stream>>>(batch, gstart);
  pre_pool<<<(N_NODES + PRE_CHUNK - 1) / PRE_CHUNK, 64, 0, stream>>>(h1, batch, pre_s, pre_m);

  // cluster mean pool + batch_p + cntp
  cluster_gather<<<N_CLUST / 4, 256, 0, stream>>>(h1, rowptrn, nidx, batch, hp, batchp);
  cntp_kernel<<<(N_CLUST + 255) / 256, 256, 0, stream>>>(batchp, cntp);

  // conv2
  gemm128_bf16<<<dim3((N_CLUST + 63) / 64, 2), 256, 0, stream>>>(hp, W2, dis2, Ts2, N_CLUST);
  conv_csr<<<N_CLUST / 4, 256, 0, stream>>>(Ts2, dis2, rowptr2, psrcC, b2, hp2);

  // conv3
  gemm128_bf16<<<dim3((N_CLUST + 63) / 64, 2), 256, 0, stream>>>(hp2, W3, dis2, Ts3, N_CLUST);
  conv_csr<<<N_CLUST / 4, 256, 0, stream>>>(Ts3, dis2, rowptr2, psrcC, b3, hp3);

  // post pools + head
  post_pool<<<N_CLUST, 64, 0, stream>>>(hp3, batchp, post_s, post_m);
  head_kernel<<<N_GRAPH, 128, 0, stream>>>(pre_s, pre_m, post_s, post_m, gstart, cntp,
                                           l1w, l1b, l2w, l2b, out);
}

// Round 7
// 689.686 us; speedup vs baseline: 2.4032x; 1.1069x over previous
//
#include <hip/hip_runtime.h>

constexpr int N_NODES = 100000;
constexpr int N_EDGES = 1600000;
constexpr int N_CLUST = 25000;
constexpr int N_GRAPH = 64;
constexpr int NCLSN   = 10;

// bucket decomposition for the sort-based CSR builds
constexpr int BKT1_SHIFT = 9;                       // node-dst buckets of 512 ids
constexpr int NBKT1 = (N_NODES + 511) / 512;        // 196
constexpr int BKT2_SHIFT = 7;                       // cluster-dst buckets of 128 ids
constexpr int NBKT2 = (N_CLUST + 127) / 128;        // 196
constexpr int EPB = 4096;                           // edges per block (count/scatter)
constexpr int NEB = (N_EDGES + EPB - 1) / EPB;      // 391
constexpr int SORT_CAP = 12288;                     // LDS staging cap (mean 8163, sd ~90)

// scan partitioning: 1024 elements per block, three concatenated segments
constexpr int SCAN_BPB = 1024;
constexpr int NB1 = (N_NODES + SCAN_BPB - 1) / SCAN_BPB;  // 98
constexpr int NB2 = (N_CLUST + SCAN_BPB - 1) / SCAN_BPB;  // 25
constexpr int NB3 = (N_CLUST + SCAN_BPB - 1) / SCAN_BPB;  // 25
constexpr int NBT = NB1 + NB2 + NB3;                      // 148

// ---- bf16 pack/unpack helpers (features stored as packed pairs in uint) ----
__device__ __forceinline__ float bf16lo(unsigned u){ return __uint_as_float(u << 16); }
__device__ __forceinline__ float bf16hi(unsigned u){ return __uint_as_float(u & 0xffff0000u); }
__device__ __forceinline__ unsigned bf16_rne(float f){
  unsigned u = __float_as_uint(f);
  return (u + 0x7fffu + ((u >> 16) & 1u)) >> 16;
}
__device__ __forceinline__ unsigned pack2(float lo, float hi){
  return bf16_rne(lo) | (bf16_rne(hi) << 16);
}

// ---------------------------------------------------------------------------
// bucket-sort CSR build, phase 1: LDS-aggregated bucket counts
// ---------------------------------------------------------------------------
__launch_bounds__(256)
__global__ void count_kernel(const int* __restrict__ ei, const int* __restrict__ cluster,
                             int* __restrict__ gcnt1, int* __restrict__ gcnt2){
  __shared__ int h1c[NBKT1], h2c[NBKT2];
  int t = threadIdx.x;
  for (int i = t; i < NBKT1; i += 256) h1c[i] = 0;
  for (int i = t; i < NBKT2; i += 256) h2c[i] = 0;
  __syncthreads();
  int e0 = blockIdx.x * EPB;
  #pragma unroll
  for (int i = 0; i < EPB / 256; ++i){
    int e = e0 + i * 256 + t;
    if (e < N_EDGES){
      int dst = ei[N_EDGES + e];
      int cd  = cluster[dst];
      atomicAdd(&h1c[dst >> BKT1_SHIFT], 1);
      atomicAdd(&h2c[cd  >> BKT2_SHIFT], 1);
    }
  }
  __syncthreads();
  for (int i = t; i < NBKT1; i += 256) if (h1c[i]) atomicAdd(&gcnt1[i], h1c[i]);
  for (int i = t; i < NBKT2; i += 256) if (h2c[i]) atomicAdd(&gcnt2[i], h2c[i]);
}

// phase 2: bucket bases
__launch_bounds__(256)
__global__ void bucket_scan(const int* __restrict__ gcnt1, const int* __restrict__ gcnt2,
                            int* __restrict__ gbase1, int* __restrict__ gcur1,
                            int* __restrict__ gbase2, int* __restrict__ gcur2){
  __shared__ int s[256];
  int t = threadIdx.x;
  int v = (t < NBKT1) ? gcnt1[t] : 0;
  s[t] = v; __syncthreads();
  for (int off = 1; off < 256; off <<= 1){
    int a = (t >= off) ? s[t - off] : 0;
    __syncthreads(); s[t] += a; __syncthreads();
  }
  if (t < NBKT1){ gbase1[t] = s[t] - v; gcur1[t] = s[t] - v; }
  __syncthreads();
  v = (t < NBKT2) ? gcnt2[t] : 0;
  s[t] = v; __syncthreads();
  for (int off = 1; off < 256; off <<= 1){
    int a = (t >= off) ? s[t - off] : 0;
    __syncthreads(); s[t] += a; __syncthreads();
  }
  if (t < NBKT2){ gbase2[t] = s[t] - v; gcur2[t] = s[t] - v; }
}

// phase 3: scatter packed words into bucket regions (per-block reserved runs)
__launch_bounds__(256)
__global__ void scatter_kernel(const int* __restrict__ ei, const int* __restrict__ cluster,
                               int* __restrict__ gcur1, int* __restrict__ gcur2,
                               unsigned int* __restrict__ stage1, unsigned int* __restrict__ stage2){
  __shared__ int h1c[NBKT1], h2c[NBKT2];
  __shared__ int gb1[NBKT1], gb2[NBKT2];
  int t = threadIdx.x;
  for (int i = t; i < NBKT1; i += 256) h1c[i] = 0;
  for (int i = t; i < NBKT2; i += 256) h2c[i] = 0;
  __syncthreads();
  int e0 = blockIdx.x * EPB;
  #pragma unroll
  for (int i = 0; i < EPB / 256; ++i){
    int e = e0 + i * 256 + t;
    if (e < N_EDGES){
      int dst = ei[N_EDGES + e];
      int cd  = cluster[dst];
      atomicAdd(&h1c[dst >> BKT1_SHIFT], 1);
      atomicAdd(&h2c[cd  >> BKT2_SHIFT], 1);
    }
  }
  __syncthreads();
  for (int i = t; i < NBKT1; i += 256){ int c = h1c[i]; gb1[i] = c ? atomicAdd(&gcur1[i], c) : 0; }
  for (int i = t; i < NBKT2; i += 256){ int c = h2c[i]; gb2[i] = c ? atomicAdd(&gcur2[i], c) : 0; }
  __syncthreads();
  for (int i = t; i < NBKT1; i += 256) h1c[i] = 0;   // reuse as local cursors
  for (int i = t; i < NBKT2; i += 256) h2c[i] = 0;
  __syncthreads();
  #pragma unroll
  for (int i = 0; i < EPB / 256; ++i){
    int e = e0 + i * 256 + t;
    if (e < N_EDGES){
      int src = ei[e], dst = ei[N_EDGES + e];
      int cs = cluster[src], cd = cluster[dst];
      int b1 = dst >> BKT1_SHIFT, b2 = cd >> BKT2_SHIFT;
      int r1 = atomicAdd(&h1c[b1], 1);
      int r2 = atomicAdd(&h2c[b2], 1);
      stage1[gb1[b1] + r1] = ((unsigned)(dst & 511) << 17) | (unsigned)src;
      stage2[gb2[b2] + r2] = ((unsigned)(cd & 127) << 15) | (unsigned)cs;
    }
  }
}

// phase 4: per-bucket LDS counting sort + coalesced degree writes
template<int NBINS, int PSHIFT>
__launch_bounds__(256)
__global__ void bucket_sort(const unsigned int* __restrict__ stage, const int* __restrict__ gbase,
                            const int* __restrict__ gcnt, int* __restrict__ outpay,
                            int* __restrict__ deg, int ntot){
  __shared__ int cnt[NBINS], off[NBINS];
  __shared__ int sorted[SORT_CAP];
  int b = blockIdx.x, t = threadIdx.x;
  int base = gbase[b], n = gcnt[b];
  for (int i = t; i < NBINS; i += 256) cnt[i] = 0;
  __syncthreads();
  for (int i = t; i < n; i += 256) atomicAdd(&cnt[stage[base + i] >> PSHIFT], 1);
  __syncthreads();
  for (int i = t; i < NBINS; i += 256){
    int idx = b * NBINS + i;
    if (idx < ntot) deg[idx] = cnt[i];
    off[i] = cnt[i];
  }
  __syncthreads();
  for (int s = 1; s < NBINS; s <<= 1){
    int v0 = 0, v1 = 0;
    if (t < NBINS && t >= s) v0 = off[t - s];
    if (NBINS > 256 && t + 256 < NBINS && t + 256 >= s) v1 = off[t + 256 - s];
    __syncthreads();
    if (t < NBINS) off[t] += v0;
    if (NBINS > 256 && t + 256 < NBINS) off[t + 256] += v1;
    __syncthreads();
  }
  for (int i = t; i < NBINS; i += 256) off[i] -= cnt[i];   // exclusive cursors
  __syncthreads();
  constexpr unsigned PMASK = (1u << PSHIFT) - 1u;
  if (n <= SORT_CAP){
    for (int i = t; i < n; i += 256){
      unsigned w = stage[base + i];
      int r = atomicAdd(&off[w >> PSHIFT], 1);
      sorted[r] = (int)(w & PMASK);
    }
    __syncthreads();
    for (int i = t; i < n; i += 256) outpay[base + i] = sorted[i];
  } else {
    for (int i = t; i < n; i += 256){
      unsigned w = stage[base + i];
      int r = atomicAdd(&off[w >> PSHIFT], 1);
      outpay[base + r] = (int)(w & PMASK);
    }
  }
}

// cluster membership counts
__global__ void cntn_kernel(const int* __restrict__ cluster, int* __restrict__ cntn){
  int v = blockIdx.x * blockDim.x + threadIdx.x;
  if (v < N_NODES) atomicAdd(&cntn[cluster[v]], 1);
}

// ---------------------------------------------------------------------------
// device-wide 3-segment exclusive scan
// ---------------------------------------------------------------------------
__device__ __forceinline__ void seg_select(int b, const int* deg1, const int* cntn,
                                           const int* deg2, const int*& src, int& n, int& base){
  if (b < NB1){ src = deg1; n = N_NODES; base = b * SCAN_BPB; }
  else if (b < NB1 + NB2){ src = cntn; n = N_CLUST; base = (b - NB1) * SCAN_BPB; }
  else { src = deg2; n = N_CLUST; base = (b - NB1 - NB2) * SCAN_BPB; }
}

__launch_bounds__(256)
__global__ void block_sums(const int* __restrict__ deg1, const int* __restrict__ cntn,
                           const int* __restrict__ deg2, int* __restrict__ bsum){
  int b = blockIdx.x;
  const int* src; int n, base;
  seg_select(b, deg1, cntn, deg2, src, n, base);
  int t = threadIdx.x;
  int i0 = base + t * 4;
  int s = 0;
  if (i0 + 3 < n){ int4 v = *(const int4*)&src[i0]; s = v.x + v.y + v.z + v.w; }
  else { for (int j = 0; j < 4; ++j){ int i = i0 + j; if (i < n) s += src[i]; } }
  __shared__ int sh[256];
  sh[t] = s; __syncthreads();
  for (int off = 128; off > 0; off >>= 1){
    if (t < off) sh[t] += sh[t + off];
    __syncthreads();
  }
  if (t == 0) bsum[b] = sh[0];
}

__launch_bounds__(256)
__global__ void scan_bsums(const int* __restrict__ bsum, int* __restrict__ boff,
                           int* __restrict__ rowptr1, int* __restrict__ rowptrn,
                           int* __restrict__ rowptr2){
  __shared__ int s[256];
  int t = threadIdx.x;
  int v = (t < NBT) ? bsum[t] : 0;
  s[t] = v; __syncthreads();
  int seg = (t < NB1) ? 0 : (t < NB1 + NB2 ? 1 : 2);
  for (int off = 1; off < 256; off <<= 1){
    int add = 0;
    if (t >= off){
      int u = t - off;
      int useg = (u < NB1) ? 0 : (u < NB1 + NB2 ? 1 : 2);
      if (useg == seg) add = s[u];
    }
    __syncthreads();
    s[t] += add;
    __syncthreads();
  }
  if (t < NBT) boff[t] = s[t] - v;
  if (t == NB1 - 1)       rowptr1[N_NODES] = s[t];
  if (t == NB1 + NB2 - 1) rowptrn[N_CLUST] = s[t];
  if (t == NBT - 1)       rowptr2[N_CLUST] = s[t];
}

__launch_bounds__(256)
__global__ void scan_final(const int* __restrict__ deg1, const int* __restrict__ cntn,
                           const int* __restrict__ deg2, const int* __restrict__ boff,
                           int* __restrict__ rowptr1, float* __restrict__ dis1,
                           int* __restrict__ rowptrn, int* __restrict__ curn,
                           int* __restrict__ rowptr2, float* __restrict__ dis2){
  int b = blockIdx.x;
  const int* src; int n, base;
  seg_select(b, deg1, cntn, deg2, src, n, base);
  int* rp; int* cur; float* dis;
  if (b < NB1){ rp = rowptr1; cur = nullptr; dis = dis1; }
  else if (b < NB1 + NB2){ rp = rowptrn; cur = curn; dis = nullptr; }
  else { rp = rowptr2; cur = nullptr; dis = dis2; }
  int t = threadIdx.x;
  int i0 = base + t * 4;
  int v[4]; int s = 0;
  #pragma unroll
  for (int j = 0; j < 4; ++j){ int i = i0 + j; v[j] = (i < n) ? src[i] : 0; s += v[j]; }
  __shared__ int sh[256];
  sh[t] = s; __syncthreads();
  for (int off = 1; off < 256; off <<= 1){
    int add = (t >= off) ? sh[t - off] : 0;
    __syncthreads();
    sh[t] += add;
    __syncthreads();
  }
  int run = sh[t] - s + boff[b];
  #pragma unroll
  for (int j = 0; j < 4; ++j){
    int i = i0 + j;
    if (i < n){
      rp[i] = run;
      if (cur) cur[i] = run;
      if (dis) dis[i] = rsqrtf((float)v[j] + 1.0f);
      run += v[j];
    }
  }
}

// node->cluster CSR fill
__global__ void fill_n(const int* __restrict__ cluster, int* __restrict__ curn,
                       int* __restrict__ nidx){
  int v = blockIdx.x * blockDim.x + threadIdx.x;
  if (v >= N_NODES) return;
  nidx[atomicAdd(&curn[cluster[v]], 1)] = v;
}

// ---------------------------------------------------------------------------
// GEMMs: C[M,128] = (A[M,128] @ B[128,128]) * scale[row], output packed bf16
// ---------------------------------------------------------------------------
__launch_bounds__(256)
__global__ void gemm128_f32(const float* __restrict__ A, const float* __restrict__ B,
                            const float* __restrict__ scale, unsigned* __restrict__ Cmat, int M){
  __shared__ float As[128 * 64];
  __shared__ float Bs[128 * 64];
  const int t = threadIdx.x;
  const int bm = blockIdx.x, bn = blockIdx.y;
  const int row0 = bm * 64;

  #pragma unroll
  for (int i = 0; i < 8; ++i){
    int idx4 = t + i * 256;
    int k = idx4 >> 4, c4 = idx4 & 15;
    float4 v = *(const float4*)&B[k * 128 + bn * 64 + c4 * 4];
    *(float4*)&Bs[k * 64 + c4 * 4] = v;
  }
  {
    int m = t & 63, kb = t >> 6;
    int row = row0 + m; if (row >= M) row = M - 1;
    const float* Arow = A + (size_t)row * 128;
    #pragma unroll
    for (int i = 0; i < 8; ++i){
      int k4 = kb + i * 4;
      float4 v = *(const float4*)&Arow[k4 * 4];
      int k = k4 * 4;
      As[(k + 0) * 64 + m] = v.x;
      As[(k + 1) * 64 + m] = v.y;
      As[(k + 2) * 64 + m] = v.z;
      As[(k + 3) * 64 + m] = v.w;
    }
  }
  __syncthreads();

  const int tx = t & 15, ty = t >> 4;
  float acc[4][4] = {};
  #pragma unroll 4
  for (int k = 0; k < 128; ++k){
    float a[4], b[4];
    *(float4*)a = *(const float4*)&As[k * 64 + (ty << 2)];
    *(float4*)b = *(const float4*)&Bs[k * 64 + (tx << 2)];
    #pragma unroll
    for (int i = 0; i < 4; ++i)
      #pragma unroll
      for (int j = 0; j < 4; ++j)
        acc[i][j] = fmaf(a[i], b[j], acc[i][j]);
  }
  #pragma unroll
  for (int i = 0; i < 4; ++i){
    int row = row0 + (ty << 2) + i;
    if (row < M){
      float sc = scale[row];
      uint2 o;
      o.x = pack2(acc[i][0] * sc, acc[i][1] * sc);
      o.y = pack2(acc[i][2] * sc, acc[i][3] * sc);
      *(uint2*)&Cmat[(size_t)row * 64 + bn * 32 + tx * 2] = o;
    }
  }
}

__launch_bounds__(256)
__global__ void gemm128_bf16(const unsigned* __restrict__ A, const float* __restrict__ B,
                             const float* __restrict__ scale, unsigned* __restrict__ Cmat, int M){
  __shared__ float As[128 * 64];
  __shared__ float Bs[128 * 64];
  const int t = threadIdx.x;
  const int bm = blockIdx.x, bn = blockIdx.y;
  const int row0 = bm * 64;

  #pragma unroll
  for (int i = 0; i < 8; ++i){
    int idx4 = t + i * 256;
    int k = idx4 >> 4, c4 = idx4 & 15;
    float4 v = *(const float4*)&B[k * 128 + bn * 64 + c4 * 4];
    *(float4*)&Bs[k * 64 + c4 * 4] = v;
  }
  {
    int m = t & 63, kb = t >> 6;
    int row = row0 + m; if (row >= M) row = M - 1;
    const unsigned* Arow = A + (size_t)row * 64;
    #pragma unroll
    for (int i = 0; i < 8; ++i){
      int k4 = kb + i * 4;
      uint2 v = *(const uint2*)&Arow[k4 * 2];
      int k = k4 * 4;
      As[(k + 0) * 64 + m] = bf16lo(v.x);
      As[(k + 1) * 64 + m] = bf16hi(v.x);
      As[(k + 2) * 64 + m] = bf16lo(v.y);
      As[(k + 3) * 64 + m] = bf16hi(v.y);
    }
  }
  __syncthreads();

  const int tx = t & 15, ty = t >> 4;
  float acc[4][4] = {};
  #pragma unroll 4
  for (int k = 0; k < 128; ++k){
    float a[4], b[4];
    *(float4*)a = *(const float4*)&As[k * 64 + (ty << 2)];
    *(float4*)b = *(const float4*)&Bs[k * 64 + (tx << 2)];
    #pragma unroll
    for (int i = 0; i < 4; ++i)
      #pragma unroll
      for (int j = 0; j < 4; ++j)
        acc[i][j] = fmaf(a[i], b[j], acc[i][j]);
  }
  #pragma unroll
  for (int i = 0; i < 4; ++i){
    int row = row0 + (ty << 2) + i;
    if (row < M){
      float sc = scale[row];
      uint2 o;
      o.x = pack2(acc[i][0] * sc, acc[i][1] * sc);
      o.y = pack2(acc[i][2] * sc, acc[i][3] * sc);
      *(uint2*)&Cmat[(size_t)row * 64 + bn * 32 + tx * 2] = o;
    }
  }
}

// ---------------------------------------------------------------------------
// CSR conv over bf16 rows: out[i] = relu( dis[i]*(sum_e Ts[src_e] + Ts[i]) + b )
// ---------------------------------------------------------------------------
__launch_bounds__(256)
__global__ void conv_csr(const unsigned* __restrict__ Ts, const float* __restrict__ dis,
                         const int* __restrict__ rowptr, const int* __restrict__ esrc,
                         const float* __restrict__ bias, unsigned* __restrict__ Hout){
  int w = blockIdx.x * 4 + (threadIdx.x >> 6);
  int l = threadIdx.x & 63;
  int beg = rowptr[w], end = rowptr[w + 1];
  float2 a0{0.f,0.f}, a1{0.f,0.f}, a2{0.f,0.f}, a3{0.f,0.f};
  for (int base = beg; base < end; base += 64){
    int n = min(64, end - base);
    int eid = esrc[base + min(l, n - 1)];
    int j = 0;
    for (; j + 4 <= n; j += 4){
      int s0 = __shfl(eid, j);
      int s1 = __shfl(eid, j + 1);
      int s2 = __shfl(eid, j + 2);
      int s3 = __shfl(eid, j + 3);
      unsigned u0 = Ts[(size_t)s0 * 64 + l];
      unsigned u1 = Ts[(size_t)s1 * 64 + l];
      unsigned u2 = Ts[(size_t)s2 * 64 + l];
      unsigned u3 = Ts[(size_t)s3 * 64 + l];
      a0.x += bf16lo(u0); a0.y += bf16hi(u0);
      a1.x += bf16lo(u1); a1.y += bf16hi(u1);
      a2.x += bf16lo(u2); a2.y += bf16hi(u2);
      a3.x += bf16lo(u3); a3.y += bf16hi(u3);
    }
    for (; j < n; ++j){
      int s = __shfl(eid, j);
      unsigned u = Ts[(size_t)s * 64 + l];
      a0.x += bf16lo(u); a0.y += bf16hi(u);
    }
  }
  float d = dis[w];
  unsigned us = Ts[(size_t)w * 64 + l];
  float2 bb = *(const float2*)&bias[l * 2];
  float rx = fmaxf(fmaf(d, a0.x + a1.x + a2.x + a3.x + bf16lo(us), bb.x), 0.f);
  float ry = fmaxf(fmaf(d, a0.y + a1.y + a2.y + a3.y + bf16hi(us), bb.y), 0.f);
  Hout[(size_t)w * 64 + l] = pack2(rx, ry);
}

// cluster mean pool + batch_p over bf16 rows
__launch_bounds__(256)
__global__ void cluster_gather(const unsigned* __restrict__ h1, const int* __restrict__ rowptrn,
                               const int* __restrict__ nidx, const int* __restrict__ batch,
                               unsigned* __restrict__ hp, int* __restrict__ batchp){
  int c = blockIdx.x * 4 + (threadIdx.x >> 6);
  int l = threadIdx.x & 63;
  int mb = rowptrn[c], me = rowptrn[c + 1];
  float2 a0{0.f,0.f}, a1{0.f,0.f}, a2{0.f,0.f}, a3{0.f,0.f};
  int vmax = -1;
  for (int base = mb; base < me; base += 64){
    int n = min(64, me - base);
    int vid = nidx[base + min(l, n - 1)];
    if (l < n) vmax = max(vmax, vid);
    int j = 0;
    for (; j + 4 <= n; j += 4){
      int s0 = __shfl(vid, j);
      int s1 = __shfl(vid, j + 1);
      int s2 = __shfl(vid, j + 2);
      int s3 = __shfl(vid, j + 3);
      unsigned u0 = h1[(size_t)s0 * 64 + l];
      unsigned u1 = h1[(size_t)s1 * 64 + l];
      unsigned u2 = h1[(size_t)s2 * 64 + l];
      unsigned u3 = h1[(size_t)s3 * 64 + l];
      a0.x += bf16lo(u0); a0.y += bf16hi(u0);
      a1.x += bf16lo(u1); a1.y += bf16hi(u1);
      a2.x += bf16lo(u2); a2.y += bf16hi(u2);
      a3.x += bf16lo(u3); a3.y += bf16hi(u3);
    }
    for (; j < n; ++j){
      int s = __shfl(vid, j);
      unsigned u = h1[(size_t)s * 64 + l];
      a0.x += bf16lo(u); a0.y += bf16hi(u);
    }
  }
  #pragma unroll
  for (int off = 32; off > 0; off >>= 1) vmax = max(vmax, __shfl_xor(vmax, off));
  float inv = 1.0f / (float)max(me - mb, 1);
  float ox = (a0.x + a1.x + a2.x + a3.x) * inv;
  float oy = (a0.y + a1.y + a2.y + a3.y) * inv;
  hp[(size_t)c * 64 + l] = pack2(ox, oy);
  if (l == 0) batchp[c] = (vmax >= 0) ? batch[vmax] : 0;  // batch sorted by node id
}

__global__ void cntp_kernel(const int* __restrict__ batchp, int* __restrict__ cntp){
  int c = blockIdx.x * blockDim.x + threadIdx.x;
  if (c < N_CLUST) atomicAdd(&cntp[batchp[c]], 1);
}

// graph -> cluster CSR: scan cntp (64 entries) + cursor fill
__global__ void scan_cntp(const int* __restrict__ cntp, int* __restrict__ gbasep,
                          int* __restrict__ curp){
  int t = threadIdx.x;                 // 64 threads
  int v = cntp[t];
  int s = v;
  for (int off = 1; off < 64; off <<= 1){
    int u = __shfl_up(s, off);
    if (t >= off) s += u;
  }
  gbasep[t] = s - v; curp[t] = s - v;
  if (t == 63) gbasep[64] = s;
}

__global__ void fill_c(const int* __restrict__ batchp, int* __restrict__ curp,
                       int* __restrict__ cidx){
  int c = blockIdx.x * blockDim.x + threadIdx.x;
  if (c < N_CLUST) cidx[atomicAdd(&curp[batchp[c]], 1)] = c;
}

// ---------------------------------------------------------------------------
__global__ void graph_bounds(const int* __restrict__ batch, int* __restrict__ gstart){
  int g = threadIdx.x;
  if (g > N_GRAPH) return;
  int lo = 0, hi = N_NODES;
  while (lo < hi){ int mid = (lo + hi) >> 1; if (batch[mid] < g) lo = mid + 1; else hi = mid; }
  gstart[g] = lo;
}

__device__ __forceinline__ void atomicMaxPosF(float* addr, float v){
  atomicMax((int*)addr, __float_as_int(v));
}

// pre-pool gather: graph g's rows are contiguous [gstart[g], gstart[g+1])
constexpr int PRE_SPLIT = 4;
__launch_bounds__(256)
__global__ void pre_pool_g(const unsigned* __restrict__ h1, const int* __restrict__ gstart,
                           float* __restrict__ psum, float* __restrict__ pmax){
  int g = blockIdx.x / PRE_SPLIT, sp = blockIdx.x % PRE_SPLIT;
  int t = threadIdx.x, w = t >> 6, l = t & 63;
  int s0 = gstart[g], s1 = gstart[g + 1];
  int n = s1 - s0;
  int per = (n + PRE_SPLIT - 1) / PRE_SPLIT;
  int b0 = s0 + sp * per, b1 = min(b0 + per, s1);
  float2 a0{0.f,0.f}, a1{0.f,0.f}, a2{0.f,0.f}, a3{0.f,0.f};
  float2 mx{0.f,0.f};
  int i = b0 + w;
  for (; i + 12 < b1; i += 16){
    unsigned u0 = h1[(size_t)(i     ) * 64 + l];
    unsigned u1 = h1[(size_t)(i +  4) * 64 + l];
    unsigned u2 = h1[(size_t)(i +  8) * 64 + l];
    unsigned u3 = h1[(size_t)(i + 12) * 64 + l];
    float f0x = bf16lo(u0), f0y = bf16hi(u0);
    float f1x = bf16lo(u1), f1y = bf16hi(u1);
    float f2x = bf16lo(u2), f2y = bf16hi(u2);
    float f3x = bf16lo(u3), f3y = bf16hi(u3);
    a0.x += f0x; a0.y += f0y; a1.x += f1x; a1.y += f1y;
    a2.x += f2x; a2.y += f2y; a3.x += f3x; a3.y += f3y;
    mx.x = fmaxf(fmaxf(mx.x, fmaxf(f0x, f1x)), fmaxf(f2x, f3x));
    mx.y = fmaxf(fmaxf(mx.y, fmaxf(f0y, f1y)), fmaxf(f2y, f3y));
  }
  for (; i < b1; i += 4){
    unsigned u = h1[(size_t)i * 64 + l];
    float fx = bf16lo(u), fy = bf16hi(u);
    a0.x += fx; a0.y += fy;
    mx.x = fmaxf(mx.x, fx); mx.y = fmaxf(mx.y, fy);
  }
  __shared__ float2 ssum[4][64], smax[4][64];
  ssum[w][l] = { a0.x + a1.x + a2.x + a3.x, a0.y + a1.y + a2.y + a3.y };
  smax[w][l] = mx;
  __syncthreads();
  if (w == 0){
    float2 S = ssum[0][l], M = smax[0][l];
    #pragma unroll
    for (int k = 1; k < 4; ++k){
      S.x += ssum[k][l].x; S.y += ssum[k][l].y;
      M.x = fmaxf(M.x, smax[k][l].x); M.y = fmaxf(M.y, smax[k][l].y);
    }
    atomicAdd(&psum[g * 128 + 2 * l], S.x);
    atomicAdd(&psum[g * 128 + 2 * l + 1], S.y);
    atomicMaxPosF(&pmax[g * 128 + 2 * l], M.x);
    atomicMaxPosF(&pmax[g * 128 + 2 * l + 1], M.y);
  }
}

// post-pool gather via graph->cluster CSR
constexpr int POST_SPLIT = 2;
__launch_bounds__(256)
__global__ void post_pool_g(const unsigned* __restrict__ hp3, const int* __restrict__ gbasep,
                            const int* __restrict__ cidx,
                            float* __restrict__ psum, float* __restrict__ pmax){
  int g = blockIdx.x / POST_SPLIT, sp = blockIdx.x % POST_SPLIT;
  int t = threadIdx.x, w = t >> 6, l = t & 63;
  int s0 = gbasep[g], s1 = gbasep[g + 1];
  int n = s1 - s0;
  int per = (n + POST_SPLIT * 4 - 1) / (POST_SPLIT * 4);
  int b0 = s0 + (sp * 4 + w) * per, b1 = min(b0 + per, s1);
  float2 a0{0.f,0.f}, a1{0.f,0.f}, a2{0.f,0.f}, a3{0.f,0.f};
  float2 mx{0.f,0.f};
  for (int base = b0; base < b1; base += 64){
    int nn = min(64, b1 - base);
    int cid = cidx[base + min(l, nn - 1)];
    int j = 0;
    for (; j + 4 <= nn; j += 4){
      int c0 = __shfl(cid, j);
      int c1 = __shfl(cid, j + 1);
      int c2 = __shfl(cid, j + 2);
      int c3 = __shfl(cid, j + 3);
      unsigned u0 = hp3[(size_t)c0 * 64 + l];
      unsigned u1 = hp3[(size_t)c1 * 64 + l];
      unsigned u2 = hp3[(size_t)c2 * 64 + l];
      unsigned u3 = hp3[(size_t)c3 * 64 + l];
      float f0x = bf16lo(u0), f0y = bf16hi(u0);
      float f1x = bf16lo(u1), f1y = bf16hi(u1);
      float f2x = bf16lo(u2), f2y = bf16hi(u2);
      float f3x = bf16lo(u3), f3y = bf16hi(u3);
      a0.x += f0x; a0.y += f0y; a1.x += f1x; a1.y += f1y;
      a2.x += f2x; a2.y += f2y; a3.x += f3x; a3.y += f3y;
      mx.x = fmaxf(fmaxf(mx.x, fmaxf(f0x, f1x)), fmaxf(f2x, f3x));
      mx.y = fmaxf(fmaxf(mx.y, fmaxf(f0y, f1y)), fmaxf(f2y, f3y));
    }
    for (; j < nn; ++j){
      int c = __shfl(cid, j);
      unsigned u = hp3[(size_t)c * 64 + l];
      float fx = bf16lo(u), fy = bf16hi(u);
      a0.x += fx; a0.y += fy;
      mx.x = fmaxf(mx.x, fx); mx.y = fmaxf(mx.y, fy);
    }
  }
  __shared__ float2 ssum[4][64], smax[4][64];
  ssum[w][l] = { a0.x + a1.x + a2.x + a3.x, a0.y + a1.y + a2.y + a3.y };
  smax[w][l] = mx;
  __syncthreads();
  if (w == 0){
    float2 S = ssum[0][l], M = smax[0][l];
    #pragma unroll
    for (int k = 1; k < 4; ++k){
      S.x += ssum[k][l].x; S.y += ssum[k][l].y;
      M.x = fmaxf(M.x, smax[k][l].x); M.y = fmaxf(M.y, smax[k][l].y);
    }
    atomicAdd(&psum[g * 128 + 2 * l], S.x);
    atomicAdd(&psum[g * 128 + 2 * l + 1], S.y);
    atomicMaxPosF(&pmax[g * 128 + 2 * l], M.x);
    atomicMaxPosF(&pmax[g * 128 + 2 * l + 1], M.y);
  }
}

__launch_bounds__(128)
__global__ void head_kernel(const float* __restrict__ psum, const float* __restrict__ pmax,
                            const float* __restrict__ postsum, const float* __restrict__ postmax,
                            const int* __restrict__ gstart, const int* __restrict__ cntp,
                            const float* __restrict__ l1w, const float* __restrict__ l1b,
                            const float* __restrict__ l2w, const float* __restrict__ l2b,
                            float* __restrict__ out){
  int g = blockIdx.x, t = threadIdx.x;
  __shared__ float z[512];
  __shared__ float a[128];
  __shared__ float logits[16];
  __shared__ float lse_s;
  float cpre  = (float)max(gstart[g + 1] - gstart[g], 1);
  float cpost = fmaxf((float)cntp[g], 1.0f);
  z[t]       = psum[g * 128 + t] / cpre;
  z[128 + t] = pmax[g * 128 + t];
  z[256 + t] = postsum[g * 128 + t] / cpost;
  z[384 + t] = postmax[g * 128 + t];
  __syncthreads();
  float acc = l1b[t];
  #pragma unroll 8
  for (int k = 0; k < 512; ++k) acc = fmaf(z[k], l1w[k * 128 + t], acc);
  a[t] = fmaxf(acc, 0.f);
  __syncthreads();
  if (t < NCLSN){
    float s2 = l2b[t];
    for (int k = 0; k < 128; ++k) s2 = fmaf(a[k], l2w[k * NCLSN + t], s2);
    logits[t] = s2;
  }
  __syncthreads();
  if (t == 0){
    float m = logits[0];
    for (int c = 1; c < NCLSN; ++c) m = fmaxf(m, logits[c]);
    float s = 0.f;
    for (int c = 0; c < NCLSN; ++c) s += expf(logits[c] - m);
    lse_s = m + logf(s);
  }
  __syncthreads();
  if (t < NCLSN) out[g * NCLSN + t] = logits[t] - lse_s;
}

// ---------------------------------------------------------------------------
extern "C" void kernel_launch(void* const* d_in, const int* in_sizes, int n_in,
                              void* d_out, int out_size, void* d_ws, size_t ws_size,
                              hipStream_t stream){
  const float* x       = (const float*)d_in[0];
  const int*   ei      = (const int*)  d_in[1];
  const int*   batch   = (const int*)  d_in[2];
  const int*   cluster = (const int*)  d_in[3];
  const float* W1      = (const float*)d_in[6];
  const float* b1      = (const float*)d_in[7];
  const float* W2      = (const float*)d_in[8];
  const float* b2      = (const float*)d_in[9];
  const float* W3      = (const float*)d_in[10];
  const float* b3      = (const float*)d_in[11];
  const float* l1w     = (const float*)d_in[12];
  const float* l1b     = (const float*)d_in[13];
  const float* l2w     = (const float*)d_in[14];
  const float* l2b     = (const float*)d_in[15];
  float* out = (float*)d_out;

  char* base = (char*)d_ws;
  size_t off = 0;
  auto alloc = [&](size_t bytes) -> char* {
    char* p = base + off;
    off += (bytes + 255) & ~size_t(255);
    return p;
  };
  // ---- zero zone (one memset) ----
  char*  zbase  = base + off;
  int*   gcnt1  = (int*)  alloc((size_t)NBKT1 * 4);
  int*   gcnt2  = (int*)  alloc((size_t)NBKT2 * 4);
  int*   cntn   = (int*)  alloc((size_t)N_CLUST * 4);
  int*   cntp   = (int*)  alloc((size_t)N_GRAPH * 4);
  float* pre_s  = (float*)alloc((size_t)N_GRAPH * 128 * 4);
  float* pre_m  = (float*)alloc((size_t)N_GRAPH * 128 * 4);
  float* post_s = (float*)alloc((size_t)N_GRAPH * 128 * 4);
  float* post_m = (float*)alloc((size_t)N_GRAPH * 128 * 4);
  size_t zsize = off;
  // ---- plain buffers (bf16 feature rows: 64 uints per row) ----
  unsigned* Ts1   = (unsigned*)alloc((size_t)N_NODES * 64 * 4);  // later aliased
  unsigned* h1    = (unsigned*)alloc((size_t)N_NODES * 64 * 4);  // stage bufs alias here
  int*   esrc1   = (int*)  alloc((size_t)N_EDGES * 4);
  int*   psrcC   = (int*)  alloc((size_t)N_EDGES * 4);
  int*   deg1    = (int*)  alloc((size_t)N_NODES * 4);
  int*   deg2    = (int*)  alloc((size_t)N_CLUST * 4);
  int*   rowptr1 = (int*)  alloc((size_t)(N_NODES + 1) * 4);
  int*   rowptrn = (int*)  alloc((size_t)(N_CLUST + 1) * 4);
  int*   curn    = (int*)  alloc((size_t)N_CLUST * 4);
  int*   rowptr2 = (int*)  alloc((size_t)(N_CLUST + 1) * 4);
  int*   nidx    = (int*)  alloc((size_t)N_NODES * 4);
  float* dis1    = (float*)alloc((size_t)N_NODES * 4);
  float* dis2    = (float*)alloc((size_t)N_CLUST * 4);
  int*   batchp  = (int*)  alloc((size_t)N_CLUST * 4);
  int*   gstart  = (int*)  alloc((size_t)(N_GRAPH + 1) * 4);
  int*   bsum    = (int*)  alloc((size_t)NBT * 4);
  int*   boff    = (int*)  alloc((size_t)NBT * 4);
  int*   gbase1  = (int*)  alloc((size_t)NBKT1 * 4);
  int*   gcur1   = (int*)  alloc((size_t)NBKT1 * 4);
  int*   gbase2  = (int*)  alloc((size_t)NBKT2 * 4);
  int*   gcur2   = (int*)  alloc((size_t)NBKT2 * 4);
  int*   gbasep  = (int*)  alloc((size_t)(N_GRAPH + 1) * 4);
  int*   curp    = (int*)  alloc((size_t)N_GRAPH * 4);
  int*   cidx    = (int*)  alloc((size_t)N_CLUST * 4);
  // stage buffers alias the (not-yet-written) h1 region (12.8 MB <= 25.6 MB)
  unsigned int* stage1 = (unsigned int*)h1;
  unsigned int* stage2 = stage1 + N_EDGES;
  // aliases into Ts1 (dead after conv1): 4 x 25000*64 uints = exactly Ts1 size
  unsigned* hp  = Ts1;
  unsigned* Ts2 = Ts1 + (size_t)N_CLUST * 64;
  unsigned* hp2 = Ts1 + (size_t)2 * N_CLUST * 64;
  unsigned* hp3 = Ts1 + (size_t)3 * N_CLUST * 64;
  unsigned* Ts3 = Ts2;

  (void)in_sizes; (void)n_in; (void)out_size; (void)ws_size;

  hipMemsetAsync(zbase, 0, zsize, stream);

  // ---- sort-based CSR build ----
  count_kernel  <<<NEB, 256, 0, stream>>>(ei, cluster, gcnt1, gcnt2);
  cntn_kernel   <<<(N_NODES + 255) / 256, 256, 0, stream>>>(cluster, cntn);
  bucket_scan   <<<1, 256, 0, stream>>>(gcnt1, gcnt2, gbase1, gcur1, gbase2, gcur2);
  scatter_kernel<<<NEB, 256, 0, stream>>>(ei, cluster, gcur1, gcur2, stage1, stage2);
  bucket_sort<512, 17><<<NBKT1, 256, 0, stream>>>(stage1, gbase1, gcnt1, esrc1, deg1, N_NODES);
  bucket_sort<128, 15><<<NBKT2, 256, 0, stream>>>(stage2, gbase2, gcnt2, psrcC, deg2, N_CLUST);
  block_sums <<<NBT, 256, 0, stream>>>(deg1, cntn, deg2, bsum);
  scan_bsums <<<1, 256, 0, stream>>>(bsum, boff, rowptr1, rowptrn, rowptr2);
  scan_final <<<NBT, 256, 0, stream>>>(deg1, cntn, deg2, boff,
                                       rowptr1, dis1, rowptrn, curn, rowptr2, dis2);
  fill_n<<<(N_NODES + 255) / 256, 256, 0, stream>>>(cluster, curn, nidx);

  // conv1
  gemm128_f32<<<dim3((N_NODES + 63) / 64, 2), 256, 0, stream>>>(x, W1, dis1, Ts1, N_NODES);
  conv_csr<<<N_NODES / 4, 256, 0, stream>>>(Ts1, dis1, rowptr1, esrc1, b1, h1);

  // pre pools (gather over contiguous sorted-batch ranges)
  graph_bounds<<<1, 128, 0, stream>>>(batch, gstart);
  pre_pool_g<<<N_GRAPH * PRE_SPLIT, 256, 0, stream>>>(h1, gstart, pre_s, pre_m);

  // cluster mean pool + batch_p + cntp + graph->cluster CSR
  cluster_gather<<<N_CLUST / 4, 256, 0, stream>>>(h1, rowptrn, nidx, batch, hp, batchp);
  cntp_kernel<<<(N_CLUST + 255) / 256, 256, 0, stream>>>(batchp, cntp);
  scan_cntp<<<1, 64, 0, stream>>>(cntp, gbasep, curp);
  fill_c<<<(N_CLUST + 255) / 256, 256, 0, stream>>>(batchp, curp, cidx);

  // conv2
  gemm128_bf16<<<dim3((N_CLUST + 63) / 64, 2), 256, 0, stream>>>(hp, W2, dis2, Ts2, N_CLUST);
  conv_csr<<<N_CLUST / 4, 256, 0, stream>>>(Ts2, dis2, rowptr2, psrcC, b2, hp2);

  // conv3
  gemm128_bf16<<<dim3((N_CLUST + 63) / 64, 2), 256, 0, stream>>>(hp2, W3, dis2, Ts3, N_CLUST);
  conv_csr<<<N_CLUST / 4, 256, 0, stream>>>(Ts3, dis2, rowptr2, psrcC, b3, hp3);

  // post pools (gather via graph->cluster CSR) + head
  post_pool_g<<<N_GRAPH * POST_SPLIT, 256, 0, stream>>>(hp3, gbasep, cidx, post_s, post_m);
  head_kernel<<<N_GRAPH, 128, 0, stream>>>(pre_s, pre_m, post_s, post_m, gstart, cntp,
                                           l1w, l1b, l2w, l2b, out);
}

// Round 9
// 648.581 us; speedup vs baseline: 2.5555x; 1.0634x over previous
//
#include <hip/hip_runtime.h>

constexpr int N_NODES = 100000;
constexpr int N_EDGES = 1600000;
constexpr int N_CLUST = 25000;
constexpr int N_GRAPH = 64;
constexpr int NCLSN   = 10;

// bucket decomposition for the sort-based CSR builds
constexpr int BKT1_SHIFT = 9;                       // node-dst buckets of 512 ids
constexpr int NBKT1 = (N_NODES + 511) / 512;        // 196
constexpr int BKT2_SHIFT = 7;                       // cluster-dst buckets of 128 ids
constexpr int NBKT2 = (N_CLUST + 127) / 128;        // 196
constexpr int EPB = 4096;                           // edges per block (count/scatter)
constexpr int NEB = (N_EDGES + EPB - 1) / EPB;      // 391
constexpr int SORT_CAP = 12288;                     // LDS staging cap (mean 8163, sd ~90)

// scan partitioning: 1024 elements per block, three concatenated segments
constexpr int SCAN_BPB = 1024;
constexpr int NB1 = (N_NODES + SCAN_BPB - 1) / SCAN_BPB;  // 98
constexpr int NB2 = (N_CLUST + SCAN_BPB - 1) / SCAN_BPB;  // 25
constexpr int NB3 = (N_CLUST + SCAN_BPB - 1) / SCAN_BPB;  // 25
constexpr int NBT = NB1 + NB2 + NB3;                      // 148

// ---- bf16 pack/unpack helpers (features stored as packed pairs in uint) ----
__device__ __forceinline__ float bf16lo(unsigned u){ return __uint_as_float(u << 16); }
__device__ __forceinline__ float bf16hi(unsigned u){ return __uint_as_float(u & 0xffff0000u); }
__device__ __forceinline__ unsigned bf16_rne(float f){
  unsigned u = __float_as_uint(f);
  return (u + 0x7fffu + ((u >> 16) & 1u)) >> 16;
}
__device__ __forceinline__ unsigned pack2(float lo, float hi){
  return bf16_rne(lo) | (bf16_rne(hi) << 16);
}

typedef short bf16x8 __attribute__((ext_vector_type(8)));
typedef float f32x4  __attribute__((ext_vector_type(4)));

// ---------------------------------------------------------------------------
// bucket-sort CSR build, phase 1: LDS-aggregated bucket counts
// ---------------------------------------------------------------------------
__launch_bounds__(256)
__global__ void count_kernel(const int* __restrict__ ei, const int* __restrict__ cluster,
                             int* __restrict__ gcnt1, int* __restrict__ gcnt2){
  __shared__ int h1c[NBKT1], h2c[NBKT2];
  int t = threadIdx.x;
  for (int i = t; i < NBKT1; i += 256) h1c[i] = 0;
  for (int i = t; i < NBKT2; i += 256) h2c[i] = 0;
  __syncthreads();
  int e0 = blockIdx.x * EPB;
  #pragma unroll
  for (int i = 0; i < EPB / 256; ++i){
    int e = e0 + i * 256 + t;
    if (e < N_EDGES){
      int dst = ei[N_EDGES + e];
      int cd  = cluster[dst];
      atomicAdd(&h1c[dst >> BKT1_SHIFT], 1);
      atomicAdd(&h2c[cd  >> BKT2_SHIFT], 1);
    }
  }
  __syncthreads();
  for (int i = t; i < NBKT1; i += 256) if (h1c[i]) atomicAdd(&gcnt1[i], h1c[i]);
  for (int i = t; i < NBKT2; i += 256) if (h2c[i]) atomicAdd(&gcnt2[i], h2c[i]);
}

// phase 2: bucket bases
__launch_bounds__(256)
__global__ void bucket_scan(const int* __restrict__ gcnt1, const int* __restrict__ gcnt2,
                            int* __restrict__ gbase1, int* __restrict__ gcur1,
                            int* __restrict__ gbase2, int* __restrict__ gcur2){
  __shared__ int s[256];
  int t = threadIdx.x;
  int v = (t < NBKT1) ? gcnt1[t] : 0;
  s[t] = v; __syncthreads();
  for (int off = 1; off < 256; off <<= 1){
    int a = (t >= off) ? s[t - off] : 0;
    __syncthreads(); s[t] += a; __syncthreads();
  }
  if (t < NBKT1){ gbase1[t] = s[t] - v; gcur1[t] = s[t] - v; }
  __syncthreads();
  v = (t < NBKT2) ? gcnt2[t] : 0;
  s[t] = v; __syncthreads();
  for (int off = 1; off < 256; off <<= 1){
    int a = (t >= off) ? s[t - off] : 0;
    __syncthreads(); s[t] += a; __syncthreads();
  }
  if (t < NBKT2){ gbase2[t] = s[t] - v; gcur2[t] = s[t] - v; }
}

// phase 3: scatter packed words into bucket regions (per-block reserved runs)
__launch_bounds__(256)
__global__ void scatter_kernel(const int* __restrict__ ei, const int* __restrict__ cluster,
                               int* __restrict__ gcur1, int* __restrict__ gcur2,
                               unsigned int* __restrict__ stage1, unsigned int* __restrict__ stage2){
  __shared__ int h1c[NBKT1], h2c[NBKT2];
  __shared__ int gb1[NBKT1], gb2[NBKT2];
  int t = threadIdx.x;
  for (int i = t; i < NBKT1; i += 256) h1c[i] = 0;
  for (int i = t; i < NBKT2; i += 256) h2c[i] = 0;
  __syncthreads();
  int e0 = blockIdx.x * EPB;
  #pragma unroll
  for (int i = 0; i < EPB / 256; ++i){
    int e = e0 + i * 256 + t;
    if (e < N_EDGES){
      int dst = ei[N_EDGES + e];
      int cd  = cluster[dst];
      atomicAdd(&h1c[dst >> BKT1_SHIFT], 1);
      atomicAdd(&h2c[cd  >> BKT2_SHIFT], 1);
    }
  }
  __syncthreads();
  for (int i = t; i < NBKT1; i += 256){ int c = h1c[i]; gb1[i] = c ? atomicAdd(&gcur1[i], c) : 0; }
  for (int i = t; i < NBKT2; i += 256){ int c = h2c[i]; gb2[i] = c ? atomicAdd(&gcur2[i], c) : 0; }
  __syncthreads();
  for (int i = t; i < NBKT1; i += 256) h1c[i] = 0;   // reuse as local cursors
  for (int i = t; i < NBKT2; i += 256) h2c[i] = 0;
  __syncthreads();
  #pragma unroll
  for (int i = 0; i < EPB / 256; ++i){
    int e = e0 + i * 256 + t;
    if (e < N_EDGES){
      int src = ei[e], dst = ei[N_EDGES + e];
      int cs = cluster[src], cd = cluster[dst];
      int b1 = dst >> BKT1_SHIFT, b2 = cd >> BKT2_SHIFT;
      int r1 = atomicAdd(&h1c[b1], 1);
      int r2 = atomicAdd(&h2c[b2], 1);
      stage1[gb1[b1] + r1] = ((unsigned)(dst & 511) << 17) | (unsigned)src;
      stage2[gb2[b2] + r2] = ((unsigned)(cd & 127) << 15) | (unsigned)cs;
    }
  }
}

// phase 4: per-bucket LDS counting sort + coalesced degree writes
template<int NBINS, int PSHIFT>
__launch_bounds__(256)
__global__ void bucket_sort(const unsigned int* __restrict__ stage, const int* __restrict__ gbase,
                            const int* __restrict__ gcnt, int* __restrict__ outpay,
                            int* __restrict__ deg, int ntot){
  __shared__ int cnt[NBINS], off[NBINS];
  __shared__ int sorted[SORT_CAP];
  int b = blockIdx.x, t = threadIdx.x;
  int base = gbase[b], n = gcnt[b];
  for (int i = t; i < NBINS; i += 256) cnt[i] = 0;
  __syncthreads();
  for (int i = t; i < n; i += 256) atomicAdd(&cnt[stage[base + i] >> PSHIFT], 1);
  __syncthreads();
  for (int i = t; i < NBINS; i += 256){
    int idx = b * NBINS + i;
    if (idx < ntot) deg[idx] = cnt[i];
    off[i] = cnt[i];
  }
  __syncthreads();
  for (int s = 1; s < NBINS; s <<= 1){
    int v0 = 0, v1 = 0;
    if (t < NBINS && t >= s) v0 = off[t - s];
    if (NBINS > 256 && t + 256 < NBINS && t + 256 >= s) v1 = off[t + 256 - s];
    __syncthreads();
    if (t < NBINS) off[t] += v0;
    if (NBINS > 256 && t + 256 < NBINS) off[t + 256] += v1;
    __syncthreads();
  }
  for (int i = t; i < NBINS; i += 256) off[i] -= cnt[i];   // exclusive cursors
  __syncthreads();
  constexpr unsigned PMASK = (1u << PSHIFT) - 1u;
  if (n <= SORT_CAP){
    for (int i = t; i < n; i += 256){
      unsigned w = stage[base + i];
      int r = atomicAdd(&off[w >> PSHIFT], 1);
      sorted[r] = (int)(w & PMASK);
    }
    __syncthreads();
    for (int i = t; i < n; i += 256) outpay[base + i] = sorted[i];
  } else {
    for (int i = t; i < n; i += 256){
      unsigned w = stage[base + i];
      int r = atomicAdd(&off[w >> PSHIFT], 1);
      outpay[base + r] = (int)(w & PMASK);
    }
  }
}

// cluster membership counts
__global__ void cntn_kernel(const int* __restrict__ cluster, int* __restrict__ cntn){
  int v = blockIdx.x * blockDim.x + threadIdx.x;
  if (v < N_NODES) atomicAdd(&cntn[cluster[v]], 1);
}

// ---------------------------------------------------------------------------
// device-wide 3-segment exclusive scan
// ---------------------------------------------------------------------------
__device__ __forceinline__ void seg_select(int b, const int* deg1, const int* cntn,
                                           const int* deg2, const int*& src, int& n, int& base){
  if (b < NB1){ src = deg1; n = N_NODES; base = b * SCAN_BPB; }
  else if (b < NB1 + NB2){ src = cntn; n = N_CLUST; base = (b - NB1) * SCAN_BPB; }
  else { src = deg2; n = N_CLUST; base = (b - NB1 - NB2) * SCAN_BPB; }
}

__launch_bounds__(256)
__global__ void block_sums(const int* __restrict__ deg1, const int* __restrict__ cntn,
                           const int* __restrict__ deg2, int* __restrict__ bsum){
  int b = blockIdx.x;
  const int* src; int n, base;
  seg_select(b, deg1, cntn, deg2, src, n, base);
  int t = threadIdx.x;
  int i0 = base + t * 4;
  int s = 0;
  if (i0 + 3 < n){ int4 v = *(const int4*)&src[i0]; s = v.x + v.y + v.z + v.w; }
  else { for (int j = 0; j < 4; ++j){ int i = i0 + j; if (i < n) s += src[i]; } }
  __shared__ int sh[256];
  sh[t] = s; __syncthreads();
  for (int off = 128; off > 0; off >>= 1){
    if (t < off) sh[t] += sh[t + off];
    __syncthreads();
  }
  if (t == 0) bsum[b] = sh[0];
}

__launch_bounds__(256)
__global__ void scan_bsums(const int* __restrict__ bsum, int* __restrict__ boff,
                           int* __restrict__ rowptr1, int* __restrict__ rowptrn,
                           int* __restrict__ rowptr2){
  __shared__ int s[256];
  int t = threadIdx.x;
  int v = (t < NBT) ? bsum[t] : 0;
  s[t] = v; __syncthreads();
  int seg = (t < NB1) ? 0 : (t < NB1 + NB2 ? 1 : 2);
  for (int off = 1; off < 256; off <<= 1){
    int add = 0;
    if (t >= off){
      int u = t - off;
      int useg = (u < NB1) ? 0 : (u < NB1 + NB2 ? 1 : 2);
      if (useg == seg) add = s[u];
    }
    __syncthreads();
    s[t] += add;
    __syncthreads();
  }
  if (t < NBT) boff[t] = s[t] - v;
  if (t == NB1 - 1)       rowptr1[N_NODES] = s[t];
  if (t == NB1 + NB2 - 1) rowptrn[N_CLUST] = s[t];
  if (t == NBT - 1)       rowptr2[N_CLUST] = s[t];
}

__launch_bounds__(256)
__global__ void scan_final(const int* __restrict__ deg1, const int* __restrict__ cntn,
                           const int* __restrict__ deg2, const int* __restrict__ boff,
                           int* __restrict__ rowptr1, float* __restrict__ dis1,
                           int* __restrict__ rowptrn, int* __restrict__ curn,
                           int* __restrict__ rowptr2, float* __restrict__ dis2){
  int b = blockIdx.x;
  const int* src; int n, base;
  seg_select(b, deg1, cntn, deg2, src, n, base);
  int* rp; int* cur; float* dis;
  if (b < NB1){ rp = rowptr1; cur = nullptr; dis = dis1; }
  else if (b < NB1 + NB2){ rp = rowptrn; cur = curn; dis = nullptr; }
  else { rp = rowptr2; cur = nullptr; dis = dis2; }
  int t = threadIdx.x;
  int i0 = base + t * 4;
  int v[4]; int s = 0;
  #pragma unroll
  for (int j = 0; j < 4; ++j){ int i = i0 + j; v[j] = (i < n) ? src[i] : 0; s += v[j]; }
  __shared__ int sh[256];
  sh[t] = s; __syncthreads();
  for (int off = 1; off < 256; off <<= 1){
    int add = (t >= off) ? sh[t - off] : 0;
    __syncthreads();
    sh[t] += add;
    __syncthreads();
  }
  int run = sh[t] - s + boff[b];
  #pragma unroll
  for (int j = 0; j < 4; ++j){
    int i = i0 + j;
    if (i < n){
      rp[i] = run;
      if (cur) cur[i] = run;
      if (dis) dis[i] = rsqrtf((float)v[j] + 1.0f);
      run += v[j];
    }
  }
}

// node->cluster CSR fill
__global__ void fill_n(const int* __restrict__ cluster, int* __restrict__ curn,
                       int* __restrict__ nidx){
  int v = blockIdx.x * blockDim.x + threadIdx.x;
  if (v >= N_NODES) return;
  nidx[atomicAdd(&curn[cluster[v]], 1)] = v;
}

// ---------------------------------------------------------------------------
// MFMA GEMM: C[M,128] = (A[M,128] @ B[128,128]) * scale[row], bf16 packed out
// block = 256 threads (4 waves), 64 rows x 128 cols per block.
// B staged to LDS in B-fragment layout (bf16 pairs, stride 68 uints),
// A strip staged as bf16 pairs (stride 68). v_mfma_f32_16x16x32_bf16.
// Layouts (verified m89/m120): A[m=lane&15][k=quad*8+j]; C: col=lane&15,
// row=quad*4+reg. A is fp32 (A_BF16=false) or packed bf16 (A_BF16=true).
// ---------------------------------------------------------------------------
template<bool A_BF16>
__launch_bounds__(256)
__global__ void gemm_mfma(const void* __restrict__ Aptr, const float* __restrict__ B,
                          const float* __restrict__ scale, unsigned* __restrict__ Cmat,
                          int M){
  __shared__ __align__(16) unsigned Blds[128 * 68];
  __shared__ __align__(16) unsigned Alds[64 * 68];
  const int t = threadIdx.x;
  const int row0 = blockIdx.x * 64;

  // stage B: task = (k-pair kp 0..63, col-quad nq 0..31)
  #pragma unroll
  for (int i = 0; i < 8; ++i){
    int task = t + i * 256;
    int kp = task >> 5, nq = task & 31;
    float4 b0 = *(const float4*)&B[(2 * kp) * 128 + nq * 4];
    float4 b1 = *(const float4*)&B[(2 * kp + 1) * 128 + nq * 4];
    Blds[(nq * 4 + 0) * 68 + kp] = pack2(b0.x, b1.x);
    Blds[(nq * 4 + 1) * 68 + kp] = pack2(b0.y, b1.y);
    Blds[(nq * 4 + 2) * 68 + kp] = pack2(b0.z, b1.z);
    Blds[(nq * 4 + 3) * 68 + kp] = pack2(b0.w, b1.w);
  }
  // stage A strip (64 rows x 128 k) as bf16 pairs
  if (A_BF16){
    const unsigned* A = (const unsigned*)Aptr;
    #pragma unroll
    for (int i = 0; i < 8; ++i){
      int idx = t + i * 256;                 // 2048 uint2 tasks
      int row = idx >> 5, c2 = idx & 31;
      int grow = min(row0 + row, M - 1);
      uint2 v = *(const uint2*)&A[(size_t)grow * 64 + c2 * 2];
      Alds[row * 68 + c2 * 2]     = v.x;
      Alds[row * 68 + c2 * 2 + 1] = v.y;
    }
  } else {
    const float* A = (const float*)Aptr;
    #pragma unroll
    for (int i = 0; i < 8; ++i){
      int idx = t + i * 256;                 // 2048 float4 tasks
      int row = idx >> 5, k4 = idx & 31;
      int grow = min(row0 + row, M - 1);
      float4 v = *(const float4*)&A[(size_t)grow * 128 + k4 * 4];
      Alds[row * 68 + k4 * 2]     = pack2(v.x, v.y);
      Alds[row * 68 + k4 * 2 + 1] = pack2(v.z, v.w);
    }
  }
  __syncthreads();

  const int wv = t >> 6, l = t & 63, quad = l >> 4, n16 = l & 15;
  f32x4 acc[8];
  #pragma unroll
  for (int nt = 0; nt < 8; ++nt) acc[nt] = (f32x4){0.f, 0.f, 0.f, 0.f};
  const int arow = wv * 16 + n16;
  #pragma unroll
  for (int ks = 0; ks < 4; ++ks){
    bf16x8 af = *(const bf16x8*)&Alds[arow * 68 + ks * 16 + quad * 4];
    #pragma unroll
    for (int nt = 0; nt < 8; ++nt){
      bf16x8 bfr = *(const bf16x8*)&Blds[(nt * 16 + n16) * 68 + ks * 16 + quad * 4];
      acc[nt] = __builtin_amdgcn_mfma_f32_16x16x32_bf16(af, bfr, acc[nt], 0, 0, 0);
    }
  }
  #pragma unroll
  for (int nt = 0; nt < 8; ++nt){
    #pragma unroll
    for (int r = 0; r < 4; ++r){
      int row = row0 + wv * 16 + quad * 4 + r;
      float sc = scale[min(row, M - 1)];
      float v = acc[nt][r] * sc;
      float vhi = __shfl_xor(v, 1);
      if (((l & 1) == 0) && row < M)
        Cmat[(size_t)row * 64 + nt * 8 + (n16 >> 1)] = pack2(v, vhi);
    }
  }
}

// ---------------------------------------------------------------------------
// CSR conv over bf16 rows: out[i] = relu( dis[i]*(sum_e Ts[src_e] + Ts[i]) + b )
// ---------------------------------------------------------------------------
__launch_bounds__(256)
__global__ void conv_csr(const unsigned* __restrict__ Ts, const float* __restrict__ dis,
                         const int* __restrict__ rowptr, const int* __restrict__ esrc,
                         const float* __restrict__ bias, unsigned* __restrict__ Hout){
  int w = blockIdx.x * 4 + (threadIdx.x >> 6);
  int l = threadIdx.x & 63;
  int beg = rowptr[w], end = rowptr[w + 1];
  float2 a0{0.f,0.f}, a1{0.f,0.f}, a2{0.f,0.f}, a3{0.f,0.f};
  for (int base = beg; base < end; base += 64){
    int n = min(64, end - base);
    int eid = esrc[base + min(l, n - 1)];
    int j = 0;
    for (; j + 4 <= n; j += 4){
      int s0 = __shfl(eid, j);
      int s1 = __shfl(eid, j + 1);
      int s2 = __shfl(eid, j + 2);
      int s3 = __shfl(eid, j + 3);
      unsigned u0 = Ts[(size_t)s0 * 64 + l];
      unsigned u1 = Ts[(size_t)s1 * 64 + l];
      unsigned u2 = Ts[(size_t)s2 * 64 + l];
      unsigned u3 = Ts[(size_t)s3 * 64 + l];
      a0.x += bf16lo(u0); a0.y += bf16hi(u0);
      a1.x += bf16lo(u1); a1.y += bf16hi(u1);
      a2.x += bf16lo(u2); a2.y += bf16hi(u2);
      a3.x += bf16lo(u3); a3.y += bf16hi(u3);
    }
    for (; j < n; ++j){
      int s = __shfl(eid, j);
      unsigned u = Ts[(size_t)s * 64 + l];
      a0.x += bf16lo(u); a0.y += bf16hi(u);
    }
  }
  float d = dis[w];
  unsigned us = Ts[(size_t)w * 64 + l];
  float2 bb = *(const float2*)&bias[l * 2];
  float rx = fmaxf(fmaf(d, a0.x + a1.x + a2.x + a3.x + bf16lo(us), bb.x), 0.f);
  float ry = fmaxf(fmaf(d, a0.y + a1.y + a2.y + a3.y + bf16hi(us), bb.y), 0.f);
  Hout[(size_t)w * 64 + l] = pack2(rx, ry);
}

// cluster mean pool + batch_p over bf16 rows
__launch_bounds__(256)
__global__ void cluster_gather(const unsigned* __restrict__ h1, const int* __restrict__ rowptrn,
                               const int* __restrict__ nidx, const int* __restrict__ batch,
                               unsigned* __restrict__ hp, int* __restrict__ batchp){
  int c = blockIdx.x * 4 + (threadIdx.x >> 6);
  int l = threadIdx.x & 63;
  int mb = rowptrn[c], me = rowptrn[c + 1];
  float2 a0{0.f,0.f}, a1{0.f,0.f}, a2{0.f,0.f}, a3{0.f,0.f};
  int vmax = -1;
  for (int base = mb; base < me; base += 64){
    int n = min(64, me - base);
    int vid = nidx[base + min(l, n - 1)];
    if (l < n) vmax = max(vmax, vid);
    int j = 0;
    for (; j + 4 <= n; j += 4){
      int s0 = __shfl(vid, j);
      int s1 = __shfl(vid, j + 1);
      int s2 = __shfl(vid, j + 2);
      int s3 = __shfl(vid, j + 3);
      unsigned u0 = h1[(size_t)s0 * 64 + l];
      unsigned u1 = h1[(size_t)s1 * 64 + l];
      unsigned u2 = h1[(size_t)s2 * 64 + l];
      unsigned u3 = h1[(size_t)s3 * 64 + l];
      a0.x += bf16lo(u0); a0.y += bf16hi(u0);
      a1.x += bf16lo(u1); a1.y += bf16hi(u1);
      a2.x += bf16lo(u2); a2.y += bf16hi(u2);
      a3.x += bf16lo(u3); a3.y += bf16hi(u3);
    }
    for (; j < n; ++j){
      int s = __shfl(vid, j);
      unsigned u = h1[(size_t)s * 64 + l];
      a0.x += bf16lo(u); a0.y += bf16hi(u);
    }
  }
  #pragma unroll
  for (int off = 32; off > 0; off >>= 1) vmax = max(vmax, __shfl_xor(vmax, off));
  float inv = 1.0f / (float)max(me - mb, 1);
  float ox = (a0.x + a1.x + a2.x + a3.x) * inv;
  float oy = (a0.y + a1.y + a2.y + a3.y) * inv;
  hp[(size_t)c * 64 + l] = pack2(ox, oy);
  if (l == 0) batchp[c] = (vmax >= 0) ? batch[vmax] : 0;  // batch sorted by node id
}

__global__ void cntp_kernel(const int* __restrict__ batchp, int* __restrict__ cntp){
  int c = blockIdx.x * blockDim.x + threadIdx.x;
  if (c < N_CLUST) atomicAdd(&cntp[batchp[c]], 1);
}

// graph -> cluster CSR: scan cntp (64 entries) + cursor fill
__global__ void scan_cntp(const int* __restrict__ cntp, int* __restrict__ gbasep,
                          int* __restrict__ curp){
  int t = threadIdx.x;                 // 64 threads
  int v = cntp[t];
  int s = v;
  for (int off = 1; off < 64; off <<= 1){
    int u = __shfl_up(s, off);
    if (t >= off) s += u;
  }
  gbasep[t] = s - v; curp[t] = s - v;
  if (t == 63) gbasep[64] = s;
}

__global__ void fill_c(const int* __restrict__ batchp, int* __restrict__ curp,
                       int* __restrict__ cidx){
  int c = blockIdx.x * blockDim.x + threadIdx.x;
  if (c < N_CLUST) cidx[atomicAdd(&curp[batchp[c]], 1)] = c;
}

// ---------------------------------------------------------------------------
__global__ void graph_bounds(const int* __restrict__ batch, int* __restrict__ gstart){
  int g = threadIdx.x;
  if (g > N_GRAPH) return;
  int lo = 0, hi = N_NODES;
  while (lo < hi){ int mid = (lo + hi) >> 1; if (batch[mid] < g) lo = mid + 1; else hi = mid; }
  gstart[g] = lo;
}

__device__ __forceinline__ void atomicMaxPosF(float* addr, float v){
  atomicMax((int*)addr, __float_as_int(v));
}

// pre-pool gather: graph g's rows are contiguous [gstart[g], gstart[g+1])
constexpr int PRE_SPLIT = 4;
__launch_bounds__(256)
__global__ void pre_pool_g(const unsigned* __restrict__ h1, const int* __restrict__ gstart,
                           float* __restrict__ psum, float* __restrict__ pmax){
  int g = blockIdx.x / PRE_SPLIT, sp = blockIdx.x % PRE_SPLIT;
  int t = threadIdx.x, w = t >> 6, l = t & 63;
  int s0 = gstart[g], s1 = gstart[g + 1];
  int n = s1 - s0;
  int per = (n + PRE_SPLIT - 1) / PRE_SPLIT;
  int b0 = s0 + sp * per, b1 = min(b0 + per, s1);
  float2 a0{0.f,0.f}, a1{0.f,0.f}, a2{0.f,0.f}, a3{0.f,0.f};
  float2 mx{0.f,0.f};
  int i = b0 + w;
  for (; i + 12 < b1; i += 16){
    unsigned u0 = h1[(size_t)(i     ) * 64 + l];
    unsigned u1 = h1[(size_t)(i +  4) * 64 + l];
    unsigned u2 = h1[(size_t)(i +  8) * 64 + l];
    unsigned u3 = h1[(size_t)(i + 12) * 64 + l];
    float f0x = bf16lo(u0), f0y = bf16hi(u0);
    float f1x = bf16lo(u1), f1y = bf16hi(u1);
    float f2x = bf16lo(u2), f2y = bf16hi(u2);
    float f3x = bf16lo(u3), f3y = bf16hi(u3);
    a0.x += f0x; a0.y += f0y; a1.x += f1x; a1.y += f1y;
    a2.x += f2x; a2.y += f2y; a3.x += f3x; a3.y += f3y;
    mx.x = fmaxf(fmaxf(mx.x, fmaxf(f0x, f1x)), fmaxf(f2x, f3x));
    mx.y = fmaxf(fmaxf(mx.y, fmaxf(f0y, f1y)), fmaxf(f2y, f3y));
  }
  for (; i < b1; i += 4){
    unsigned u = h1[(size_t)i * 64 + l];
    float fx = bf16lo(u), fy = bf16hi(u);
    a0.x += fx; a0.y += fy;
    mx.x = fmaxf(mx.x, fx); mx.y = fmaxf(mx.y, fy);
  }
  __shared__ float2 ssum[4][64], smax[4][64];
  ssum[w][l] = { a0.x + a1.x + a2.x + a3.x, a0.y + a1.y + a2.y + a3.y };
  smax[w][l] = mx;
  __syncthreads();
  if (w == 0){
    float2 S = ssum[0][l], M = smax[0][l];
    #pragma unroll
    for (int k = 1; k < 4; ++k){
      S.x += ssum[k][l].x; S.y += ssum[k][l].y;
      M.x = fmaxf(M.x, smax[k][l].x); M.y = fmaxf(M.y, smax[k][l].y);
    }
    atomicAdd(&psum[g * 128 + 2 * l], S.x);
    atomicAdd(&psum[g * 128 + 2 * l + 1], S.y);
    atomicMaxPosF(&pmax[g * 128 + 2 * l], M.x);
    atomicMaxPosF(&pmax[g * 128 + 2 * l + 1], M.y);
  }
}

// post-pool gather via graph->cluster CSR
constexpr int POST_SPLIT = 2;
__launch_bounds__(256)
__global__ void post_pool_g(const unsigned* __restrict__ hp3, const int* __restrict__ gbasep,
                            const int* __restrict__ cidx,
                            float* __restrict__ psum, float* __restrict__ pmax){
  int g = blockIdx.x / POST_SPLIT, sp = blockIdx.x % POST_SPLIT;
  int t = threadIdx.x, w = t >> 6, l = t & 63;
  int s0 = gbasep[g], s1 = gbasep[g + 1];
  int n = s1 - s0;
  int per = (n + POST_SPLIT * 4 - 1) / (POST_SPLIT * 4);
  int b0 = s0 + (sp * 4 + w) * per, b1 = min(b0 + per, s1);
  float2 a0{0.f,0.f}, a1{0.f,0.f}, a2{0.f,0.f}, a3{0.f,0.f};
  float2 mx{0.f,0.f};
  for (int base = b0; base < b1; base += 64){
    int nn = min(64, b1 - base);
    int cid = cidx[base + min(l, nn - 1)];
    int j = 0;
    for (; j + 4 <= nn; j += 4){
      int c0 = __shfl(cid, j);
      int c1 = __shfl(cid, j + 1);
      int c2 = __shfl(cid, j + 2);
      int c3 = __shfl(cid, j + 3);
      unsigned u0 = hp3[(size_t)c0 * 64 + l];
      unsigned u1 = hp3[(size_t)c1 * 64 + l];
      unsigned u2 = hp3[(size_t)c2 * 64 + l];
      unsigned u3 = hp3[(size_t)c3 * 64 + l];
      float f0x = bf16lo(u0), f0y = bf16hi(u0);
      float f1x = bf16lo(u1), f1y = bf16hi(u1);
      float f2x = bf16lo(u2), f2y = bf16hi(u2);
      float f3x = bf16lo(u3), f3y = bf16hi(u3);
      a0.x += f0x; a0.y += f0y; a1.x += f1x; a1.y += f1y;
      a2.x += f2x; a2.y += f2y; a3.x += f3x; a3.y += f3y;
      mx.x = fmaxf(fmaxf(mx.x, fmaxf(f0x, f1x)), fmaxf(f2x, f3x));
      mx.y = fmaxf(fmaxf(mx.y, fmaxf(f0y, f1y)), fmaxf(f2y, f3y));
    }
    for (; j < nn; ++j){
      int c = __shfl(cid, j);
      unsigned u = hp3[(size_t)c * 64 + l];
      float fx = bf16lo(u), fy = bf16hi(u);
      a0.x += fx; a0.y += fy;
      mx.x = fmaxf(mx.x, fx); mx.y = fmaxf(mx.y, fy);
    }
  }
  __shared__ float2 ssum[4][64], smax[4][64];
  ssum[w][l] = { a0.x + a1.x + a2.x + a3.x, a0.y + a1.y + a2.y + a3.y };
  smax[w][l] = mx;
  __syncthreads();
  if (w == 0){
    float2 S = ssum[0][l], M = smax[0][l];
    #pragma unroll
    for (int k = 1; k < 4; ++k){
      S.x += ssum[k][l].x; S.y += ssum[k][l].y;
      M.x = fmaxf(M.x, smax[k][l].x); M.y = fmaxf(M.y, smax[k][l].y);
    }
    atomicAdd(&psum[g * 128 + 2 * l], S.x);
    atomicAdd(&psum[g * 128 + 2 * l + 1], S.y);
    atomicMaxPosF(&pmax[g * 128 + 2 * l], M.x);
    atomicMaxPosF(&pmax[g * 128 + 2 * l + 1], M.y);
  }
}

__launch_bounds__(128)
__global__ void head_kernel(const float* __restrict__ psum, const float* __restrict__ pmax,
                            const float* __restrict__ postsum, const float* __restrict__ postmax,
                            const int* __restrict__ gstart, const int* __restrict__ cntp,
                            const float* __restrict__ l1w, const float* __restrict__ l1b,
                            const float* __restrict__ l2w, const float* __restrict__ l2b,
                            float* __restrict__ out){
  int g = blockIdx.x, t = threadIdx.x;
  __shared__ float z[512];
  __shared__ float a[128];
  __shared__ float logits[16];
  __shared__ float lse_s;
  float cpre  = (float)max(gstart[g + 1] - gstart[g], 1);
  float cpost = fmaxf((float)cntp[g], 1.0f);
  z[t]       = psum[g * 128 + t] / cpre;
  z[128 + t] = pmax[g * 128 + t];
  z[256 + t] = postsum[g * 128 + t] / cpost;
  z[384 + t] = postmax[g * 128 + t];
  __syncthreads();
  float acc = l1b[t];
  #pragma unroll 8
  for (int k = 0; k < 512; ++k) acc = fmaf(z[k], l1w[k * 128 + t], acc);
  a[t] = fmaxf(acc, 0.f);
  __syncthreads();
  if (t < NCLSN){
    float s2 = l2b[t];
    for (int k = 0; k < 128; ++k) s2 = fmaf(a[k], l2w[k * NCLSN + t], s2);
    logits[t] = s2;
  }
  __syncthreads();
  if (t == 0){
    float m = logits[0];
    for (int c = 1; c < NCLSN; ++c) m = fmaxf(m, logits[c]);
    float s = 0.f;
    for (int c = 0; c < NCLSN; ++c) s += expf(logits[c] - m);
    lse_s = m + logf(s);
  }
  __syncthreads();
  if (t < NCLSN) out[g * NCLSN + t] = logits[t] - lse_s;
}

// ---------------------------------------------------------------------------
extern "C" void kernel_launch(void* const* d_in, const int* in_sizes, int n_in,
                              void* d_out, int out_size, void* d_ws, size_t ws_size,
                              hipStream_t stream){
  const float* x       = (const float*)d_in[0];
  const int*   ei      = (const int*)  d_in[1];
  const int*   batch   = (const int*)  d_in[2];
  const int*   cluster = (const int*)  d_in[3];
  const float* W1      = (const float*)d_in[6];
  const float* b1      = (const float*)d_in[7];
  const float* W2      = (const float*)d_in[8];
  const float* b2      = (const float*)d_in[9];
  const float* W3      = (const float*)d_in[10];
  const float* b3      = (const float*)d_in[11];
  const float* l1w     = (const float*)d_in[12];
  const float* l1b     = (const float*)d_in[13];
  const float* l2w     = (const float*)d_in[14];
  const float* l2b     = (const float*)d_in[15];
  float* out = (float*)d_out;

  char* base = (char*)d_ws;
  size_t off = 0;
  auto alloc = [&](size_t bytes) -> char* {
    char* p = base + off;
    off += (bytes + 255) & ~size_t(255);
    return p;
  };
  // ---- zero zone (one memset) ----
  char*  zbase  = base + off;
  int*   gcnt1  = (int*)  alloc((size_t)NBKT1 * 4);
  int*   gcnt2  = (int*)  alloc((size_t)NBKT2 * 4);
  int*   cntn   = (int*)  alloc((size_t)N_CLUST * 4);
  int*   cntp   = (int*)  alloc((size_t)N_GRAPH * 4);
  float* pre_s  = (float*)alloc((size_t)N_GRAPH * 128 * 4);
  float* pre_m  = (float*)alloc((size_t)N_GRAPH * 128 * 4);
  float* post_s = (float*)alloc((size_t)N_GRAPH * 128 * 4);
  float* post_m = (float*)alloc((size_t)N_GRAPH * 128 * 4);
  size_t zsize = off;
  // ---- plain buffers (bf16 feature rows: 64 uints per row) ----
  unsigned* Ts1   = (unsigned*)alloc((size_t)N_NODES * 64 * 4);  // later aliased
  unsigned* h1    = (unsigned*)alloc((size_t)N_NODES * 64 * 4);  // stage bufs alias here
  int*   esrc1   = (int*)  alloc((size_t)N_EDGES * 4);
  int*   psrcC   = (int*)  alloc((size_t)N_EDGES * 4);
  int*   deg1    = (int*)  alloc((size_t)N_NODES * 4);
  int*   deg2    = (int*)  alloc((size_t)N_CLUST * 4);
  int*   rowptr1 = (int*)  alloc((size_t)(N_NODES + 1) * 4);
  int*   rowptrn = (int*)  alloc((size_t)(N_CLUST + 1) * 4);
  int*   curn    = (int*)  alloc((size_t)N_CLUST * 4);
  int*   rowptr2 = (int*)  alloc((size_t)(N_CLUST + 1) * 4);
  int*   nidx    = (int*)  alloc((size_t)N_NODES * 4);
  float* dis1    = (float*)alloc((size_t)N_NODES * 4);
  float* dis2    = (float*)alloc((size_t)N_CLUST * 4);
  int*   batchp  = (int*)  alloc((size_t)N_CLUST * 4);
  int*   gstart  = (int*)  alloc((size_t)(N_GRAPH + 1) * 4);
  int*   bsum    = (int*)  alloc((size_t)NBT * 4);
  int*   boff    = (int*)  alloc((size_t)NBT * 4);
  int*   gbase1  = (int*)  alloc((size_t)NBKT1 * 4);
  int*   gcur1   = (int*)  alloc((size_t)NBKT1 * 4);
  int*   gbase2  = (int*)  alloc((size_t)NBKT2 * 4);
  int*   gcur2   = (int*)  alloc((size_t)NBKT2 * 4);
  int*   gbasep  = (int*)  alloc((size_t)(N_GRAPH + 1) * 4);
  int*   curp    = (int*)  alloc((size_t)N_GRAPH * 4);
  int*   cidx    = (int*)  alloc((size_t)N_CLUST * 4);
  // stage buffers alias the (not-yet-written) h1 region (12.8 MB <= 25.6 MB)
  unsigned int* stage1 = (unsigned int*)h1;
  unsigned int* stage2 = stage1 + N_EDGES;
  // aliases into Ts1 (dead after conv1): 4 x 25000*64 uints = exactly Ts1 size
  unsigned* hp  = Ts1;
  unsigned* Ts2 = Ts1 + (size_t)N_CLUST * 64;
  unsigned* hp2 = Ts1 + (size_t)2 * N_CLUST * 64;
  unsigned* hp3 = Ts1 + (size_t)3 * N_CLUST * 64;
  unsigned* Ts3 = Ts2;

  (void)in_sizes; (void)n_in; (void)out_size; (void)ws_size;

  hipMemsetAsync(zbase, 0, zsize, stream);

  // ---- sort-based CSR build ----
  count_kernel  <<<NEB, 256, 0, stream>>>(ei, cluster, gcnt1, gcnt2);
  cntn_kernel   <<<(N_NODES + 255) / 256, 256, 0, stream>>>(cluster, cntn);
  bucket_scan   <<<1, 256, 0, stream>>>(gcnt1, gcnt2, gbase1, gcur1, gbase2, gcur2);
  scatter_kernel<<<NEB, 256, 0, stream>>>(ei, cluster, gcur1, gcur2, stage1, stage2);
  bucket_sort<512, 17><<<NBKT1, 256, 0, stream>>>(stage1, gbase1, gcnt1, esrc1, deg1, N_NODES);
  bucket_sort<128, 15><<<NBKT2, 256, 0, stream>>>(stage2, gbase2, gcnt2, psrcC, deg2, N_CLUST);
  block_sums <<<NBT, 256, 0, stream>>>(deg1, cntn, deg2, bsum);
  scan_bsums <<<1, 256, 0, stream>>>(bsum, boff, rowptr1, rowptrn, rowptr2);
  scan_final <<<NBT, 256, 0, stream>>>(deg1, cntn, deg2, boff,
                                       rowptr1, dis1, rowptrn, curn, rowptr2, dis2);
  fill_n<<<(N_NODES + 255) / 256, 256, 0, stream>>>(cluster, curn, nidx);

  // conv1
  gemm_mfma<false><<<(N_NODES + 63) / 64, 256, 0, stream>>>(x, W1, dis1, Ts1, N_NODES);
  conv_csr<<<N_NODES / 4, 256, 0, stream>>>(Ts1, dis1, rowptr1, esrc1, b1, h1);

  // pre pools (gather over contiguous sorted-batch ranges)
  graph_bounds<<<1, 128, 0, stream>>>(batch, gstart);
  pre_pool_g<<<N_GRAPH * PRE_SPLIT, 256, 0, stream>>>(h1, gstart, pre_s, pre_m);

  // cluster mean pool + batch_p + cntp + graph->cluster CSR
  cluster_gather<<<N_CLUST / 4, 256, 0, stream>>>(h1, rowptrn, nidx, batch, hp, batchp);
  cntp_kernel<<<(N_CLUST + 255) / 256, 256, 0, stream>>>(batchp, cntp);
  scan_cntp<<<1, 64, 0, stream>>>(cntp, gbasep, curp);
  fill_c<<<(N_CLUST + 255) / 256, 256, 0, stream>>>(batchp, curp, cidx);

  // conv2
  gemm_mfma<true><<<(N_CLUST + 63) / 64, 256, 0, stream>>>(hp, W2, dis2, Ts2, N_CLUST);
  conv_csr<<<N_CLUST / 4, 256, 0, stream>>>(Ts2, dis2, rowptr2, psrcC, b2, hp2);

  // conv3
  gemm_mfma<true><<<(N_CLUST + 63) / 64, 256, 0, stream>>>(hp2, W3, dis2, Ts3, N_CLUST);
  conv_csr<<<N_CLUST / 4, 256, 0, stream>>>(Ts3, dis2, rowptr2, psrcC, b3, hp3);

  // post pools (gather via graph->cluster CSR) + head
  post_pool_g<<<N_GRAPH * POST_SPLIT, 256, 0, stream>>>(hp3, gbasep, cidx, post_s, post_m);
  head_kernel<<<N_GRAPH, 128, 0, stream>>>(pre_s, pre_m, post_s, post_m, gstart, cntp,
                                           l1w, l1b, l2w, l2b, out);
}

// Round 10
// 608.011 us; speedup vs baseline: 2.7260x; 1.0667x over previous
//
#include <hip/hip_runtime.h>

constexpr int N_NODES = 100000;
constexpr int N_EDGES = 1600000;
constexpr int N_CLUST = 25000;
constexpr int N_GRAPH = 64;
constexpr int NCLSN   = 10;

// bucket decomposition for the sort-based node-CSR build
constexpr int BKT1_SHIFT = 9;                       // node-dst buckets of 512 ids
constexpr int NBKT1 = (N_NODES + 511) / 512;        // 196
constexpr int EPB = 4096;                           // edges per block (count/scatter)
constexpr int NEB = (N_EDGES + EPB - 1) / EPB;      // 391
constexpr int SORT_CAP = 12288;                     // LDS staging cap (mean 8163, sd ~90)

// scan partitioning: 1024 elements per block, three concatenated segments
constexpr int SCAN_BPB = 1024;
constexpr int NB1 = (N_NODES + SCAN_BPB - 1) / SCAN_BPB;  // 98
constexpr int NB2 = (N_CLUST + SCAN_BPB - 1) / SCAN_BPB;  // 25
constexpr int NB3 = (N_CLUST + SCAN_BPB - 1) / SCAN_BPB;  // 25
constexpr int NBT = NB1 + NB2 + NB3;                      // 148

// ---- bf16 pack/unpack helpers (features stored as packed pairs in uint) ----
__device__ __forceinline__ float bf16lo(unsigned u){ return __uint_as_float(u << 16); }
__device__ __forceinline__ float bf16hi(unsigned u){ return __uint_as_float(u & 0xffff0000u); }
__device__ __forceinline__ unsigned bf16_rne(float f){
  unsigned u = __float_as_uint(f);
  return (u + 0x7fffu + ((u >> 16) & 1u)) >> 16;
}
__device__ __forceinline__ unsigned pack2(float lo, float hi){
  return bf16_rne(lo) | (bf16_rne(hi) << 16);
}

typedef short bf16x8 __attribute__((ext_vector_type(8)));
typedef float f32x4  __attribute__((ext_vector_type(4)));

// ---------------------------------------------------------------------------
// bucket-sort node-CSR build, phase 1: LDS-aggregated bucket counts (dst only)
// ---------------------------------------------------------------------------
__launch_bounds__(256)
__global__ void count_kernel(const int* __restrict__ ei, int* __restrict__ gcnt1){
  __shared__ int h1c[NBKT1];
  int t = threadIdx.x;
  for (int i = t; i < NBKT1; i += 256) h1c[i] = 0;
  __syncthreads();
  int e0 = blockIdx.x * EPB;
  #pragma unroll
  for (int i = 0; i < EPB / 256; ++i){
    int e = e0 + i * 256 + t;
    if (e < N_EDGES) atomicAdd(&h1c[ei[N_EDGES + e] >> BKT1_SHIFT], 1);
  }
  __syncthreads();
  for (int i = t; i < NBKT1; i += 256) if (h1c[i]) atomicAdd(&gcnt1[i], h1c[i]);
}

// phase 2: bucket bases
__launch_bounds__(256)
__global__ void bucket_scan(const int* __restrict__ gcnt1,
                            int* __restrict__ gbase1, int* __restrict__ gcur1){
  __shared__ int s[256];
  int t = threadIdx.x;
  int v = (t < NBKT1) ? gcnt1[t] : 0;
  s[t] = v; __syncthreads();
  for (int off = 1; off < 256; off <<= 1){
    int a = (t >= off) ? s[t - off] : 0;
    __syncthreads(); s[t] += a; __syncthreads();
  }
  if (t < NBKT1){ gbase1[t] = s[t] - v; gcur1[t] = s[t] - v; }
}

// phase 3: scatter packed words into bucket regions (per-block reserved runs)
__launch_bounds__(256)
__global__ void scatter_kernel(const int* __restrict__ ei, int* __restrict__ gcur1,
                               unsigned int* __restrict__ stage1){
  __shared__ int h1c[NBKT1];
  __shared__ int gb1[NBKT1];
  int t = threadIdx.x;
  for (int i = t; i < NBKT1; i += 256) h1c[i] = 0;
  __syncthreads();
  int e0 = blockIdx.x * EPB;
  #pragma unroll
  for (int i = 0; i < EPB / 256; ++i){
    int e = e0 + i * 256 + t;
    if (e < N_EDGES) atomicAdd(&h1c[ei[N_EDGES + e] >> BKT1_SHIFT], 1);
  }
  __syncthreads();
  for (int i = t; i < NBKT1; i += 256){ int c = h1c[i]; gb1[i] = c ? atomicAdd(&gcur1[i], c) : 0; }
  __syncthreads();
  for (int i = t; i < NBKT1; i += 256) h1c[i] = 0;   // reuse as local cursors
  __syncthreads();
  #pragma unroll
  for (int i = 0; i < EPB / 256; ++i){
    int e = e0 + i * 256 + t;
    if (e < N_EDGES){
      int src = ei[e], dst = ei[N_EDGES + e];
      int b1 = dst >> BKT1_SHIFT;
      int r1 = atomicAdd(&h1c[b1], 1);
      stage1[gb1[b1] + r1] = ((unsigned)(dst & 511) << 17) | (unsigned)src;
    }
  }
}

// phase 4: per-bucket LDS counting sort + coalesced degree writes
template<int NBINS, int PSHIFT>
__launch_bounds__(256)
__global__ void bucket_sort(const unsigned int* __restrict__ stage, const int* __restrict__ gbase,
                            const int* __restrict__ gcnt, int* __restrict__ outpay,
                            int* __restrict__ deg, int ntot){
  __shared__ int cnt[NBINS], off[NBINS];
  __shared__ int sorted[SORT_CAP];
  int b = blockIdx.x, t = threadIdx.x;
  int base = gbase[b], n = gcnt[b];
  for (int i = t; i < NBINS; i += 256) cnt[i] = 0;
  __syncthreads();
  for (int i = t; i < n; i += 256) atomicAdd(&cnt[stage[base + i] >> PSHIFT], 1);
  __syncthreads();
  for (int i = t; i < NBINS; i += 256){
    int idx = b * NBINS + i;
    if (idx < ntot) deg[idx] = cnt[i];
    off[i] = cnt[i];
  }
  __syncthreads();
  for (int s = 1; s < NBINS; s <<= 1){
    int v0 = 0, v1 = 0;
    if (t < NBINS && t >= s) v0 = off[t - s];
    if (NBINS > 256 && t + 256 < NBINS && t + 256 >= s) v1 = off[t + 256 - s];
    __syncthreads();
    if (t < NBINS) off[t] += v0;
    if (NBINS > 256 && t + 256 < NBINS) off[t + 256] += v1;
    __syncthreads();
  }
  for (int i = t; i < NBINS; i += 256) off[i] -= cnt[i];   // exclusive cursors
  __syncthreads();
  constexpr unsigned PMASK = (1u << PSHIFT) - 1u;
  if (n <= SORT_CAP){
    for (int i = t; i < n; i += 256){
      unsigned w = stage[base + i];
      int r = atomicAdd(&off[w >> PSHIFT], 1);
      sorted[r] = (int)(w & PMASK);
    }
    __syncthreads();
    for (int i = t; i < n; i += 256) outpay[base + i] = sorted[i];
  } else {
    for (int i = t; i < n; i += 256){
      unsigned w = stage[base + i];
      int r = atomicAdd(&off[w >> PSHIFT], 1);
      outpay[base + r] = (int)(w & PMASK);
    }
  }
}

// per-node: cluster membership count + cluster in-degree (sum of member deg1)
__global__ void node_prep(const int* __restrict__ cluster, const int* __restrict__ deg1,
                          int* __restrict__ cntn, int* __restrict__ deg2){
  int v = blockIdx.x * blockDim.x + threadIdx.x;
  if (v < N_NODES){
    int c = cluster[v];
    atomicAdd(&cntn[c], 1);
    atomicAdd(&deg2[c], deg1[v]);
  }
}

// ---------------------------------------------------------------------------
// device-wide 3-segment exclusive scan
// ---------------------------------------------------------------------------
__device__ __forceinline__ void seg_select(int b, const int* deg1, const int* cntn,
                                           const int* deg2, const int*& src, int& n, int& base){
  if (b < NB1){ src = deg1; n = N_NODES; base = b * SCAN_BPB; }
  else if (b < NB1 + NB2){ src = cntn; n = N_CLUST; base = (b - NB1) * SCAN_BPB; }
  else { src = deg2; n = N_CLUST; base = (b - NB1 - NB2) * SCAN_BPB; }
}

__launch_bounds__(256)
__global__ void block_sums(const int* __restrict__ deg1, const int* __restrict__ cntn,
                           const int* __restrict__ deg2, int* __restrict__ bsum){
  int b = blockIdx.x;
  const int* src; int n, base;
  seg_select(b, deg1, cntn, deg2, src, n, base);
  int t = threadIdx.x;
  int i0 = base + t * 4;
  int s = 0;
  if (i0 + 3 < n){ int4 v = *(const int4*)&src[i0]; s = v.x + v.y + v.z + v.w; }
  else { for (int j = 0; j < 4; ++j){ int i = i0 + j; if (i < n) s += src[i]; } }
  __shared__ int sh[256];
  sh[t] = s; __syncthreads();
  for (int off = 128; off > 0; off >>= 1){
    if (t < off) sh[t] += sh[t + off];
    __syncthreads();
  }
  if (t == 0) bsum[b] = sh[0];
}

__launch_bounds__(256)
__global__ void scan_bsums(const int* __restrict__ bsum, int* __restrict__ boff,
                           int* __restrict__ rowptr1, int* __restrict__ rowptrn,
                           int* __restrict__ rowptr2){
  __shared__ int s[256];
  int t = threadIdx.x;
  int v = (t < NBT) ? bsum[t] : 0;
  s[t] = v; __syncthreads();
  int seg = (t < NB1) ? 0 : (t < NB1 + NB2 ? 1 : 2);
  for (int off = 1; off < 256; off <<= 1){
    int add = 0;
    if (t >= off){
      int u = t - off;
      int useg = (u < NB1) ? 0 : (u < NB1 + NB2 ? 1 : 2);
      if (useg == seg) add = s[u];
    }
    __syncthreads();
    s[t] += add;
    __syncthreads();
  }
  if (t < NBT) boff[t] = s[t] - v;
  if (t == NB1 - 1)       rowptr1[N_NODES] = s[t];
  if (t == NB1 + NB2 - 1) rowptrn[N_CLUST] = s[t];
  if (t == NBT - 1)       rowptr2[N_CLUST] = s[t];
}

__launch_bounds__(256)
__global__ void scan_final(const int* __restrict__ deg1, const int* __restrict__ cntn,
                           const int* __restrict__ deg2, const int* __restrict__ boff,
                           int* __restrict__ rowptr1, float* __restrict__ dis1,
                           int* __restrict__ rowptrn, int* __restrict__ curn,
                           int* __restrict__ rowptr2, float* __restrict__ dis2){
  int b = blockIdx.x;
  const int* src; int n, base;
  seg_select(b, deg1, cntn, deg2, src, n, base);
  int* rp; int* cur; float* dis;
  if (b < NB1){ rp = rowptr1; cur = nullptr; dis = dis1; }
  else if (b < NB1 + NB2){ rp = rowptrn; cur = curn; dis = nullptr; }
  else { rp = rowptr2; cur = nullptr; dis = dis2; }
  int t = threadIdx.x;
  int i0 = base + t * 4;
  int v[4]; int s = 0;
  #pragma unroll
  for (int j = 0; j < 4; ++j){ int i = i0 + j; v[j] = (i < n) ? src[i] : 0; s += v[j]; }
  __shared__ int sh[256];
  sh[t] = s; __syncthreads();
  for (int off = 1; off < 256; off <<= 1){
    int add = (t >= off) ? sh[t - off] : 0;
    __syncthreads();
    sh[t] += add;
    __syncthreads();
  }
  int run = sh[t] - s + boff[b];
  #pragma unroll
  for (int j = 0; j < 4; ++j){
    int i = i0 + j;
    if (i < n){
      rp[i] = run;
      if (cur) cur[i] = run;
      if (dis) dis[i] = rsqrtf((float)v[j] + 1.0f);
      run += v[j];
    }
  }
}

// node->cluster CSR fill
__global__ void fill_n(const int* __restrict__ cluster, int* __restrict__ curn,
                       int* __restrict__ nidx){
  int v = blockIdx.x * blockDim.x + threadIdx.x;
  if (v >= N_NODES) return;
  nidx[atomicAdd(&curn[cluster[v]], 1)] = v;
}

// ---------------------------------------------------------------------------
// psrcC build: cluster c's pooled-edge list = concat of members' edge runs,
// mapped through cluster[]. One wave per cluster; flat index -> (member, edge)
// via wave-scan of member degrees. Writes fully coalesced.
// ---------------------------------------------------------------------------
__launch_bounds__(256)
__global__ void psrc_build(const int* __restrict__ rowptrn, const int* __restrict__ nidx,
                           const int* __restrict__ rowptr1, const int* __restrict__ esrc1,
                           const int* __restrict__ cluster, const int* __restrict__ rowptr2,
                           int* __restrict__ psrcC){
  int c = blockIdx.x * 4 + (threadIdx.x >> 6);
  int l = threadIdx.x & 63;
  int mb = rowptrn[c], me = rowptrn[c + 1];
  int cnt = me - mb;                       // members per cluster (<= 64)
  int base_l = 0, d_l = 0;
  if (l < cnt){
    int v = nidx[mb + l];
    base_l = rowptr1[v];
    d_l = rowptr1[v + 1] - base_l;
  }
  int pref = d_l;                          // inclusive scan over 64 lanes
  #pragma unroll
  for (int off = 1; off < 64; off <<= 1){
    int u = __shfl_up(pref, off);
    if (l >= off) pref += u;
  }
  int total = __shfl(pref, 63);
  int wbase = rowptr2[c];
  int iters = (total + 63) >> 6;           // uniform loop; all lanes active
  for (int k = 0; k < iters; ++k){
    int idx = k * 64 + l;
    int idxc = min(idx, total - 1);        // clamp so search/load stay valid
    int m = 0;
    for (int j = 0; j < cnt; ++j){         // cnt is wave-uniform; all lanes active
      int pj = __shfl(pref, j);
      if (idxc >= pj) m = j + 1;
    }
    int pm = __shfl(pref, m);
    int dm = __shfl(d_l, m);
    int bm = __shfl(base_l, m);
    int e = bm + idxc - (pm - dm);
    int sc = cluster[esrc1[e]];
    if (idx < total) psrcC[wbase + idx] = sc;
  }
}

// ---------------------------------------------------------------------------
// MFMA GEMM: C[M,128] = (A[M,128] @ B[128,128]) * scale[row], bf16 packed out
// ---------------------------------------------------------------------------
template<bool A_BF16>
__launch_bounds__(256)
__global__ void gemm_mfma(const void* __restrict__ Aptr, const float* __restrict__ B,
                          const float* __restrict__ scale, unsigned* __restrict__ Cmat,
                          int M){
  __shared__ __align__(16) unsigned Blds[128 * 68];
  __shared__ __align__(16) unsigned Alds[64 * 68];
  const int t = threadIdx.x;
  const int row0 = blockIdx.x * 64;

  #pragma unroll
  for (int i = 0; i < 8; ++i){
    int task = t + i * 256;
    int kp = task >> 5, nq = task & 31;
    float4 b0 = *(const float4*)&B[(2 * kp) * 128 + nq * 4];
    float4 b1 = *(const float4*)&B[(2 * kp + 1) * 128 + nq * 4];
    Blds[(nq * 4 + 0) * 68 + kp] = pack2(b0.x, b1.x);
    Blds[(nq * 4 + 1) * 68 + kp] = pack2(b0.y, b1.y);
    Blds[(nq * 4 + 2) * 68 + kp] = pack2(b0.z, b1.z);
    Blds[(nq * 4 + 3) * 68 + kp] = pack2(b0.w, b1.w);
  }
  if (A_BF16){
    const unsigned* A = (const unsigned*)Aptr;
    #pragma unroll
    for (int i = 0; i < 8; ++i){
      int idx = t + i * 256;
      int row = idx >> 5, c2 = idx & 31;
      int grow = min(row0 + row, M - 1);
      uint2 v = *(const uint2*)&A[(size_t)grow * 64 + c2 * 2];
      Alds[row * 68 + c2 * 2]     = v.x;
      Alds[row * 68 + c2 * 2 + 1] = v.y;
    }
  } else {
    const float* A = (const float*)Aptr;
    #pragma unroll
    for (int i = 0; i < 8; ++i){
      int idx = t + i * 256;
      int row = idx >> 5, k4 = idx & 31;
      int grow = min(row0 + row, M - 1);
      float4 v = *(const float4*)&A[(size_t)grow * 128 + k4 * 4];
      Alds[row * 68 + k4 * 2]     = pack2(v.x, v.y);
      Alds[row * 68 + k4 * 2 + 1] = pack2(v.z, v.w);
    }
  }
  __syncthreads();

  const int wv = t >> 6, l = t & 63, quad = l >> 4, n16 = l & 15;
  f32x4 acc[8];
  #pragma unroll
  for (int nt = 0; nt < 8; ++nt) acc[nt] = (f32x4){0.f, 0.f, 0.f, 0.f};
  const int arow = wv * 16 + n16;
  #pragma unroll
  for (int ks = 0; ks < 4; ++ks){
    bf16x8 af = *(const bf16x8*)&Alds[arow * 68 + ks * 16 + quad * 4];
    #pragma unroll
    for (int nt = 0; nt < 8; ++nt){
      bf16x8 bfr = *(const bf16x8*)&Blds[(nt * 16 + n16) * 68 + ks * 16 + quad * 4];
      acc[nt] = __builtin_amdgcn_mfma_f32_16x16x32_bf16(af, bfr, acc[nt], 0, 0, 0);
    }
  }
  #pragma unroll
  for (int nt = 0; nt < 8; ++nt){
    #pragma unroll
    for (int r = 0; r < 4; ++r){
      int row = row0 + wv * 16 + quad * 4 + r;
      float sc = scale[min(row, M - 1)];
      float v = acc[nt][r] * sc;
      float vhi = __shfl_xor(v, 1);
      if (((l & 1) == 0) && row < M)
        Cmat[(size_t)row * 64 + nt * 8 + (n16 >> 1)] = pack2(v, vhi);
    }
  }
}

// ---------------------------------------------------------------------------
// CSR conv over bf16 rows: out[i] = relu( dis[i]*(sum_e Ts[src_e] + Ts[i]) + b )
// ---------------------------------------------------------------------------
__launch_bounds__(256)
__global__ void conv_csr(const unsigned* __restrict__ Ts, const float* __restrict__ dis,
                         const int* __restrict__ rowptr, const int* __restrict__ esrc,
                         const float* __restrict__ bias, unsigned* __restrict__ Hout){
  int w = blockIdx.x * 4 + (threadIdx.x >> 6);
  int l = threadIdx.x & 63;
  int beg = rowptr[w], end = rowptr[w + 1];
  float2 a0{0.f,0.f}, a1{0.f,0.f}, a2{0.f,0.f}, a3{0.f,0.f};
  for (int base = beg; base < end; base += 64){
    int n = min(64, end - base);
    int eid = esrc[base + min(l, n - 1)];
    int j = 0;
    for (; j + 4 <= n; j += 4){
      int s0 = __shfl(eid, j);
      int s1 = __shfl(eid, j + 1);
      int s2 = __shfl(eid, j + 2);
      int s3 = __shfl(eid, j + 3);
      unsigned u0 = Ts[(size_t)s0 * 64 + l];
      unsigned u1 = Ts[(size_t)s1 * 64 + l];
      unsigned u2 = Ts[(size_t)s2 * 64 + l];
      unsigned u3 = Ts[(size_t)s3 * 64 + l];
      a0.x += bf16lo(u0); a0.y += bf16hi(u0);
      a1.x += bf16lo(u1); a1.y += bf16hi(u1);
      a2.x += bf16lo(u2); a2.y += bf16hi(u2);
      a3.x += bf16lo(u3); a3.y += bf16hi(u3);
    }
    for (; j < n; ++j){
      int s = __shfl(eid, j);
      unsigned u = Ts[(size_t)s * 64 + l];
      a0.x += bf16lo(u); a0.y += bf16hi(u);
    }
  }
  float d = dis[w];
  unsigned us = Ts[(size_t)w * 64 + l];
  float2 bb = *(const float2*)&bias[l * 2];
  float rx = fmaxf(fmaf(d, a0.x + a1.x + a2.x + a3.x + bf16lo(us), bb.x), 0.f);
  float ry = fmaxf(fmaf(d, a0.y + a1.y + a2.y + a3.y + bf16hi(us), bb.y), 0.f);
  Hout[(size_t)w * 64 + l] = pack2(rx, ry);
}

// cluster mean pool + batch_p over bf16 rows
__launch_bounds__(256)
__global__ void cluster_gather(const unsigned* __restrict__ h1, const int* __restrict__ rowptrn,
                               const int* __restrict__ nidx, const int* __restrict__ batch,
                               unsigned* __restrict__ hp, int* __restrict__ batchp){
  int c = blockIdx.x * 4 + (threadIdx.x >> 6);
  int l = threadIdx.x & 63;
  int mb = rowptrn[c], me = rowptrn[c + 1];
  float2 a0{0.f,0.f}, a1{0.f,0.f}, a2{0.f,0.f}, a3{0.f,0.f};
  int vmax = -1;
  for (int base = mb; base < me; base += 64){
    int n = min(64, me - base);
    int vid = nidx[base + min(l, n - 1)];
    if (l < n) vmax = max(vmax, vid);
    int j = 0;
    for (; j + 4 <= n; j += 4){
      int s0 = __shfl(vid, j);
      int s1 = __shfl(vid, j + 1);
      int s2 = __shfl(vid, j + 2);
      int s3 = __shfl(vid, j + 3);
      unsigned u0 = h1[(size_t)s0 * 64 + l];
      unsigned u1 = h1[(size_t)s1 * 64 + l];
      unsigned u2 = h1[(size_t)s2 * 64 + l];
      unsigned u3 = h1[(size_t)s3 * 64 + l];
      a0.x += bf16lo(u0); a0.y += bf16hi(u0);
      a1.x += bf16lo(u1); a1.y += bf16hi(u1);
      a2.x += bf16lo(u2); a2.y += bf16hi(u2);
      a3.x += bf16lo(u3); a3.y += bf16hi(u3);
    }
    for (; j < n; ++j){
      int s = __shfl(vid, j);
      unsigned u = h1[(size_t)s * 64 + l];
      a0.x += bf16lo(u); a0.y += bf16hi(u);
    }
  }
  #pragma unroll
  for (int off = 32; off > 0; off >>= 1) vmax = max(vmax, __shfl_xor(vmax, off));
  float inv = 1.0f / (float)max(me - mb, 1);
  float ox = (a0.x + a1.x + a2.x + a3.x) * inv;
  float oy = (a0.y + a1.y + a2.y + a3.y) * inv;
  hp[(size_t)c * 64 + l] = pack2(ox, oy);
  if (l == 0) batchp[c] = (vmax >= 0) ? batch[vmax] : 0;  // batch sorted by node id
}

__global__ void cntp_kernel(const int* __restrict__ batchp, int* __restrict__ cntp){
  int c = blockIdx.x * blockDim.x + threadIdx.x;
  if (c < N_CLUST) atomicAdd(&cntp[batchp[c]], 1);
}

// graph -> cluster CSR: scan cntp (64 entries) + cursor fill
__global__ void scan_cntp(const int* __restrict__ cntp, int* __restrict__ gbasep,
                          int* __restrict__ curp){
  int t = threadIdx.x;                 // 64 threads
  int v = cntp[t];
  int s = v;
  for (int off = 1; off < 64; off <<= 1){
    int u = __shfl_up(s, off);
    if (t >= off) s += u;
  }
  gbasep[t] = s - v; curp[t] = s - v;
  if (t == 63) gbasep[64] = s;
}

__global__ void fill_c(const int* __restrict__ batchp, int* __restrict__ curp,
                       int* __restrict__ cidx){
  int c = blockIdx.x * blockDim.x + threadIdx.x;
  if (c < N_CLUST) cidx[atomicAdd(&curp[batchp[c]], 1)] = c;
}

// ---------------------------------------------------------------------------
__global__ void graph_bounds(const int* __restrict__ batch, int* __restrict__ gstart){
  int g = threadIdx.x;
  if (g > N_GRAPH) return;
  int lo = 0, hi = N_NODES;
  while (lo < hi){ int mid = (lo + hi) >> 1; if (batch[mid] < g) lo = mid + 1; else hi = mid; }
  gstart[g] = lo;
}

__device__ __forceinline__ void atomicMaxPosF(float* addr, float v){
  atomicMax((int*)addr, __float_as_int(v));
}

// pre-pool gather: graph g's rows are contiguous [gstart[g], gstart[g+1])
constexpr int PRE_SPLIT = 4;
__launch_bounds__(256)
__global__ void pre_pool_g(const unsigned* __restrict__ h1, const int* __restrict__ gstart,
                           float* __restrict__ psum, float* __restrict__ pmax){
  int g = blockIdx.x / PRE_SPLIT, sp = blockIdx.x % PRE_SPLIT;
  int t = threadIdx.x, w = t >> 6, l = t & 63;
  int s0 = gstart[g], s1 = gstart[g + 1];
  int n = s1 - s0;
  int per = (n + PRE_SPLIT - 1) / PRE_SPLIT;
  int b0 = s0 + sp * per, b1 = min(b0 + per, s1);
  float2 a0{0.f,0.f}, a1{0.f,0.f}, a2{0.f,0.f}, a3{0.f,0.f};
  float2 mx{0.f,0.f};
  int i = b0 + w;
  for (; i + 12 < b1; i += 16){
    unsigned u0 = h1[(size_t)(i     ) * 64 + l];
    unsigned u1 = h1[(size_t)(i +  4) * 64 + l];
    unsigned u2 = h1[(size_t)(i +  8) * 64 + l];
    unsigned u3 = h1[(size_t)(i + 12) * 64 + l];
    float f0x = bf16lo(u0), f0y = bf16hi(u0);
    float f1x = bf16lo(u1), f1y = bf16hi(u1);
    float f2x = bf16lo(u2), f2y = bf16hi(u2);
    float f3x = bf16lo(u3), f3y = bf16hi(u3);
    a0.x += f0x; a0.y += f0y; a1.x += f1x; a1.y += f1y;
    a2.x += f2x; a2.y += f2y; a3.x += f3x; a3.y += f3y;
    mx.x = fmaxf(fmaxf(mx.x, fmaxf(f0x, f1x)), fmaxf(f2x, f3x));
    mx.y = fmaxf(fmaxf(mx.y, fmaxf(f0y, f1y)), fmaxf(f2y, f3y));
  }
  for (; i < b1; i += 4){
    unsigned u = h1[(size_t)i * 64 + l];
    float fx = bf16lo(u), fy = bf16hi(u);
    a0.x += fx; a0.y += fy;
    mx.x = fmaxf(mx.x, fx); mx.y = fmaxf(mx.y, fy);
  }
  __shared__ float2 ssum[4][64], smax[4][64];
  ssum[w][l] = { a0.x + a1.x + a2.x + a3.x, a0.y + a1.y + a2.y + a3.y };
  smax[w][l] = mx;
  __syncthreads();
  if (w == 0){
    float2 S = ssum[0][l], M = smax[0][l];
    #pragma unroll
    for (int k = 1; k < 4; ++k){
      S.x += ssum[k][l].x; S.y += ssum[k][l].y;
      M.x = fmaxf(M.x, smax[k][l].x); M.y = fmaxf(M.y, smax[k][l].y);
    }
    atomicAdd(&psum[g * 128 + 2 * l], S.x);
    atomicAdd(&psum[g * 128 + 2 * l + 1], S.y);
    atomicMaxPosF(&pmax[g * 128 + 2 * l], M.x);
    atomicMaxPosF(&pmax[g * 128 + 2 * l + 1], M.y);
  }
}

// post-pool gather via graph->cluster CSR
constexpr int POST_SPLIT = 2;
__launch_bounds__(256)
__global__ void post_pool_g(const unsigned* __restrict__ hp3, const int* __restrict__ gbasep,
                            const int* __restrict__ cidx,
                            float* __restrict__ psum, float* __restrict__ pmax){
  int g = blockIdx.x / POST_SPLIT, sp = blockIdx.x % POST_SPLIT;
  int t = threadIdx.x, w = t >> 6, l = t & 63;
  int s0 = gbasep[g], s1 = gbasep[g + 1];
  int n = s1 - s0;
  int per = (n + POST_SPLIT * 4 - 1) / (POST_SPLIT * 4);
  int b0 = s0 + (sp * 4 + w) * per, b1 = min(b0 + per, s1);
  float2 a0{0.f,0.f}, a1{0.f,0.f}, a2{0.f,0.f}, a3{0.f,0.f};
  float2 mx{0.f,0.f};
  for (int base = b0; base < b1; base += 64){
    int nn = min(64, b1 - base);
    int cid = cidx[base + min(l, nn - 1)];
    int j = 0;
    for (; j + 4 <= nn; j += 4){
      int c0 = __shfl(cid, j);
      int c1 = __shfl(cid, j + 1);
      int c2 = __shfl(cid, j + 2);
      int c3 = __shfl(cid, j + 3);
      unsigned u0 = hp3[(size_t)c0 * 64 + l];
      unsigned u1 = hp3[(size_t)c1 * 64 + l];
      unsigned u2 = hp3[(size_t)c2 * 64 + l];
      unsigned u3 = hp3[(size_t)c3 * 64 + l];
      float f0x = bf16lo(u0), f0y = bf16hi(u0);
      float f1x = bf16lo(u1), f1y = bf16hi(u1);
      float f2x = bf16lo(u2), f2y = bf16hi(u2);
      float f3x = bf16lo(u3), f3y = bf16hi(u3);
      a0.x += f0x; a0.y += f0y; a1.x += f1x; a1.y += f1y;
      a2.x += f2x; a2.y += f2y; a3.x += f3x; a3.y += f3y;
      mx.x = fmaxf(fmaxf(mx.x, fmaxf(f0x, f1x)), fmaxf(f2x, f3x));
      mx.y = fmaxf(fmaxf(mx.y, fmaxf(f0y, f1y)), fmaxf(f2y, f3y));
    }
    for (; j < nn; ++j){
      int c = __shfl(cid, j);
      unsigned u = hp3[(size_t)c * 64 + l];
      float fx = bf16lo(u), fy = bf16hi(u);
      a0.x += fx; a0.y += fy;
      mx.x = fmaxf(mx.x, fx); mx.y = fmaxf(mx.y, fy);
    }
  }
  __shared__ float2 ssum[4][64], smax[4][64];
  ssum[w][l] = { a0.x + a1.x + a2.x + a3.x, a0.y + a1.y + a2.y + a3.y };
  smax[w][l] = mx;
  __syncthreads();
  if (w == 0){
    float2 S = ssum[0][l], M = smax[0][l];
    #pragma unroll
    for (int k = 1; k < 4; ++k){
      S.x += ssum[k][l].x; S.y += ssum[k][l].y;
      M.x = fmaxf(M.x, smax[k][l].x); M.y = fmaxf(M.y, smax[k][l].y);
    }
    atomicAdd(&psum[g * 128 + 2 * l], S.x);
    atomicAdd(&psum[g * 128 + 2 * l + 1], S.y);
    atomicMaxPosF(&pmax[g * 128 + 2 * l], M.x);
    atomicMaxPosF(&pmax[g * 128 + 2 * l + 1], M.y);
  }
}

__launch_bounds__(128)
__global__ void head_kernel(const float* __restrict__ psum, const float* __restrict__ pmax,
                            const float* __restrict__ postsum, const float* __restrict__ postmax,
                            const int* __restrict__ gstart, const int* __restrict__ cntp,
                            const float* __restrict__ l1w, const float* __restrict__ l1b,
                            const float* __restrict__ l2w, const float* __restrict__ l2b,
                            float* __restrict__ out){
  int g = blockIdx.x, t = threadIdx.x;
  __shared__ float z[512];
  __shared__ float a[128];
  __shared__ float logits[16];
  __shared__ float lse_s;
  float cpre  = (float)max(gstart[g + 1] - gstart[g], 1);
  float cpost = fmaxf((float)cntp[g], 1.0f);
  z[t]       = psum[g * 128 + t] / cpre;
  z[128 + t] = pmax[g * 128 + t];
  z[256 + t] = postsum[g * 128 + t] / cpost;
  z[384 + t] = postmax[g * 128 + t];
  __syncthreads();
  float acc = l1b[t];
  #pragma unroll 8
  for (int k = 0; k < 512; ++k) acc = fmaf(z[k], l1w[k * 128 + t], acc);
  a[t] = fmaxf(acc, 0.f);
  __syncthreads();
  if (t < NCLSN){
    float s2 = l2b[t];
    for (int k = 0; k < 128; ++k) s2 = fmaf(a[k], l2w[k * NCLSN + t], s2);
    logits[t] = s2;
  }
  __syncthreads();
  if (t == 0){
    float m = logits[0];
    for (int c = 1; c < NCLSN; ++c) m = fmaxf(m, logits[c]);
    float s = 0.f;
    for (int c = 0; c < NCLSN; ++c) s += expf(logits[c] - m);
    lse_s = m + logf(s);
  }
  __syncthreads();
  if (t < NCLSN) out[g * NCLSN + t] = logits[t] - lse_s;
}

// ---------------------------------------------------------------------------
extern "C" void kernel_launch(void* const* d_in, const int* in_sizes, int n_in,
                              void* d_out, int out_size, void* d_ws, size_t ws_size,
                              hipStream_t stream){
  const float* x       = (const float*)d_in[0];
  const int*   ei      = (const int*)  d_in[1];
  const int*   batch   = (const int*)  d_in[2];
  const int*   cluster = (const int*)  d_in[3];
  const float* W1      = (const float*)d_in[6];
  const float* b1      = (const float*)d_in[7];
  const float* W2      = (const float*)d_in[8];
  const float* b2      = (const float*)d_in[9];
  const float* W3      = (const float*)d_in[10];
  const float* b3      = (const float*)d_in[11];
  const float* l1w     = (const float*)d_in[12];
  const float* l1b     = (const float*)d_in[13];
  const float* l2w     = (const float*)d_in[14];
  const float* l2b     = (const float*)d_in[15];
  float* out = (float*)d_out;

  char* base = (char*)d_ws;
  size_t off = 0;
  auto alloc = [&](size_t bytes) -> char* {
    char* p = base + off;
    off += (bytes + 255) & ~size_t(255);
    return p;
  };
  // ---- zero zone (one memset) ----
  char*  zbase  = base + off;
  int*   gcnt1  = (int*)  alloc((size_t)NBKT1 * 4);
  int*   cntn   = (int*)  alloc((size_t)N_CLUST * 4);
  int*   deg2   = (int*)  alloc((size_t)N_CLUST * 4);
  int*   cntp   = (int*)  alloc((size_t)N_GRAPH * 4);
  float* pre_s  = (float*)alloc((size_t)N_GRAPH * 128 * 4);
  float* pre_m  = (float*)alloc((size_t)N_GRAPH * 128 * 4);
  float* post_s = (float*)alloc((size_t)N_GRAPH * 128 * 4);
  float* post_m = (float*)alloc((size_t)N_GRAPH * 128 * 4);
  size_t zsize = off;
  // ---- plain buffers (bf16 feature rows: 64 uints per row) ----
  unsigned* Ts1   = (unsigned*)alloc((size_t)N_NODES * 64 * 4);  // later aliased
  unsigned* h1    = (unsigned*)alloc((size_t)N_NODES * 64 * 4);  // stage buf aliases here
  int*   esrc1   = (int*)  alloc((size_t)N_EDGES * 4);
  int*   psrcC   = (int*)  alloc((size_t)N_EDGES * 4);
  int*   deg1    = (int*)  alloc((size_t)N_NODES * 4);
  int*   rowptr1 = (int*)  alloc((size_t)(N_NODES + 1) * 4);
  int*   rowptrn = (int*)  alloc((size_t)(N_CLUST + 1) * 4);
  int*   curn    = (int*)  alloc((size_t)N_CLUST * 4);
  int*   rowptr2 = (int*)  alloc((size_t)(N_CLUST + 1) * 4);
  int*   nidx    = (int*)  alloc((size_t)N_NODES * 4);
  float* dis1    = (float*)alloc((size_t)N_NODES * 4);
  float* dis2    = (float*)alloc((size_t)N_CLUST * 4);
  int*   batchp  = (int*)  alloc((size_t)N_CLUST * 4);
  int*   gstart  = (int*)  alloc((size_t)(N_GRAPH + 1) * 4);
  int*   bsum    = (int*)  alloc((size_t)NBT * 4);
  int*   boff    = (int*)  alloc((size_t)NBT * 4);
  int*   gbase1  = (int*)  alloc((size_t)NBKT1 * 4);
  int*   gcur1   = (int*)  alloc((size_t)NBKT1 * 4);
  int*   gbasep  = (int*)  alloc((size_t)(N_GRAPH + 1) * 4);
  int*   curp    = (int*)  alloc((size_t)N_GRAPH * 4);
  int*   cidx    = (int*)  alloc((size_t)N_CLUST * 4);
  // stage buffer aliases the (not-yet-written) h1 region (6.4 MB <= 25.6 MB)
  unsigned int* stage1 = (unsigned int*)h1;
  // aliases into Ts1 (dead after conv1): 4 x 25000*64 uints = exactly Ts1 size
  unsigned* hp  = Ts1;
  unsigned* Ts2 = Ts1 + (size_t)N_CLUST * 64;
  unsigned* hp2 = Ts1 + (size_t)2 * N_CLUST * 64;
  unsigned* hp3 = Ts1 + (size_t)3 * N_CLUST * 64;
  unsigned* Ts3 = Ts2;

  (void)in_sizes; (void)n_in; (void)out_size; (void)ws_size;

  hipMemsetAsync(zbase, 0, zsize, stream);

  // ---- sort-based node-CSR build ----
  count_kernel  <<<NEB, 256, 0, stream>>>(ei, gcnt1);
  bucket_scan   <<<1, 256, 0, stream>>>(gcnt1, gbase1, gcur1);
  scatter_kernel<<<NEB, 256, 0, stream>>>(ei, gcur1, stage1);
  bucket_sort<512, 17><<<NBKT1, 256, 0, stream>>>(stage1, gbase1, gcnt1, esrc1, deg1, N_NODES);
  node_prep<<<(N_NODES + 255) / 256, 256, 0, stream>>>(cluster, deg1, cntn, deg2);
  block_sums <<<NBT, 256, 0, stream>>>(deg1, cntn, deg2, bsum);
  scan_bsums <<<1, 256, 0, stream>>>(bsum, boff, rowptr1, rowptrn, rowptr2);
  scan_final <<<NBT, 256, 0, stream>>>(deg1, cntn, deg2, boff,
                                       rowptr1, dis1, rowptrn, curn, rowptr2, dis2);
  fill_n<<<(N_NODES + 255) / 256, 256, 0, stream>>>(cluster, curn, nidx);
  psrc_build<<<N_CLUST / 4, 256, 0, stream>>>(rowptrn, nidx, rowptr1, esrc1,
                                              cluster, rowptr2, psrcC);

  // conv1
  gemm_mfma<false><<<(N_NODES + 63) / 64, 256, 0, stream>>>(x, W1, dis1, Ts1, N_NODES);
  conv_csr<<<N_NODES / 4, 256, 0, stream>>>(Ts1, dis1, rowptr1, esrc1, b1, h1);

  // pre pools (gather over contiguous sorted-batch ranges)
  graph_bounds<<<1, 128, 0, stream>>>(batch, gstart);
  pre_pool_g<<<N_GRAPH * PRE_SPLIT, 256, 0, stream>>>(h1, gstart, pre_s, pre_m);

  // cluster mean pool + batch_p + cntp + graph->cluster CSR
  cluster_gather<<<N_CLUST / 4, 256, 0, stream>>>(h1, rowptrn, nidx, batch, hp, batchp);
  cntp_kernel<<<(N_CLUST + 255) / 256, 256, 0, stream>>>(batchp, cntp);
  scan_cntp<<<1, 64, 0, stream>>>(cntp, gbasep, curp);
  fill_c<<<(N_CLUST + 255) / 256, 256, 0, stream>>>(batchp, curp, cidx);

  // conv2
  gemm_mfma<true><<<(N_CLUST + 63) / 64, 256, 0, stream>>>(hp, W2, dis2, Ts2, N_CLUST);
  conv_csr<<<N_CLUST / 4, 256, 0, stream>>>(Ts2, dis2, rowptr2, psrcC, b2, hp2);

  // conv3
  gemm_mfma<true><<<(N_CLUST + 63) / 64, 256, 0, stream>>>(hp2, W3, dis2, Ts3, N_CLUST);
  conv_csr<<<N_CLUST / 4, 256, 0, stream>>>(Ts3, dis2, rowptr2, psrcC, b3, hp3);

  // post pools (gather via graph->cluster CSR) + head
  post_pool_g<<<N_GRAPH * POST_SPLIT, 256, 0, stream>>>(hp3, gbasep, cidx, post_s, post_m);
  head_kernel<<<N_GRAPH, 128, 0, stream>>>(pre_s, pre_m, post_s, post_m, gstart, cntp,
                                           l1w, l1b, l2w, l2b, out);
}

// Round 11
// 536.325 us; speedup vs baseline: 3.0904x; 1.1337x over previous
//
#include <hip/hip_runtime.h>

constexpr int N_NODES = 100000;
constexpr int N_EDGES = 1600000;
constexpr int N_CLUST = 25000;
constexpr int N_GRAPH = 64;
constexpr int NCLSN   = 10;

// bucket decomposition for the radix node-CSR build
constexpr int BKT1_SHIFT = 9;                       // node-dst buckets of 512 ids
constexpr int NBKT1 = (N_NODES + 511) / 512;        // 196
constexpr int EPB = 4096;                           // edges per block (count/scatter)
constexpr int NEB = (N_EDGES + EPB - 1) / EPB;      // 391
constexpr int SORT_CAP = 12288;                     // LDS staging cap (mean 8163, sd ~90)

// scan partitioning: 1024 elements per block, three concatenated segments
constexpr int SCAN_BPB = 1024;
constexpr int NB1 = (N_NODES + SCAN_BPB - 1) / SCAN_BPB;  // 98
constexpr int NB2 = (N_CLUST + SCAN_BPB - 1) / SCAN_BPB;  // 25
constexpr int NB3 = (N_CLUST + SCAN_BPB - 1) / SCAN_BPB;  // 25
constexpr int NBT = NB1 + NB2 + NB3;                      // 148

// ---- bf16 pack/unpack helpers (features stored as packed pairs in uint) ----
__device__ __forceinline__ float bf16lo(unsigned u){ return __uint_as_float(u << 16); }
__device__ __forceinline__ float bf16hi(unsigned u){ return __uint_as_float(u & 0xffff0000u); }
__device__ __forceinline__ unsigned bf16_rne(float f){
  unsigned u = __float_as_uint(f);
  return (u + 0x7fffu + ((u >> 16) & 1u)) >> 16;
}
__device__ __forceinline__ unsigned pack2(float lo, float hi){
  return bf16_rne(lo) | (bf16_rne(hi) << 16);
}

typedef short bf16x8 __attribute__((ext_vector_type(8)));
typedef float f32x4  __attribute__((ext_vector_type(4)));

// ---------------------------------------------------------------------------
// radix node-CSR build, phase 1: per-block bucket histograms (no global atomics)
// ---------------------------------------------------------------------------
__launch_bounds__(1024)
__global__ void count_kernel(const int* __restrict__ ei, int* __restrict__ bhist){
  __shared__ int h1c[NBKT1];
  int t = threadIdx.x;
  for (int i = t; i < NBKT1; i += 1024) h1c[i] = 0;
  __syncthreads();
  int e0 = blockIdx.x * EPB;
  #pragma unroll
  for (int i = 0; i < EPB / 1024; ++i){
    int e = e0 + i * 1024 + t;
    if (e < N_EDGES) atomicAdd(&h1c[ei[N_EDGES + e] >> BKT1_SHIFT], 1);
  }
  __syncthreads();
  for (int i = t; i < NBKT1; i += 1024) bhist[blockIdx.x * NBKT1 + i] = h1c[i];
}

// phase 2a: column scan of the histogram matrix -> per-(block,bucket) offsets
// + bucket totals. one block per bucket.
__launch_bounds__(512)
__global__ void colscan(const int* __restrict__ bhist, int* __restrict__ boffs,
                        int* __restrict__ gcnt1){
  __shared__ int s[512];
  int i = blockIdx.x;                 // bucket
  int t = threadIdx.x;                // edge-block index
  int v = (t < NEB) ? bhist[t * NBKT1 + i] : 0;
  s[t] = v; __syncthreads();
  for (int o = 1; o < 512; o <<= 1){
    int a = (t >= o) ? s[t - o] : 0;
    __syncthreads(); s[t] += a; __syncthreads();
  }
  if (t < NEB) boffs[t * NBKT1 + i] = s[t] - v;   // exclusive within column
  if (t == 511) gcnt1[i] = s[511];
}

// phase 2b: bucket bases (prefix over 196 totals)
__launch_bounds__(256)
__global__ void bucket_scan(const int* __restrict__ gcnt1, int* __restrict__ gbase1){
  __shared__ int s[256];
  int t = threadIdx.x;
  int v = (t < NBKT1) ? gcnt1[t] : 0;
  s[t] = v; __syncthreads();
  for (int off = 1; off < 256; off <<= 1){
    int a = (t >= off) ? s[t - off] : 0;
    __syncthreads(); s[t] += a; __syncthreads();
  }
  if (t < NBKT1) gbase1[t] = s[t] - v;
}

// phase 3: single-pass scatter into pre-reserved runs (no global atomics)
__launch_bounds__(1024)
__global__ void scatter_kernel(const int* __restrict__ ei, const int* __restrict__ gbase1,
                               const int* __restrict__ boffs, unsigned int* __restrict__ stage1){
  __shared__ int gb1[NBKT1];
  __shared__ int cur[NBKT1];
  int t = threadIdx.x, b = blockIdx.x;
  for (int i = t; i < NBKT1; i += 1024){
    gb1[i] = gbase1[i] + boffs[b * NBKT1 + i];
    cur[i] = 0;
  }
  __syncthreads();
  int e0 = b * EPB;
  #pragma unroll
  for (int i = 0; i < EPB / 1024; ++i){
    int e = e0 + i * 1024 + t;
    if (e < N_EDGES){
      int src = ei[e], dst = ei[N_EDGES + e];
      int bk = dst >> BKT1_SHIFT;
      int r = atomicAdd(&cur[bk], 1);
      stage1[gb1[bk] + r] = ((unsigned)(dst & 511) << 17) | (unsigned)src;
    }
  }
}

// phase 4: per-bucket LDS counting sort + coalesced degree writes (1024 thr)
__launch_bounds__(1024)
__global__ void bucket_sort(const unsigned int* __restrict__ stage, const int* __restrict__ gbase,
                            const int* __restrict__ gcnt, int* __restrict__ outpay,
                            int* __restrict__ deg){
  __shared__ int cnt[512], off[512];
  __shared__ int sorted[SORT_CAP];
  int b = blockIdx.x, t = threadIdx.x;
  int base = gbase[b], n = gcnt[b];
  if (t < 512) cnt[t] = 0;
  __syncthreads();
  for (int i = t; i < n; i += 1024) atomicAdd(&cnt[stage[base + i] >> 17], 1);
  __syncthreads();
  if (t < 512){
    int idx = b * 512 + t;
    if (idx < N_NODES) deg[idx] = cnt[t];
    off[t] = cnt[t];
  }
  __syncthreads();
  for (int s = 1; s < 512; s <<= 1){
    int v = 0;
    if (t < 512 && t >= s) v = off[t - s];
    __syncthreads();
    if (t < 512) off[t] += v;
    __syncthreads();
  }
  if (t < 512) off[t] -= cnt[t];       // exclusive cursors
  __syncthreads();
  if (n <= SORT_CAP){
    for (int i = t; i < n; i += 1024){
      unsigned w = stage[base + i];
      int r = atomicAdd(&off[w >> 17], 1);
      sorted[r] = (int)(w & 0x1FFFFu);
    }
    __syncthreads();
    for (int i = t; i < n; i += 1024) outpay[base + i] = sorted[i];
  } else {  // never expected; correct fallback
    for (int i = t; i < n; i += 1024){
      unsigned w = stage[base + i];
      int r = atomicAdd(&off[w >> 17], 1);
      outpay[base + r] = (int)(w & 0x1FFFFu);
    }
  }
}

// per-node: cluster membership count + cluster in-degree (sum of member deg1)
__global__ void node_prep(const int* __restrict__ cluster, const int* __restrict__ deg1,
                          int* __restrict__ cntn, int* __restrict__ deg2){
  int v = blockIdx.x * blockDim.x + threadIdx.x;
  if (v < N_NODES){
    int c = cluster[v];
    atomicAdd(&cntn[c], 1);
    atomicAdd(&deg2[c], deg1[v]);
  }
}

// ---------------------------------------------------------------------------
// device-wide 3-segment exclusive scan
// ---------------------------------------------------------------------------
__device__ __forceinline__ void seg_select(int b, const int* deg1, const int* cntn,
                                           const int* deg2, const int*& src, int& n, int& base){
  if (b < NB1){ src = deg1; n = N_NODES; base = b * SCAN_BPB; }
  else if (b < NB1 + NB2){ src = cntn; n = N_CLUST; base = (b - NB1) * SCAN_BPB; }
  else { src = deg2; n = N_CLUST; base = (b - NB1 - NB2) * SCAN_BPB; }
}

__launch_bounds__(256)
__global__ void block_sums(const int* __restrict__ deg1, const int* __restrict__ cntn,
                           const int* __restrict__ deg2, int* __restrict__ bsum){
  int b = blockIdx.x;
  const int* src; int n, base;
  seg_select(b, deg1, cntn, deg2, src, n, base);
  int t = threadIdx.x;
  int i0 = base + t * 4;
  int s = 0;
  if (i0 + 3 < n){ int4 v = *(const int4*)&src[i0]; s = v.x + v.y + v.z + v.w; }
  else { for (int j = 0; j < 4; ++j){ int i = i0 + j; if (i < n) s += src[i]; } }
  __shared__ int sh[256];
  sh[t] = s; __syncthreads();
  for (int off = 128; off > 0; off >>= 1){
    if (t < off) sh[t] += sh[t + off];
    __syncthreads();
  }
  if (t == 0) bsum[b] = sh[0];
}

__launch_bounds__(256)
__global__ void scan_bsums(const int* __restrict__ bsum, int* __restrict__ boff,
                           int* __restrict__ rowptr1, int* __restrict__ rowptrn,
                           int* __restrict__ rowptr2){
  __shared__ int s[256];
  int t = threadIdx.x;
  int v = (t < NBT) ? bsum[t] : 0;
  s[t] = v; __syncthreads();
  int seg = (t < NB1) ? 0 : (t < NB1 + NB2 ? 1 : 2);
  for (int off = 1; off < 256; off <<= 1){
    int add = 0;
    if (t >= off){
      int u = t - off;
      int useg = (u < NB1) ? 0 : (u < NB1 + NB2 ? 1 : 2);
      if (useg == seg) add = s[u];
    }
    __syncthreads();
    s[t] += add;
    __syncthreads();
  }
  if (t < NBT) boff[t] = s[t] - v;
  if (t == NB1 - 1)       rowptr1[N_NODES] = s[t];
  if (t == NB1 + NB2 - 1) rowptrn[N_CLUST] = s[t];
  if (t == NBT - 1)       rowptr2[N_CLUST] = s[t];
}

__launch_bounds__(256)
__global__ void scan_final(const int* __restrict__ deg1, const int* __restrict__ cntn,
                           const int* __restrict__ deg2, const int* __restrict__ boff,
                           int* __restrict__ rowptr1, float* __restrict__ dis1,
                           int* __restrict__ rowptrn, int* __restrict__ curn,
                           int* __restrict__ rowptr2, float* __restrict__ dis2){
  int b = blockIdx.x;
  const int* src; int n, base;
  seg_select(b, deg1, cntn, deg2, src, n, base);
  int* rp; int* cur; float* dis;
  if (b < NB1){ rp = rowptr1; cur = nullptr; dis = dis1; }
  else if (b < NB1 + NB2){ rp = rowptrn; cur = curn; dis = nullptr; }
  else { rp = rowptr2; cur = nullptr; dis = dis2; }
  int t = threadIdx.x;
  int i0 = base + t * 4;
  int v[4]; int s = 0;
  #pragma unroll
  for (int j = 0; j < 4; ++j){ int i = i0 + j; v[j] = (i < n) ? src[i] : 0; s += v[j]; }
  __shared__ int sh[256];
  sh[t] = s; __syncthreads();
  for (int off = 1; off < 256; off <<= 1){
    int add = (t >= off) ? sh[t - off] : 0;
    __syncthreads();
    sh[t] += add;
    __syncthreads();
  }
  int run = sh[t] - s + boff[b];
  #pragma unroll
  for (int j = 0; j < 4; ++j){
    int i = i0 + j;
    if (i < n){
      rp[i] = run;
      if (cur) cur[i] = run;
      if (dis) dis[i] = rsqrtf((float)v[j] + 1.0f);
      run += v[j];
    }
  }
}

// node->cluster CSR fill
__global__ void fill_n(const int* __restrict__ cluster, int* __restrict__ curn,
                       int* __restrict__ nidx){
  int v = blockIdx.x * blockDim.x + threadIdx.x;
  if (v >= N_NODES) return;
  nidx[atomicAdd(&curn[cluster[v]], 1)] = v;
}

// ---------------------------------------------------------------------------
// psrcC build: cluster c's pooled-edge list = concat of members' edge runs,
// mapped through cluster[]. One wave per cluster.
// ---------------------------------------------------------------------------
__launch_bounds__(256)
__global__ void psrc_build(const int* __restrict__ rowptrn, const int* __restrict__ nidx,
                           const int* __restrict__ rowptr1, const int* __restrict__ esrc1,
                           const int* __restrict__ cluster, const int* __restrict__ rowptr2,
                           int* __restrict__ psrcC){
  int c = blockIdx.x * 4 + (threadIdx.x >> 6);
  int l = threadIdx.x & 63;
  int mb = rowptrn[c], me = rowptrn[c + 1];
  int cnt = me - mb;                       // members per cluster (<= 64)
  int base_l = 0, d_l = 0;
  if (l < cnt){
    int v = nidx[mb + l];
    base_l = rowptr1[v];
    d_l = rowptr1[v + 1] - base_l;
  }
  int pref = d_l;                          // inclusive scan over 64 lanes
  #pragma unroll
  for (int off = 1; off < 64; off <<= 1){
    int u = __shfl_up(pref, off);
    if (l >= off) pref += u;
  }
  int total = __shfl(pref, 63);
  int wbase = rowptr2[c];
  int iters = (total + 63) >> 6;           // uniform loop; all lanes active
  for (int k = 0; k < iters; ++k){
    int idx = k * 64 + l;
    int idxc = min(idx, total - 1);
    int m = 0;
    for (int j = 0; j < cnt; ++j){
      int pj = __shfl(pref, j);
      if (idxc >= pj) m = j + 1;
    }
    int pm = __shfl(pref, m);
    int dm = __shfl(d_l, m);
    int bm = __shfl(base_l, m);
    int e = bm + idxc - (pm - dm);
    int sc = cluster[esrc1[e]];
    if (idx < total) psrcC[wbase + idx] = sc;
  }
}

// ---------------------------------------------------------------------------
// MFMA GEMM: C[M,128] = (A[M,128] @ B[128,128]) * scale[row], bf16 packed out
// ---------------------------------------------------------------------------
template<bool A_BF16>
__launch_bounds__(256)
__global__ void gemm_mfma(const void* __restrict__ Aptr, const float* __restrict__ B,
                          const float* __restrict__ scale, unsigned* __restrict__ Cmat,
                          int M){
  __shared__ __align__(16) unsigned Blds[128 * 68];
  __shared__ __align__(16) unsigned Alds[64 * 68];
  const int t = threadIdx.x;
  const int row0 = blockIdx.x * 64;

  #pragma unroll
  for (int i = 0; i < 8; ++i){
    int task = t + i * 256;
    int kp = task >> 5, nq = task & 31;
    float4 b0 = *(const float4*)&B[(2 * kp) * 128 + nq * 4];
    float4 b1 = *(const float4*)&B[(2 * kp + 1) * 128 + nq * 4];
    Blds[(nq * 4 + 0) * 68 + kp] = pack2(b0.x, b1.x);
    Blds[(nq * 4 + 1) * 68 + kp] = pack2(b0.y, b1.y);
    Blds[(nq * 4 + 2) * 68 + kp] = pack2(b0.z, b1.z);
    Blds[(nq * 4 + 3) * 68 + kp] = pack2(b0.w, b1.w);
  }
  if (A_BF16){
    const unsigned* A = (const unsigned*)Aptr;
    #pragma unroll
    for (int i = 0; i < 8; ++i){
      int idx = t + i * 256;
      int row = idx >> 5, c2 = idx & 31;
      int grow = min(row0 + row, M - 1);
      uint2 v = *(const uint2*)&A[(size_t)grow * 64 + c2 * 2];
      Alds[row * 68 + c2 * 2]     = v.x;
      Alds[row * 68 + c2 * 2 + 1] = v.y;
    }
  } else {
    const float* A = (const float*)Aptr;
    #pragma unroll
    for (int i = 0; i < 8; ++i){
      int idx = t + i * 256;
      int row = idx >> 5, k4 = idx & 31;
      int grow = min(row0 + row, M - 1);
      float4 v = *(const float4*)&A[(size_t)grow * 128 + k4 * 4];
      Alds[row * 68 + k4 * 2]     = pack2(v.x, v.y);
      Alds[row * 68 + k4 * 2 + 1] = pack2(v.z, v.w);
    }
  }
  __syncthreads();

  const int wv = t >> 6, l = t & 63, quad = l >> 4, n16 = l & 15;
  f32x4 acc[8];
  #pragma unroll
  for (int nt = 0; nt < 8; ++nt) acc[nt] = (f32x4){0.f, 0.f, 0.f, 0.f};
  const int arow = wv * 16 + n16;
  #pragma unroll
  for (int ks = 0; ks < 4; ++ks){
    bf16x8 af = *(const bf16x8*)&Alds[arow * 68 + ks * 16 + quad * 4];
    #pragma unroll
    for (int nt = 0; nt < 8; ++nt){
      bf16x8 bfr = *(const bf16x8*)&Blds[(nt * 16 + n16) * 68 + ks * 16 + quad * 4];
      acc[nt] = __builtin_amdgcn_mfma_f32_16x16x32_bf16(af, bfr, acc[nt], 0, 0, 0);
    }
  }
  #pragma unroll
  for (int nt = 0; nt < 8; ++nt){
    #pragma unroll
    for (int r = 0; r < 4; ++r){
      int row = row0 + wv * 16 + quad * 4 + r;
      float sc = scale[min(row, M - 1)];
      float v = acc[nt][r] * sc;
      float vhi = __shfl_xor(v, 1);
      if (((l & 1) == 0) && row < M)
        Cmat[(size_t)row * 64 + nt * 8 + (n16 >> 1)] = pack2(v, vhi);
    }
  }
}

// ---------------------------------------------------------------------------
// CSR conv over bf16 rows, ILP-8: out[i]=relu(dis[i]*(sum Ts[src]+Ts[i])+b)
// ---------------------------------------------------------------------------
__launch_bounds__(256)
__global__ void conv_csr(const unsigned* __restrict__ Ts, const float* __restrict__ dis,
                         const int* __restrict__ rowptr, const int* __restrict__ esrc,
                         const float* __restrict__ bias, unsigned* __restrict__ Hout){
  int w = blockIdx.x * 4 + (threadIdx.x >> 6);
  int l = threadIdx.x & 63;
  int beg = rowptr[w], end = rowptr[w + 1];
  float2 a0{0.f,0.f}, a1{0.f,0.f}, a2{0.f,0.f}, a3{0.f,0.f};
  float2 a4{0.f,0.f}, a5{0.f,0.f}, a6{0.f,0.f}, a7{0.f,0.f};
  for (int base = beg; base < end; base += 64){
    int n = min(64, end - base);
    int eid = esrc[base + min(l, n - 1)];
    int j = 0;
    for (; j + 8 <= n; j += 8){
      int s0 = __shfl(eid, j);
      int s1 = __shfl(eid, j + 1);
      int s2 = __shfl(eid, j + 2);
      int s3 = __shfl(eid, j + 3);
      int s4 = __shfl(eid, j + 4);
      int s5 = __shfl(eid, j + 5);
      int s6 = __shfl(eid, j + 6);
      int s7 = __shfl(eid, j + 7);
      unsigned u0 = Ts[(size_t)s0 * 64 + l];
      unsigned u1 = Ts[(size_t)s1 * 64 + l];
      unsigned u2 = Ts[(size_t)s2 * 64 + l];
      unsigned u3 = Ts[(size_t)s3 * 64 + l];
      unsigned u4 = Ts[(size_t)s4 * 64 + l];
      unsigned u5 = Ts[(size_t)s5 * 64 + l];
      unsigned u6 = Ts[(size_t)s6 * 64 + l];
      unsigned u7 = Ts[(size_t)s7 * 64 + l];
      a0.x += bf16lo(u0); a0.y += bf16hi(u0);
      a1.x += bf16lo(u1); a1.y += bf16hi(u1);
      a2.x += bf16lo(u2); a2.y += bf16hi(u2);
      a3.x += bf16lo(u3); a3.y += bf16hi(u3);
      a4.x += bf16lo(u4); a4.y += bf16hi(u4);
      a5.x += bf16lo(u5); a5.y += bf16hi(u5);
      a6.x += bf16lo(u6); a6.y += bf16hi(u6);
      a7.x += bf16lo(u7); a7.y += bf16hi(u7);
    }
    for (; j + 4 <= n; j += 4){
      int s0 = __shfl(eid, j);
      int s1 = __shfl(eid, j + 1);
      int s2 = __shfl(eid, j + 2);
      int s3 = __shfl(eid, j + 3);
      unsigned u0 = Ts[(size_t)s0 * 64 + l];
      unsigned u1 = Ts[(size_t)s1 * 64 + l];
      unsigned u2 = Ts[(size_t)s2 * 64 + l];
      unsigned u3 = Ts[(size_t)s3 * 64 + l];
      a0.x += bf16lo(u0); a0.y += bf16hi(u0);
      a1.x += bf16lo(u1); a1.y += bf16hi(u1);
      a2.x += bf16lo(u2); a2.y += bf16hi(u2);
      a3.x += bf16lo(u3); a3.y += bf16hi(u3);
    }
    for (; j < n; ++j){
      int s = __shfl(eid, j);
      unsigned u = Ts[(size_t)s * 64 + l];
      a0.x += bf16lo(u); a0.y += bf16hi(u);
    }
  }
  float d = dis[w];
  unsigned us = Ts[(size_t)w * 64 + l];
  float2 bb = *(const float2*)&bias[l * 2];
  float sx = ((a0.x + a1.x) + (a2.x + a3.x)) + ((a4.x + a5.x) + (a6.x + a7.x)) + bf16lo(us);
  float sy = ((a0.y + a1.y) + (a2.y + a3.y)) + ((a4.y + a5.y) + (a6.y + a7.y)) + bf16hi(us);
  float rx = fmaxf(fmaf(d, sx, bb.x), 0.f);
  float ry = fmaxf(fmaf(d, sy, bb.y), 0.f);
  Hout[(size_t)w * 64 + l] = pack2(rx, ry);
}

// cluster mean pool + batch_p over bf16 rows
__launch_bounds__(256)
__global__ void cluster_gather(const unsigned* __restrict__ h1, const int* __restrict__ rowptrn,
                               const int* __restrict__ nidx, const int* __restrict__ batch,
                               unsigned* __restrict__ hp, int* __restrict__ batchp){
  int c = blockIdx.x * 4 + (threadIdx.x >> 6);
  int l = threadIdx.x & 63;
  int mb = rowptrn[c], me = rowptrn[c + 1];
  float2 a0{0.f,0.f}, a1{0.f,0.f}, a2{0.f,0.f}, a3{0.f,0.f};
  int vmax = -1;
  for (int base = mb; base < me; base += 64){
    int n = min(64, me - base);
    int vid = nidx[base + min(l, n - 1)];
    if (l < n) vmax = max(vmax, vid);
    int j = 0;
    for (; j + 4 <= n; j += 4){
      int s0 = __shfl(vid, j);
      int s1 = __shfl(vid, j + 1);
      int s2 = __shfl(vid, j + 2);
      int s3 = __shfl(vid, j + 3);
      unsigned u0 = h1[(size_t)s0 * 64 + l];
      unsigned u1 = h1[(size_t)s1 * 64 + l];
      unsigned u2 = h1[(size_t)s2 * 64 + l];
      unsigned u3 = h1[(size_t)s3 * 64 + l];
      a0.x += bf16lo(u0); a0.y += bf16hi(u0);
      a1.x += bf16lo(u1); a1.y += bf16hi(u1);
      a2.x += bf16lo(u2); a2.y += bf16hi(u2);
      a3.x += bf16lo(u3); a3.y += bf16hi(u3);
    }
    for (; j < n; ++j){
      int s = __shfl(vid, j);
      unsigned u = h1[(size_t)s * 64 + l];
      a0.x += bf16lo(u); a0.y += bf16hi(u);
    }
  }
  #pragma unroll
  for (int off = 32; off > 0; off >>= 1) vmax = max(vmax, __shfl_xor(vmax, off));
  float inv = 1.0f / (float)max(me - mb, 1);
  float ox = (a0.x + a1.x + a2.x + a3.x) * inv;
  float oy = (a0.y + a1.y + a2.y + a3.y) * inv;
  hp[(size_t)c * 64 + l] = pack2(ox, oy);
  if (l == 0) batchp[c] = (vmax >= 0) ? batch[vmax] : 0;  // batch sorted by node id
}

__global__ void cntp_kernel(const int* __restrict__ batchp, int* __restrict__ cntp){
  int c = blockIdx.x * blockDim.x + threadIdx.x;
  if (c < N_CLUST) atomicAdd(&cntp[batchp[c]], 1);
}

// graph -> cluster CSR: scan cntp (64 entries) + cursor fill
__global__ void scan_cntp(const int* __restrict__ cntp, int* __restrict__ gbasep,
                          int* __restrict__ curp){
  int t = threadIdx.x;                 // 64 threads
  int v = cntp[t];
  int s = v;
  for (int off = 1; off < 64; off <<= 1){
    int u = __shfl_up(s, off);
    if (t >= off) s += u;
  }
  gbasep[t] = s - v; curp[t] = s - v;
  if (t == 63) gbasep[64] = s;
}

__global__ void fill_c(const int* __restrict__ batchp, int* __restrict__ curp,
                       int* __restrict__ cidx){
  int c = blockIdx.x * blockDim.x + threadIdx.x;
  if (c < N_CLUST) cidx[atomicAdd(&curp[batchp[c]], 1)] = c;
}

// ---------------------------------------------------------------------------
__global__ void graph_bounds(const int* __restrict__ batch, int* __restrict__ gstart){
  int g = threadIdx.x;
  if (g > N_GRAPH) return;
  int lo = 0, hi = N_NODES;
  while (lo < hi){ int mid = (lo + hi) >> 1; if (batch[mid] < g) lo = mid + 1; else hi = mid; }
  gstart[g] = lo;
}

__device__ __forceinline__ void atomicMaxPosF(float* addr, float v){
  atomicMax((int*)addr, __float_as_int(v));
}

// pre-pool gather: graph g's rows are contiguous [gstart[g], gstart[g+1])
constexpr int PRE_SPLIT = 8;
__launch_bounds__(256)
__global__ void pre_pool_g(const unsigned* __restrict__ h1, const int* __restrict__ gstart,
                           float* __restrict__ psum, float* __restrict__ pmax){
  int g = blockIdx.x / PRE_SPLIT, sp = blockIdx.x % PRE_SPLIT;
  int t = threadIdx.x, w = t >> 6, l = t & 63;
  int s0 = gstart[g], s1 = gstart[g + 1];
  int n = s1 - s0;
  int per = (n + PRE_SPLIT - 1) / PRE_SPLIT;
  int b0 = s0 + sp * per, b1 = min(b0 + per, s1);
  float2 a0{0.f,0.f}, a1{0.f,0.f}, a2{0.f,0.f}, a3{0.f,0.f};
  float2 mx{0.f,0.f};
  int i = b0 + w;
  for (; i + 12 < b1; i += 16){
    unsigned u0 = h1[(size_t)(i     ) * 64 + l];
    unsigned u1 = h1[(size_t)(i +  4) * 64 + l];
    unsigned u2 = h1[(size_t)(i +  8) * 64 + l];
    unsigned u3 = h1[(size_t)(i + 12) * 64 + l];
    float f0x = bf16lo(u0), f0y = bf16hi(u0);
    float f1x = bf16lo(u1), f1y = bf16hi(u1);
    float f2x = bf16lo(u2), f2y = bf16hi(u2);
    float f3x = bf16lo(u3), f3y = bf16hi(u3);
    a0.x += f0x; a0.y += f0y; a1.x += f1x; a1.y += f1y;
    a2.x += f2x; a2.y += f2y; a3.x += f3x; a3.y += f3y;
    mx.x = fmaxf(fmaxf(mx.x, fmaxf(f0x, f1x)), fmaxf(f2x, f3x));
    mx.y = fmaxf(fmaxf(mx.y, fmaxf(f0y, f1y)), fmaxf(f2y, f3y));
  }
  for (; i < b1; i += 4){
    unsigned u = h1[(size_t)i * 64 + l];
    float fx = bf16lo(u), fy = bf16hi(u);
    a0.x += fx; a0.y += fy;
    mx.x = fmaxf(mx.x, fx); mx.y = fmaxf(mx.y, fy);
  }
  __shared__ float2 ssum[4][64], smax[4][64];
  ssum[w][l] = { a0.x + a1.x + a2.x + a3.x, a0.y + a1.y + a2.y + a3.y };
  smax[w][l] = mx;
  __syncthreads();
  if (w == 0){
    float2 S = ssum[0][l], M = smax[0][l];
    #pragma unroll
    for (int k = 1; k < 4; ++k){
      S.x += ssum[k][l].x; S.y += ssum[k][l].y;
      M.x = fmaxf(M.x, smax[k][l].x); M.y = fmaxf(M.y, smax[k][l].y);
    }
    atomicAdd(&psum[g * 128 + 2 * l], S.x);
    atomicAdd(&psum[g * 128 + 2 * l + 1], S.y);
    atomicMaxPosF(&pmax[g * 128 + 2 * l], M.x);
    atomicMaxPosF(&pmax[g * 128 + 2 * l + 1], M.y);
  }
}

// post-pool gather via graph->cluster CSR
constexpr int POST_SPLIT = 4;
__launch_bounds__(256)
__global__ void post_pool_g(const unsigned* __restrict__ hp3, const int* __restrict__ gbasep,
                            const int* __restrict__ cidx,
                            float* __restrict__ psum, float* __restrict__ pmax){
  int g = blockIdx.x / POST_SPLIT, sp = blockIdx.x % POST_SPLIT;
  int t = threadIdx.x, w = t >> 6, l = t & 63;
  int s0 = gbasep[g], s1 = gbasep[g + 1];
  int n = s1 - s0;
  int per = (n + POST_SPLIT * 4 - 1) / (POST_SPLIT * 4);
  int b0 = s0 + (sp * 4 + w) * per, b1 = min(b0 + per, s1);
  float2 a0{0.f,0.f}, a1{0.f,0.f}, a2{0.f,0.f}, a3{0.f,0.f};
  float2 mx{0.f,0.f};
  for (int base = b0; base < b1; base += 64){
    int nn = min(64, b1 - base);
    int cid = cidx[base + min(l, nn - 1)];
    int j = 0;
    for (; j + 4 <= nn; j += 4){
      int c0 = __shfl(cid, j);
      int c1 = __shfl(cid, j + 1);
      int c2 = __shfl(cid, j + 2);
      int c3 = __shfl(cid, j + 3);
      unsigned u0 = hp3[(size_t)c0 * 64 + l];
      unsigned u1 = hp3[(size_t)c1 * 64 + l];
      unsigned u2 = hp3[(size_t)c2 * 64 + l];
      unsigned u3 = hp3[(size_t)c3 * 64 + l];
      float f0x = bf16lo(u0), f0y = bf16hi(u0);
      float f1x = bf16lo(u1), f1y = bf16hi(u1);
      float f2x = bf16lo(u2), f2y = bf16hi(u2);
      float f3x = bf16lo(u3), f3y = bf16hi(u3);
      a0.x += f0x; a0.y += f0y; a1.x += f1x; a1.y += f1y;
      a2.x += f2x; a2.y += f2y; a3.x += f3x; a3.y += f3y;
      mx.x = fmaxf(fmaxf(mx.x, fmaxf(f0x, f1x)), fmaxf(f2x, f3x));
      mx.y = fmaxf(fmaxf(mx.y, fmaxf(f0y, f1y)), fmaxf(f2y, f3y));
    }
    for (; j < nn; ++j){
      int c = __shfl(cid, j);
      unsigned u = hp3[(size_t)c * 64 + l];
      float fx = bf16lo(u), fy = bf16hi(u);
      a0.x += fx; a0.y += fy;
      mx.x = fmaxf(mx.x, fx); mx.y = fmaxf(mx.y, fy);
    }
  }
  __shared__ float2 ssum[4][64], smax[4][64];
  ssum[w][l] = { a0.x + a1.x + a2.x + a3.x, a0.y + a1.y + a2.y + a3.y };
  smax[w][l] = mx;
  __syncthreads();
  if (w == 0){
    float2 S = ssum[0][l], M = smax[0][l];
    #pragma unroll
    for (int k = 1; k < 4; ++k){
      S.x += ssum[k][l].x; S.y += ssum[k][l].y;
      M.x = fmaxf(M.x, smax[k][l].x); M.y = fmaxf(M.y, smax[k][l].y);
    }
    atomicAdd(&psum[g * 128 + 2 * l], S.x);
    atomicAdd(&psum[g * 128 + 2 * l + 1], S.y);
    atomicMaxPosF(&pmax[g * 128 + 2 * l], M.x);
    atomicMaxPosF(&pmax[g * 128 + 2 * l + 1], M.y);
  }
}

__launch_bounds__(128)
__global__ void head_kernel(const float* __restrict__ psum, const float* __restrict__ pmax,
                            const float* __restrict__ postsum, const float* __restrict__ postmax,
                            const int* __restrict__ gstart, const int* __restrict__ cntp,
                            const float* __restrict__ l1w, const float* __restrict__ l1b,
                            const float* __restrict__ l2w, const float* __restrict__ l2b,
                            float* __restrict__ out){
  int g = blockIdx.x, t = threadIdx.x;
  __shared__ float z[512];
  __shared__ float a[128];
  __shared__ float logits[16];
  __shared__ float lse_s;
  float cpre  = (float)max(gstart[g + 1] - gstart[g], 1);
  float cpost = fmaxf((float)cntp[g], 1.0f);
  z[t]       = psum[g * 128 + t] / cpre;
  z[128 + t] = pmax[g * 128 + t];
  z[256 + t] = postsum[g * 128 + t] / cpost;
  z[384 + t] = postmax[g * 128 + t];
  __syncthreads();
  float acc = l1b[t];
  #pragma unroll 8
  for (int k = 0; k < 512; ++k) acc = fmaf(z[k], l1w[k * 128 + t], acc);
  a[t] = fmaxf(acc, 0.f);
  __syncthreads();
  if (t < NCLSN){
    float s2 = l2b[t];
    for (int k = 0; k < 128; ++k) s2 = fmaf(a[k], l2w[k * NCLSN + t], s2);
    logits[t] = s2;
  }
  __syncthreads();
  if (t == 0){
    float m = logits[0];
    for (int c = 1; c < NCLSN; ++c) m = fmaxf(m, logits[c]);
    float s = 0.f;
    for (int c = 0; c < NCLSN; ++c) s += expf(logits[c] - m);
    lse_s = m + logf(s);
  }
  __syncthreads();
  if (t < NCLSN) out[g * NCLSN + t] = logits[t] - lse_s;
}

// ---------------------------------------------------------------------------
extern "C" void kernel_launch(void* const* d_in, const int* in_sizes, int n_in,
                              void* d_out, int out_size, void* d_ws, size_t ws_size,
                              hipStream_t stream){
  const float* x       = (const float*)d_in[0];
  const int*   ei      = (const int*)  d_in[1];
  const int*   batch   = (const int*)  d_in[2];
  const int*   cluster = (const int*)  d_in[3];
  const float* W1      = (const float*)d_in[6];
  const float* b1      = (const float*)d_in[7];
  const float* W2      = (const float*)d_in[8];
  const float* b2      = (const float*)d_in[9];
  const float* W3      = (const float*)d_in[10];
  const float* b3      = (const float*)d_in[11];
  const float* l1w     = (const float*)d_in[12];
  const float* l1b     = (const float*)d_in[13];
  const float* l2w     = (const float*)d_in[14];
  const float* l2b     = (const float*)d_in[15];
  float* out = (float*)d_out;

  char* base = (char*)d_ws;
  size_t off = 0;
  auto alloc = [&](size_t bytes) -> char* {
    char* p = base + off;
    off += (bytes + 255) & ~size_t(255);
    return p;
  };
  // ---- zero zone (one memset) ----
  char*  zbase  = base + off;
  int*   cntn   = (int*)  alloc((size_t)N_CLUST * 4);
  int*   deg2   = (int*)  alloc((size_t)N_CLUST * 4);
  int*   cntp   = (int*)  alloc((size_t)N_GRAPH * 4);
  float* pre_s  = (float*)alloc((size_t)N_GRAPH * 128 * 4);
  float* pre_m  = (float*)alloc((size_t)N_GRAPH * 128 * 4);
  float* post_s = (float*)alloc((size_t)N_GRAPH * 128 * 4);
  float* post_m = (float*)alloc((size_t)N_GRAPH * 128 * 4);
  size_t zsize = off;
  // ---- plain buffers (bf16 feature rows: 64 uints per row) ----
  unsigned* Ts1   = (unsigned*)alloc((size_t)N_NODES * 64 * 4);  // later aliased
  unsigned* h1    = (unsigned*)alloc((size_t)N_NODES * 64 * 4);  // stage buf aliases here
  int*   esrc1   = (int*)  alloc((size_t)N_EDGES * 4);
  int*   psrcC   = (int*)  alloc((size_t)N_EDGES * 4);
  int*   deg1    = (int*)  alloc((size_t)N_NODES * 4);
  int*   rowptr1 = (int*)  alloc((size_t)(N_NODES + 1) * 4);
  int*   rowptrn = (int*)  alloc((size_t)(N_CLUST + 1) * 4);
  int*   curn    = (int*)  alloc((size_t)N_CLUST * 4);
  int*   rowptr2 = (int*)  alloc((size_t)(N_CLUST + 1) * 4);
  int*   nidx    = (int*)  alloc((size_t)N_NODES * 4);
  float* dis1    = (float*)alloc((size_t)N_NODES * 4);
  float* dis2    = (float*)alloc((size_t)N_CLUST * 4);
  int*   batchp  = (int*)  alloc((size_t)N_CLUST * 4);
  int*   gstart  = (int*)  alloc((size_t)(N_GRAPH + 1) * 4);
  int*   bsum    = (int*)  alloc((size_t)NBT * 4);
  int*   boff    = (int*)  alloc((size_t)NBT * 4);
  int*   gcnt1   = (int*)  alloc((size_t)NBKT1 * 4);
  int*   gbase1  = (int*)  alloc((size_t)NBKT1 * 4);
  int*   bhist   = (int*)  alloc((size_t)NEB * NBKT1 * 4);
  int*   boffs   = (int*)  alloc((size_t)NEB * NBKT1 * 4);
  int*   gbasep  = (int*)  alloc((size_t)(N_GRAPH + 1) * 4);
  int*   curp    = (int*)  alloc((size_t)N_GRAPH * 4);
  int*   cidx    = (int*)  alloc((size_t)N_CLUST * 4);
  // stage buffer aliases the (not-yet-written) h1 region (6.4 MB <= 25.6 MB)
  unsigned int* stage1 = (unsigned int*)h1;
  // aliases into Ts1 (dead after conv1): 4 x 25000*64 uints = exactly Ts1 size
  unsigned* hp  = Ts1;
  unsigned* Ts2 = Ts1 + (size_t)N_CLUST * 64;
  unsigned* hp2 = Ts1 + (size_t)2 * N_CLUST * 64;
  unsigned* hp3 = Ts1 + (size_t)3 * N_CLUST * 64;
  unsigned* Ts3 = Ts2;

  (void)in_sizes; (void)n_in; (void)out_size; (void)ws_size;

  hipMemsetAsync(zbase, 0, zsize, stream);

  // ---- radix node-CSR build ----
  count_kernel  <<<NEB, 1024, 0, stream>>>(ei, bhist);
  colscan       <<<NBKT1, 512, 0, stream>>>(bhist, boffs, gcnt1);
  bucket_scan   <<<1, 256, 0, stream>>>(gcnt1, gbase1);
  scatter_kernel<<<NEB, 1024, 0, stream>>>(ei, gbase1, boffs, stage1);
  bucket_sort   <<<NBKT1, 1024, 0, stream>>>(stage1, gbase1, gcnt1, esrc1, deg1);
  node_prep<<<(N_NODES + 255) / 256, 256, 0, stream>>>(cluster, deg1, cntn, deg2);
  block_sums <<<NBT, 256, 0, stream>>>(deg1, cntn, deg2, bsum);
  scan_bsums <<<1, 256, 0, stream>>>(bsum, boff, rowptr1, rowptrn, rowptr2);
  scan_final <<<NBT, 256, 0, stream>>>(deg1, cntn, deg2, boff,
                                       rowptr1, dis1, rowptrn, curn, rowptr2, dis2);
  fill_n<<<(N_NODES + 255) / 256, 256, 0, stream>>>(cluster, curn, nidx);
  psrc_build<<<N_CLUST / 4, 256, 0, stream>>>(rowptrn, nidx, rowptr1, esrc1,
                                              cluster, rowptr2, psrcC);

  // conv1
  gemm_mfma<false><<<(N_NODES + 63) / 64, 256, 0, stream>>>(x, W1, dis1, Ts1, N_NODES);
  conv_csr<<<N_NODES / 4, 256, 0, stream>>>(Ts1, dis1, rowptr1, esrc1, b1, h1);

  // pre pools (gather over contiguous sorted-batch ranges)
  graph_bounds<<<1, 128, 0, stream>>>(batch, gstart);
  pre_pool_g<<<N_GRAPH * PRE_SPLIT, 256, 0, stream>>>(h1, gstart, pre_s, pre_m);

  // cluster mean pool + batch_p + cntp + graph->cluster CSR
  cluster_gather<<<N_CLUST / 4, 256, 0, stream>>>(h1, rowptrn, nidx, batch, hp, batchp);
  cntp_kernel<<<(N_CLUST + 255) / 256, 256, 0, stream>>>(batchp, cntp);
  scan_cntp<<<1, 64, 0, stream>>>(cntp, gbasep, curp);
  fill_c<<<(N_CLUST + 255) / 256, 256, 0, stream>>>(batchp, curp, cidx);

  // conv2
  gemm_mfma<true><<<(N_CLUST + 63) / 64, 256, 0, stream>>>(hp, W2, dis2, Ts2, N_CLUST);
  conv_csr<<<N_CLUST / 4, 256, 0, stream>>>(Ts2, dis2, rowptr2, psrcC, b2, hp2);

  // conv3
  gemm_mfma<true><<<(N_CLUST + 63) / 64, 256, 0, stream>>>(hp2, W3, dis2, Ts3, N_CLUST);
  conv_csr<<<N_CLUST / 4, 256, 0, stream>>>(Ts3, dis2, rowptr2, psrcC, b3, hp3);

  // post pools (gather via graph->cluster CSR) + head
  post_pool_g<<<N_GRAPH * POST_SPLIT, 256, 0, stream>>>(hp3, gbasep, cidx, post_s, post_m);
  head_kernel<<<N_GRAPH, 128, 0, stream>>>(pre_s, pre_m, post_s, post_m, gstart, cntp,
                                           l1w, l1b, l2w, l2b, out);
}

// Round 12
// 527.579 us; speedup vs baseline: 3.1416x; 1.0166x over previous
//
#include <hip/hip_runtime.h>

constexpr int N_NODES = 100000;
constexpr int N_EDGES = 1600000;
constexpr int N_CLUST = 25000;
constexpr int N_GRAPH = 64;
constexpr int NCLSN   = 10;

// bucket decomposition for the radix node-CSR build
constexpr int BKT1_SHIFT = 9;                       // node-dst buckets of 512 ids
constexpr int NBKT1 = (N_NODES + 511) / 512;        // 196
constexpr int EPB = 4096;                           // edges per block (count/scatter)
constexpr int NEB = (N_EDGES + EPB - 1) / EPB;      // 391
constexpr int SORT_CAP = 12288;                     // LDS staging cap (mean 8163, sd ~90)

// scan partitioning: 1024 elements per block, three concatenated segments
constexpr int SCAN_BPB = 1024;
constexpr int NB1 = (N_NODES + SCAN_BPB - 1) / SCAN_BPB;  // 98
constexpr int NB2 = (N_CLUST + SCAN_BPB - 1) / SCAN_BPB;  // 25
constexpr int NB3 = (N_CLUST + SCAN_BPB - 1) / SCAN_BPB;  // 25
constexpr int NBT = NB1 + NB2 + NB3;                      // 148

// ---- bf16 pack/unpack helpers (features stored as packed pairs in uint) ----
__device__ __forceinline__ float bf16lo(unsigned u){ return __uint_as_float(u << 16); }
__device__ __forceinline__ float bf16hi(unsigned u){ return __uint_as_float(u & 0xffff0000u); }
__device__ __forceinline__ unsigned bf16_rne(float f){
  unsigned u = __float_as_uint(f);
  return (u + 0x7fffu + ((u >> 16) & 1u)) >> 16;
}
__device__ __forceinline__ unsigned pack2(float lo, float hi){
  return bf16_rne(lo) | (bf16_rne(hi) << 16);
}

typedef short bf16x8 __attribute__((ext_vector_type(8)));
typedef float f32x4  __attribute__((ext_vector_type(4)));

// ---------------------------------------------------------------------------
// radix node-CSR build, phase 1: per-block bucket histograms (no global atomics)
// ---------------------------------------------------------------------------
__launch_bounds__(1024)
__global__ void count_kernel(const int* __restrict__ ei, int* __restrict__ bhist){
  __shared__ int h1c[NBKT1];
  int t = threadIdx.x;
  for (int i = t; i < NBKT1; i += 1024) h1c[i] = 0;
  __syncthreads();
  int e0 = blockIdx.x * EPB;
  #pragma unroll
  for (int i = 0; i < EPB / 1024; ++i){
    int e = e0 + i * 1024 + t;
    if (e < N_EDGES) atomicAdd(&h1c[ei[N_EDGES + e] >> BKT1_SHIFT], 1);
  }
  __syncthreads();
  for (int i = t; i < NBKT1; i += 1024) bhist[blockIdx.x * NBKT1 + i] = h1c[i];
}

// phase 2a: column scan of the histogram matrix -> per-(block,bucket) offsets
__launch_bounds__(512)
__global__ void colscan(const int* __restrict__ bhist, int* __restrict__ boffs,
                        int* __restrict__ gcnt1){
  __shared__ int s[512];
  int i = blockIdx.x;                 // bucket
  int t = threadIdx.x;                // edge-block index
  int v = (t < NEB) ? bhist[t * NBKT1 + i] : 0;
  s[t] = v; __syncthreads();
  for (int o = 1; o < 512; o <<= 1){
    int a = (t >= o) ? s[t - o] : 0;
    __syncthreads(); s[t] += a; __syncthreads();
  }
  if (t < NEB) boffs[t * NBKT1 + i] = s[t] - v;   // exclusive within column
  if (t == 511) gcnt1[i] = s[511];
}

// phase 2b: bucket bases (prefix over 196 totals)
__launch_bounds__(256)
__global__ void bucket_scan(const int* __restrict__ gcnt1, int* __restrict__ gbase1){
  __shared__ int s[256];
  int t = threadIdx.x;
  int v = (t < NBKT1) ? gcnt1[t] : 0;
  s[t] = v; __syncthreads();
  for (int off = 1; off < 256; off <<= 1){
    int a = (t >= off) ? s[t - off] : 0;
    __syncthreads(); s[t] += a; __syncthreads();
  }
  if (t < NBKT1) gbase1[t] = s[t] - v;
}

// phase 3: single-pass scatter into pre-reserved runs (no global atomics)
__launch_bounds__(1024)
__global__ void scatter_kernel(const int* __restrict__ ei, const int* __restrict__ gbase1,
                               const int* __restrict__ boffs, unsigned int* __restrict__ stage1){
  __shared__ int gb1[NBKT1];
  __shared__ int cur[NBKT1];
  int t = threadIdx.x, b = blockIdx.x;
  for (int i = t; i < NBKT1; i += 1024){
    gb1[i] = gbase1[i] + boffs[b * NBKT1 + i];
    cur[i] = 0;
  }
  __syncthreads();
  int e0 = b * EPB;
  #pragma unroll
  for (int i = 0; i < EPB / 1024; ++i){
    int e = e0 + i * 1024 + t;
    if (e < N_EDGES){
      int src = ei[e], dst = ei[N_EDGES + e];
      int bk = dst >> BKT1_SHIFT;
      int r = atomicAdd(&cur[bk], 1);
      stage1[gb1[bk] + r] = ((unsigned)(dst & 511) << 17) | (unsigned)src;
    }
  }
}

// phase 4: per-bucket LDS counting sort + coalesced degree writes (1024 thr)
__launch_bounds__(1024)
__global__ void bucket_sort(const unsigned int* __restrict__ stage, const int* __restrict__ gbase,
                            const int* __restrict__ gcnt, int* __restrict__ outpay,
                            int* __restrict__ deg){
  __shared__ int cnt[512], off[512];
  __shared__ int sorted[SORT_CAP];
  int b = blockIdx.x, t = threadIdx.x;
  int base = gbase[b], n = gcnt[b];
  if (t < 512) cnt[t] = 0;
  __syncthreads();
  for (int i = t; i < n; i += 1024) atomicAdd(&cnt[stage[base + i] >> 17], 1);
  __syncthreads();
  if (t < 512){
    int idx = b * 512 + t;
    if (idx < N_NODES) deg[idx] = cnt[t];
    off[t] = cnt[t];
  }
  __syncthreads();
  for (int s = 1; s < 512; s <<= 1){
    int v = 0;
    if (t < 512 && t >= s) v = off[t - s];
    __syncthreads();
    if (t < 512) off[t] += v;
    __syncthreads();
  }
  if (t < 512) off[t] -= cnt[t];       // exclusive cursors
  __syncthreads();
  if (n <= SORT_CAP){
    for (int i = t; i < n; i += 1024){
      unsigned w = stage[base + i];
      int r = atomicAdd(&off[w >> 17], 1);
      sorted[r] = (int)(w & 0x1FFFFu);
    }
    __syncthreads();
    for (int i = t; i < n; i += 1024) outpay[base + i] = sorted[i];
  } else {  // never expected; correct fallback
    for (int i = t; i < n; i += 1024){
      unsigned w = stage[base + i];
      int r = atomicAdd(&off[w >> 17], 1);
      outpay[base + r] = (int)(w & 0x1FFFFu);
    }
  }
}

// per-node: cluster membership count + cluster in-degree (sum of member deg1)
__global__ void node_prep(const int* __restrict__ cluster, const int* __restrict__ deg1,
                          int* __restrict__ cntn, int* __restrict__ deg2){
  int v = blockIdx.x * blockDim.x + threadIdx.x;
  if (v < N_NODES){
    int c = cluster[v];
    atomicAdd(&cntn[c], 1);
    atomicAdd(&deg2[c], deg1[v]);
  }
}

// ---------------------------------------------------------------------------
// device-wide 3-segment exclusive scan
// ---------------------------------------------------------------------------
__device__ __forceinline__ void seg_select(int b, const int* deg1, const int* cntn,
                                           const int* deg2, const int*& src, int& n, int& base){
  if (b < NB1){ src = deg1; n = N_NODES; base = b * SCAN_BPB; }
  else if (b < NB1 + NB2){ src = cntn; n = N_CLUST; base = (b - NB1) * SCAN_BPB; }
  else { src = deg2; n = N_CLUST; base = (b - NB1 - NB2) * SCAN_BPB; }
}

__launch_bounds__(256)
__global__ void block_sums(const int* __restrict__ deg1, const int* __restrict__ cntn,
                           const int* __restrict__ deg2, int* __restrict__ bsum){
  int b = blockIdx.x;
  const int* src; int n, base;
  seg_select(b, deg1, cntn, deg2, src, n, base);
  int t = threadIdx.x;
  int i0 = base + t * 4;
  int s = 0;
  if (i0 + 3 < n){ int4 v = *(const int4*)&src[i0]; s = v.x + v.y + v.z + v.w; }
  else { for (int j = 0; j < 4; ++j){ int i = i0 + j; if (i < n) s += src[i]; } }
  __shared__ int sh[256];
  sh[t] = s; __syncthreads();
  for (int off = 128; off > 0; off >>= 1){
    if (t < off) sh[t] += sh[t + off];
    __syncthreads();
  }
  if (t == 0) bsum[b] = sh[0];
}

__launch_bounds__(256)
__global__ void scan_bsums(const int* __restrict__ bsum, int* __restrict__ boff,
                           int* __restrict__ rowptr1, int* __restrict__ rowptrn,
                           int* __restrict__ rowptr2){
  __shared__ int s[256];
  int t = threadIdx.x;
  int v = (t < NBT) ? bsum[t] : 0;
  s[t] = v; __syncthreads();
  int seg = (t < NB1) ? 0 : (t < NB1 + NB2 ? 1 : 2);
  for (int off = 1; off < 256; off <<= 1){
    int add = 0;
    if (t >= off){
      int u = t - off;
      int useg = (u < NB1) ? 0 : (u < NB1 + NB2 ? 1 : 2);
      if (useg == seg) add = s[u];
    }
    __syncthreads();
    s[t] += add;
    __syncthreads();
  }
  if (t < NBT) boff[t] = s[t] - v;
  if (t == NB1 - 1)       rowptr1[N_NODES] = s[t];
  if (t == NB1 + NB2 - 1) rowptrn[N_CLUST] = s[t];
  if (t == NBT - 1)       rowptr2[N_CLUST] = s[t];
}

__launch_bounds__(256)
__global__ void scan_final(const int* __restrict__ deg1, const int* __restrict__ cntn,
                           const int* __restrict__ deg2, const int* __restrict__ boff,
                           int* __restrict__ rowptr1, float* __restrict__ dis1,
                           int* __restrict__ rowptrn, int* __restrict__ curn,
                           int* __restrict__ rowptr2, float* __restrict__ dis2){
  int b = blockIdx.x;
  const int* src; int n, base;
  seg_select(b, deg1, cntn, deg2, src, n, base);
  int* rp; int* cur; float* dis;
  if (b < NB1){ rp = rowptr1; cur = nullptr; dis = dis1; }
  else if (b < NB1 + NB2){ rp = rowptrn; cur = curn; dis = nullptr; }
  else { rp = rowptr2; cur = nullptr; dis = dis2; }
  int t = threadIdx.x;
  int i0 = base + t * 4;
  int v[4]; int s = 0;
  #pragma unroll
  for (int j = 0; j < 4; ++j){ int i = i0 + j; v[j] = (i < n) ? src[i] : 0; s += v[j]; }
  __shared__ int sh[256];
  sh[t] = s; __syncthreads();
  for (int off = 1; off < 256; off <<= 1){
    int add = (t >= off) ? sh[t - off] : 0;
    __syncthreads();
    sh[t] += add;
    __syncthreads();
  }
  int run = sh[t] - s + boff[b];
  #pragma unroll
  for (int j = 0; j < 4; ++j){
    int i = i0 + j;
    if (i < n){
      rp[i] = run;
      if (cur) cur[i] = run;
      if (dis) dis[i] = rsqrtf((float)v[j] + 1.0f);
      run += v[j];
    }
  }
}

// node->cluster CSR fill
__global__ void fill_n(const int* __restrict__ cluster, int* __restrict__ curn,
                       int* __restrict__ nidx){
  int v = blockIdx.x * blockDim.x + threadIdx.x;
  if (v >= N_NODES) return;
  nidx[atomicAdd(&curn[cluster[v]], 1)] = v;
}

// ---------------------------------------------------------------------------
// psrcC build: cluster c's pooled-edge list = concat of members' edge runs
// ---------------------------------------------------------------------------
__launch_bounds__(256)
__global__ void psrc_build(const int* __restrict__ rowptrn, const int* __restrict__ nidx,
                           const int* __restrict__ rowptr1, const int* __restrict__ esrc1,
                           const int* __restrict__ cluster, const int* __restrict__ rowptr2,
                           int* __restrict__ psrcC){
  int c = blockIdx.x * 4 + (threadIdx.x >> 6);
  int l = threadIdx.x & 63;
  int mb = rowptrn[c], me = rowptrn[c + 1];
  int cnt = me - mb;                       // members per cluster (<= 64)
  int base_l = 0, d_l = 0;
  if (l < cnt){
    int v = nidx[mb + l];
    base_l = rowptr1[v];
    d_l = rowptr1[v + 1] - base_l;
  }
  int pref = d_l;                          // inclusive scan over 64 lanes
  #pragma unroll
  for (int off = 1; off < 64; off <<= 1){
    int u = __shfl_up(pref, off);
    if (l >= off) pref += u;
  }
  int total = __shfl(pref, 63);
  int wbase = rowptr2[c];
  int iters = (total + 63) >> 6;           // uniform loop; all lanes active
  for (int k = 0; k < iters; ++k){
    int idx = k * 64 + l;
    int idxc = min(idx, total - 1);
    int m = 0;
    for (int j = 0; j < cnt; ++j){
      int pj = __shfl(pref, j);
      if (idxc >= pj) m = j + 1;
    }
    int pm = __shfl(pref, m);
    int dm = __shfl(d_l, m);
    int bm = __shfl(base_l, m);
    int e = bm + idxc - (pm - dm);
    int sc = cluster[esrc1[e]];
    if (idx < total) psrcC[wbase + idx] = sc;
  }
}

// ---------------------------------------------------------------------------
// MFMA GEMM: C[M,128] = (A[M,128] @ B[128,128]) * scale[row], bf16 packed out
// ---------------------------------------------------------------------------
template<bool A_BF16>
__launch_bounds__(256)
__global__ void gemm_mfma(const void* __restrict__ Aptr, const float* __restrict__ B,
                          const float* __restrict__ scale, unsigned* __restrict__ Cmat,
                          int M){
  __shared__ __align__(16) unsigned Blds[128 * 68];
  __shared__ __align__(16) unsigned Alds[64 * 68];
  const int t = threadIdx.x;
  const int row0 = blockIdx.x * 64;

  #pragma unroll
  for (int i = 0; i < 8; ++i){
    int task = t + i * 256;
    int kp = task >> 5, nq = task & 31;
    float4 b0 = *(const float4*)&B[(2 * kp) * 128 + nq * 4];
    float4 b1 = *(const float4*)&B[(2 * kp + 1) * 128 + nq * 4];
    Blds[(nq * 4 + 0) * 68 + kp] = pack2(b0.x, b1.x);
    Blds[(nq * 4 + 1) * 68 + kp] = pack2(b0.y, b1.y);
    Blds[(nq * 4 + 2) * 68 + kp] = pack2(b0.z, b1.z);
    Blds[(nq * 4 + 3) * 68 + kp] = pack2(b0.w, b1.w);
  }
  if (A_BF16){
    const unsigned* A = (const unsigned*)Aptr;
    #pragma unroll
    for (int i = 0; i < 8; ++i){
      int idx = t + i * 256;
      int row = idx >> 5, c2 = idx & 31;
      int grow = min(row0 + row, M - 1);
      uint2 v = *(const uint2*)&A[(size_t)grow * 64 + c2 * 2];
      Alds[row * 68 + c2 * 2]     = v.x;
      Alds[row * 68 + c2 * 2 + 1] = v.y;
    }
  } else {
    const float* A = (const float*)Aptr;
    #pragma unroll
    for (int i = 0; i < 8; ++i){
      int idx = t + i * 256;
      int row = idx >> 5, k4 = idx & 31;
      int grow = min(row0 + row, M - 1);
      float4 v = *(const float4*)&A[(size_t)grow * 128 + k4 * 4];
      Alds[row * 68 + k4 * 2]     = pack2(v.x, v.y);
      Alds[row * 68 + k4 * 2 + 1] = pack2(v.z, v.w);
    }
  }
  __syncthreads();

  const int wv = t >> 6, l = t & 63, quad = l >> 4, n16 = l & 15;
  f32x4 acc[8];
  #pragma unroll
  for (int nt = 0; nt < 8; ++nt) acc[nt] = (f32x4){0.f, 0.f, 0.f, 0.f};
  const int arow = wv * 16 + n16;
  #pragma unroll
  for (int ks = 0; ks < 4; ++ks){
    bf16x8 af = *(const bf16x8*)&Alds[arow * 68 + ks * 16 + quad * 4];
    #pragma unroll
    for (int nt = 0; nt < 8; ++nt){
      bf16x8 bfr = *(const bf16x8*)&Blds[(nt * 16 + n16) * 68 + ks * 16 + quad * 4];
      acc[nt] = __builtin_amdgcn_mfma_f32_16x16x32_bf16(af, bfr, acc[nt], 0, 0, 0);
    }
  }
  #pragma unroll
  for (int nt = 0; nt < 8; ++nt){
    #pragma unroll
    for (int r = 0; r < 4; ++r){
      int row = row0 + wv * 16 + quad * 4 + r;
      float sc = scale[min(row, M - 1)];
      float v = acc[nt][r] * sc;
      float vhi = __shfl_xor(v, 1);
      if (((l & 1) == 0) && row < M)
        Cmat[(size_t)row * 64 + nt * 8 + (n16 >> 1)] = pack2(v, vhi);
    }
  }
}

// ---------------------------------------------------------------------------
// CSR conv, quarter-wave uint4 gather: lane l handles uint4 q=l&15 of edge
// j+(l>>4). One dwordx4 load serves 4 edges (1 KB/wave-instruction).
// out[i] = relu( dis[i]*(sum_e Ts[src_e] + Ts[i]) + b )
// ---------------------------------------------------------------------------
__launch_bounds__(256)
__global__ void conv_csr(const unsigned* __restrict__ Ts, const float* __restrict__ dis,
                         const int* __restrict__ rowptr, const int* __restrict__ esrc,
                         const float* __restrict__ bias, unsigned* __restrict__ Hout){
  int w = blockIdx.x * 4 + (threadIdx.x >> 6);
  int l = threadIdx.x & 63;
  int q = l & 15, h = l >> 4;
  int beg = rowptr[w], end = rowptr[w + 1];
  float acc[8] = {0.f,0.f,0.f,0.f,0.f,0.f,0.f,0.f};
  for (int base = beg; base < end; base += 64){
    int n = min(64, end - base);
    int eid = esrc[base + min(l, n - 1)];
    int j = 0;
    for (; j + 8 <= n; j += 8){
      int s0 = __shfl(eid, j + h);
      int s1 = __shfl(eid, j + 4 + h);
      uint4 u0 = *(const uint4*)&Ts[(size_t)s0 * 64 + q * 4];
      uint4 u1 = *(const uint4*)&Ts[(size_t)s1 * 64 + q * 4];
      acc[0] += bf16lo(u0.x); acc[1] += bf16hi(u0.x);
      acc[2] += bf16lo(u0.y); acc[3] += bf16hi(u0.y);
      acc[4] += bf16lo(u0.z); acc[5] += bf16hi(u0.z);
      acc[6] += bf16lo(u0.w); acc[7] += bf16hi(u0.w);
      acc[0] += bf16lo(u1.x); acc[1] += bf16hi(u1.x);
      acc[2] += bf16lo(u1.y); acc[3] += bf16hi(u1.y);
      acc[4] += bf16lo(u1.z); acc[5] += bf16hi(u1.z);
      acc[6] += bf16lo(u1.w); acc[7] += bf16hi(u1.w);
    }
    for (; j < n; j += 4){
      int ei = j + h;
      int s = __shfl(eid, min(ei, n - 1));
      uint4 u = *(const uint4*)&Ts[(size_t)s * 64 + q * 4];
      if (ei < n){
        acc[0] += bf16lo(u.x); acc[1] += bf16hi(u.x);
        acc[2] += bf16lo(u.y); acc[3] += bf16hi(u.y);
        acc[4] += bf16lo(u.z); acc[5] += bf16hi(u.z);
        acc[6] += bf16lo(u.w); acc[7] += bf16hi(u.w);
      }
    }
  }
  // cross-quarter reduction: quarters hold disjoint edge subsets, same features
  #pragma unroll
  for (int k = 0; k < 8; ++k){
    acc[k] += __shfl_xor(acc[k], 16);
    acc[k] += __shfl_xor(acc[k], 32);
  }
  float d = dis[w];
  uint4 us = *(const uint4*)&Ts[(size_t)w * 64 + q * 4];
  float4 b0 = *(const float4*)&bias[q * 8];
  float4 b1 = *(const float4*)&bias[q * 8 + 4];
  float r0 = fmaxf(fmaf(d, acc[0] + bf16lo(us.x), b0.x), 0.f);
  float r1 = fmaxf(fmaf(d, acc[1] + bf16hi(us.x), b0.y), 0.f);
  float r2 = fmaxf(fmaf(d, acc[2] + bf16lo(us.y), b0.z), 0.f);
  float r3 = fmaxf(fmaf(d, acc[3] + bf16hi(us.y), b0.w), 0.f);
  float r4 = fmaxf(fmaf(d, acc[4] + bf16lo(us.z), b1.x), 0.f);
  float r5 = fmaxf(fmaf(d, acc[5] + bf16hi(us.z), b1.y), 0.f);
  float r6 = fmaxf(fmaf(d, acc[6] + bf16lo(us.w), b1.z), 0.f);
  float r7 = fmaxf(fmaf(d, acc[7] + bf16hi(us.w), b1.w), 0.f);
  if (h == 0){
    uint4 o;
    o.x = pack2(r0, r1); o.y = pack2(r2, r3);
    o.z = pack2(r4, r5); o.w = pack2(r6, r7);
    *(uint4*)&Hout[(size_t)w * 64 + q * 4] = o;
  }
}

// cluster mean pool + batch_p, quarter-wave uint4 gather
__launch_bounds__(256)
__global__ void cluster_gather(const unsigned* __restrict__ h1, const int* __restrict__ rowptrn,
                               const int* __restrict__ nidx, const int* __restrict__ batch,
                               unsigned* __restrict__ hp, int* __restrict__ batchp){
  int c = blockIdx.x * 4 + (threadIdx.x >> 6);
  int l = threadIdx.x & 63;
  int q = l & 15, h = l >> 4;
  int mb = rowptrn[c], me = rowptrn[c + 1];
  float acc[8] = {0.f,0.f,0.f,0.f,0.f,0.f,0.f,0.f};
  int vmax = -1;
  for (int base = mb; base < me; base += 64){
    int n = min(64, me - base);
    int vid = nidx[base + min(l, n - 1)];
    if (l < n) vmax = max(vmax, vid);
    int j = 0;
    for (; j + 8 <= n; j += 8){
      int s0 = __shfl(vid, j + h);
      int s1 = __shfl(vid, j + 4 + h);
      uint4 u0 = *(const uint4*)&h1[(size_t)s0 * 64 + q * 4];
      uint4 u1 = *(const uint4*)&h1[(size_t)s1 * 64 + q * 4];
      acc[0] += bf16lo(u0.x); acc[1] += bf16hi(u0.x);
      acc[2] += bf16lo(u0.y); acc[3] += bf16hi(u0.y);
      acc[4] += bf16lo(u0.z); acc[5] += bf16hi(u0.z);
      acc[6] += bf16lo(u0.w); acc[7] += bf16hi(u0.w);
      acc[0] += bf16lo(u1.x); acc[1] += bf16hi(u1.x);
      acc[2] += bf16lo(u1.y); acc[3] += bf16hi(u1.y);
      acc[4] += bf16lo(u1.z); acc[5] += bf16hi(u1.z);
      acc[6] += bf16lo(u1.w); acc[7] += bf16hi(u1.w);
    }
    for (; j < n; j += 4){
      int ei = j + h;
      int s = __shfl(vid, min(ei, n - 1));
      uint4 u = *(const uint4*)&h1[(size_t)s * 64 + q * 4];
      if (ei < n){
        acc[0] += bf16lo(u.x); acc[1] += bf16hi(u.x);
        acc[2] += bf16lo(u.y); acc[3] += bf16hi(u.y);
        acc[4] += bf16lo(u.z); acc[5] += bf16hi(u.z);
        acc[6] += bf16lo(u.w); acc[7] += bf16hi(u.w);
      }
    }
  }
  #pragma unroll
  for (int k = 0; k < 8; ++k){
    acc[k] += __shfl_xor(acc[k], 16);
    acc[k] += __shfl_xor(acc[k], 32);
  }
  #pragma unroll
  for (int off = 32; off > 0; off >>= 1) vmax = max(vmax, __shfl_xor(vmax, off));
  float inv = 1.0f / (float)max(me - mb, 1);
  if (h == 0){
    uint4 o;
    o.x = pack2(acc[0] * inv, acc[1] * inv);
    o.y = pack2(acc[2] * inv, acc[3] * inv);
    o.z = pack2(acc[4] * inv, acc[5] * inv);
    o.w = pack2(acc[6] * inv, acc[7] * inv);
    *(uint4*)&hp[(size_t)c * 64 + q * 4] = o;
  }
  if (l == 0) batchp[c] = (vmax >= 0) ? batch[vmax] : 0;  // batch sorted by node id
}

__global__ void cntp_kernel(const int* __restrict__ batchp, int* __restrict__ cntp){
  int c = blockIdx.x * blockDim.x + threadIdx.x;
  if (c < N_CLUST) atomicAdd(&cntp[batchp[c]], 1);
}

// graph -> cluster CSR: scan cntp (64 entries) + cursor fill
__global__ void scan_cntp(const int* __restrict__ cntp, int* __restrict__ gbasep,
                          int* __restrict__ curp){
  int t = threadIdx.x;                 // 64 threads
  int v = cntp[t];
  int s = v;
  for (int off = 1; off < 64; off <<= 1){
    int u = __shfl_up(s, off);
    if (t >= off) s += u;
  }
  gbasep[t] = s - v; curp[t] = s - v;
  if (t == 63) gbasep[64] = s;
}

__global__ void fill_c(const int* __restrict__ batchp, int* __restrict__ curp,
                       int* __restrict__ cidx){
  int c = blockIdx.x * blockDim.x + threadIdx.x;
  if (c < N_CLUST) cidx[atomicAdd(&curp[batchp[c]], 1)] = c;
}

// ---------------------------------------------------------------------------
__global__ void graph_bounds(const int* __restrict__ batch, int* __restrict__ gstart){
  int g = threadIdx.x;
  if (g > N_GRAPH) return;
  int lo = 0, hi = N_NODES;
  while (lo < hi){ int mid = (lo + hi) >> 1; if (batch[mid] < g) lo = mid + 1; else hi = mid; }
  gstart[g] = lo;
}

__device__ __forceinline__ void atomicMaxPosF(float* addr, float v){
  atomicMax((int*)addr, __float_as_int(v));
}

// pre-pool gather: graph g's rows are contiguous [gstart[g], gstart[g+1])
constexpr int PRE_SPLIT = 8;
__launch_bounds__(256)
__global__ void pre_pool_g(const unsigned* __restrict__ h1, const int* __restrict__ gstart,
                           float* __restrict__ psum, float* __restrict__ pmax){
  int g = blockIdx.x / PRE_SPLIT, sp = blockIdx.x % PRE_SPLIT;
  int t = threadIdx.x, w = t >> 6, l = t & 63;
  int s0 = gstart[g], s1 = gstart[g + 1];
  int n = s1 - s0;
  int per = (n + PRE_SPLIT - 1) / PRE_SPLIT;
  int b0 = s0 + sp * per, b1 = min(b0 + per, s1);
  float2 a0{0.f,0.f}, a1{0.f,0.f}, a2{0.f,0.f}, a3{0.f,0.f};
  float2 mx{0.f,0.f};
  int i = b0 + w;
  for (; i + 12 < b1; i += 16){
    unsigned u0 = h1[(size_t)(i     ) * 64 + l];
    unsigned u1 = h1[(size_t)(i +  4) * 64 + l];
    unsigned u2 = h1[(size_t)(i +  8) * 64 + l];
    unsigned u3 = h1[(size_t)(i + 12) * 64 + l];
    float f0x = bf16lo(u0), f0y = bf16hi(u0);
    float f1x = bf16lo(u1), f1y = bf16hi(u1);
    float f2x = bf16lo(u2), f2y = bf16hi(u2);
    float f3x = bf16lo(u3), f3y = bf16hi(u3);
    a0.x += f0x; a0.y += f0y; a1.x += f1x; a1.y += f1y;
    a2.x += f2x; a2.y += f2y; a3.x += f3x; a3.y += f3y;
    mx.x = fmaxf(fmaxf(mx.x, fmaxf(f0x, f1x)), fmaxf(f2x, f3x));
    mx.y = fmaxf(fmaxf(mx.y, fmaxf(f0y, f1y)), fmaxf(f2y, f3y));
  }
  for (; i < b1; i += 4){
    unsigned u = h1[(size_t)i * 64 + l];
    float fx = bf16lo(u), fy = bf16hi(u);
    a0.x += fx; a0.y += fy;
    mx.x = fmaxf(mx.x, fx); mx.y = fmaxf(mx.y, fy);
  }
  __shared__ float2 ssum[4][64], smax[4][64];
  ssum[w][l] = { a0.x + a1.x + a2.x + a3.x, a0.y + a1.y + a2.y + a3.y };
  smax[w][l] = mx;
  __syncthreads();
  if (w == 0){
    float2 S = ssum[0][l], M = smax[0][l];
    #pragma unroll
    for (int k = 1; k < 4; ++k){
      S.x += ssum[k][l].x; S.y += ssum[k][l].y;
      M.x = fmaxf(M.x, smax[k][l].x); M.y = fmaxf(M.y, smax[k][l].y);
    }
    atomicAdd(&psum[g * 128 + 2 * l], S.x);
    atomicAdd(&psum[g * 128 + 2 * l + 1], S.y);
    atomicMaxPosF(&pmax[g * 128 + 2 * l], M.x);
    atomicMaxPosF(&pmax[g * 128 + 2 * l + 1], M.y);
  }
}

// post-pool gather via graph->cluster CSR
constexpr int POST_SPLIT = 4;
__launch_bounds__(256)
__global__ void post_pool_g(const unsigned* __restrict__ hp3, const int* __restrict__ gbasep,
                            const int* __restrict__ cidx,
                            float* __restrict__ psum, float* __restrict__ pmax){
  int g = blockIdx.x / POST_SPLIT, sp = blockIdx.x % POST_SPLIT;
  int t = threadIdx.x, w = t >> 6, l = t & 63;
  int s0 = gbasep[g], s1 = gbasep[g + 1];
  int n = s1 - s0;
  int per = (n + POST_SPLIT * 4 - 1) / (POST_SPLIT * 4);
  int b0 = s0 + (sp * 4 + w) * per, b1 = min(b0 + per, s1);
  float2 a0{0.f,0.f}, a1{0.f,0.f}, a2{0.f,0.f}, a3{0.f,0.f};
  float2 mx{0.f,0.f};
  for (int base = b0; base < b1; base += 64){
    int nn = min(64, b1 - base);
    int cid = cidx[base + min(l, nn - 1)];
    int j = 0;
    for (; j + 4 <= nn; j += 4){
      int c0 = __shfl(cid, j);
      int c1 = __shfl(cid, j + 1);
      int c2 = __shfl(cid, j + 2);
      int c3 = __shfl(cid, j + 3);
      unsigned u0 = hp3[(size_t)c0 * 64 + l];
      unsigned u1 = hp3[(size_t)c1 * 64 + l];
      unsigned u2 = hp3[(size_t)c2 * 64 + l];
      unsigned u3 = hp3[(size_t)c3 * 64 + l];
      float f0x = bf16lo(u0), f0y = bf16hi(u0);
      float f1x = bf16lo(u1), f1y = bf16hi(u1);
      float f2x = bf16lo(u2), f2y = bf16hi(u2);
      float f3x = bf16lo(u3), f3y = bf16hi(u3);
      a0.x += f0x; a0.y += f0y; a1.x += f1x; a1.y += f1y;
      a2.x += f2x; a2.y += f2y; a3.x += f3x; a3.y += f3y;
      mx.x = fmaxf(fmaxf(mx.x, fmaxf(f0x, f1x)), fmaxf(f2x, f3x));
      mx.y = fmaxf(fmaxf(mx.y, fmaxf(f0y, f1y)), fmaxf(f2y, f3y));
    }
    for (; j < nn; ++j){
      int c = __shfl(cid, j);
      unsigned u = hp3[(size_t)c * 64 + l];
      float fx = bf16lo(u), fy = bf16hi(u);
      a0.x += fx; a0.y += fy;
      mx.x = fmaxf(mx.x, fx); mx.y = fmaxf(mx.y, fy);
    }
  }
  __shared__ float2 ssum[4][64], smax[4][64];
  ssum[w][l] = { a0.x + a1.x + a2.x + a3.x, a0.y + a1.y + a2.y + a3.y };
  smax[w][l] = mx;
  __syncthreads();
  if (w == 0){
    float2 S = ssum[0][l], M = smax[0][l];
    #pragma unroll
    for (int k = 1; k < 4; ++k){
      S.x += ssum[k][l].x; S.y += ssum[k][l].y;
      M.x = fmaxf(M.x, smax[k][l].x); M.y = fmaxf(M.y, smax[k][l].y);
    }
    atomicAdd(&psum[g * 128 + 2 * l], S.x);
    atomicAdd(&psum[g * 128 + 2 * l + 1], S.y);
    atomicMaxPosF(&pmax[g * 128 + 2 * l], M.x);
    atomicMaxPosF(&pmax[g * 128 + 2 * l + 1], M.y);
  }
}

__launch_bounds__(128)
__global__ void head_kernel(const float* __restrict__ psum, const float* __restrict__ pmax,
                            const float* __restrict__ postsum, const float* __restrict__ postmax,
                            const int* __restrict__ gstart, const int* __restrict__ cntp,
                            const float* __restrict__ l1w, const float* __restrict__ l1b,
                            const float* __restrict__ l2w, const float* __restrict__ l2b,
                            float* __restrict__ out){
  int g = blockIdx.x, t = threadIdx.x;
  __shared__ float z[512];
  __shared__ float a[128];
  __shared__ float logits[16];
  __shared__ float lse_s;
  float cpre  = (float)max(gstart[g + 1] - gstart[g], 1);
  float cpost = fmaxf((float)cntp[g], 1.0f);
  z[t]       = psum[g * 128 + t] / cpre;
  z[128 + t] = pmax[g * 128 + t];
  z[256 + t] = postsum[g * 128 + t] / cpost;
  z[384 + t] = postmax[g * 128 + t];
  __syncthreads();
  float acc = l1b[t];
  #pragma unroll 8
  for (int k = 0; k < 512; ++k) acc = fmaf(z[k], l1w[k * 128 + t], acc);
  a[t] = fmaxf(acc, 0.f);
  __syncthreads();
  if (t < NCLSN){
    float s2 = l2b[t];
    for (int k = 0; k < 128; ++k) s2 = fmaf(a[k], l2w[k * NCLSN + t], s2);
    logits[t] = s2;
  }
  __syncthreads();
  if (t == 0){
    float m = logits[0];
    for (int c = 1; c < NCLSN; ++c) m = fmaxf(m, logits[c]);
    float s = 0.f;
    for (int c = 0; c < NCLSN; ++c) s += expf(logits[c] - m);
    lse_s = m + logf(s);
  }
  __syncthreads();
  if (t < NCLSN) out[g * NCLSN + t] = logits[t] - lse_s;
}

// ---------------------------------------------------------------------------
extern "C" void kernel_launch(void* const* d_in, const int* in_sizes, int n_in,
                              void* d_out, int out_size, void* d_ws, size_t ws_size,
                              hipStream_t stream){
  const float* x       = (const float*)d_in[0];
  const int*   ei      = (const int*)  d_in[1];
  const int*   batch   = (const int*)  d_in[2];
  const int*   cluster = (const int*)  d_in[3];
  const float* W1      = (const float*)d_in[6];
  const float* b1      = (const float*)d_in[7];
  const float* W2      = (const float*)d_in[8];
  const float* b2      = (const float*)d_in[9];
  const float* W3      = (const float*)d_in[10];
  const float* b3      = (const float*)d_in[11];
  const float* l1w     = (const float*)d_in[12];
  const float* l1b     = (const float*)d_in[13];
  const float* l2w     = (const float*)d_in[14];
  const float* l2b     = (const float*)d_in[15];
  float* out = (float*)d_out;

  char* base = (char*)d_ws;
  size_t off = 0;
  auto alloc = [&](size_t bytes) -> char* {
    char* p = base + off;
    off += (bytes + 255) & ~size_t(255);
    return p;
  };
  // ---- zero zone (one memset) ----
  char*  zbase  = base + off;
  int*   cntn   = (int*)  alloc((size_t)N_CLUST * 4);
  int*   deg2   = (int*)  alloc((size_t)N_CLUST * 4);
  int*   cntp   = (int*)  alloc((size_t)N_GRAPH * 4);
  float* pre_s  = (float*)alloc((size_t)N_GRAPH * 128 * 4);
  float* pre_m  = (float*)alloc((size_t)N_GRAPH * 128 * 4);
  float* post_s = (float*)alloc((size_t)N_GRAPH * 128 * 4);
  float* post_m = (float*)alloc((size_t)N_GRAPH * 128 * 4);
  size_t zsize = off;
  // ---- plain buffers (bf16 feature rows: 64 uints per row) ----
  unsigned* Ts1   = (unsigned*)alloc((size_t)N_NODES * 64 * 4);  // later aliased
  unsigned* h1    = (unsigned*)alloc((size_t)N_NODES * 64 * 4);  // stage buf aliases here
  int*   esrc1   = (int*)  alloc((size_t)N_EDGES * 4);
  int*   psrcC   = (int*)  alloc((size_t)N_EDGES * 4);
  int*   deg1    = (int*)  alloc((size_t)N_NODES * 4);
  int*   rowptr1 = (int*)  alloc((size_t)(N_NODES + 1) * 4);
  int*   rowptrn = (int*)  alloc((size_t)(N_CLUST + 1) * 4);
  int*   curn    = (int*)  alloc((size_t)N_CLUST * 4);
  int*   rowptr2 = (int*)  alloc((size_t)(N_CLUST + 1) * 4);
  int*   nidx    = (int*)  alloc((size_t)N_NODES * 4);
  float* dis1    = (float*)alloc((size_t)N_NODES * 4);
  float* dis2    = (float*)alloc((size_t)N_CLUST * 4);
  int*   batchp  = (int*)  alloc((size_t)N_CLUST * 4);
  int*   gstart  = (int*)  alloc((size_t)(N_GRAPH + 1) * 4);
  int*   bsum    = (int*)  alloc((size_t)NBT * 4);
  int*   boff    = (int*)  alloc((size_t)NBT * 4);
  int*   gcnt1   = (int*)  alloc((size_t)NBKT1 * 4);
  int*   gbase1  = (int*)  alloc((size_t)NBKT1 * 4);
  int*   bhist   = (int*)  alloc((size_t)NEB * NBKT1 * 4);
  int*   boffs   = (int*)  alloc((size_t)NEB * NBKT1 * 4);
  int*   gbasep  = (int*)  alloc((size_t)(N_GRAPH + 1) * 4);
  int*   curp    = (int*)  alloc((size_t)N_GRAPH * 4);
  int*   cidx    = (int*)  alloc((size_t)N_CLUST * 4);
  // stage buffer aliases the (not-yet-written) h1 region (6.4 MB <= 25.6 MB)
  unsigned int* stage1 = (unsigned int*)h1;
  // aliases into Ts1 (dead after conv1): 4 x 25000*64 uints = exactly Ts1 size
  unsigned* hp  = Ts1;
  unsigned* Ts2 = Ts1 + (size_t)N_CLUST * 64;
  unsigned* hp2 = Ts1 + (size_t)2 * N_CLUST * 64;
  unsigned* hp3 = Ts1 + (size_t)3 * N_CLUST * 64;
  unsigned* Ts3 = Ts2;

  (void)in_sizes; (void)n_in; (void)out_size; (void)ws_size;

  hipMemsetAsync(zbase, 0, zsize, stream);

  // ---- radix node-CSR build ----
  count_kernel  <<<NEB, 1024, 0, stream>>>(ei, bhist);
  colscan       <<<NBKT1, 512, 0, stream>>>(bhist, boffs, gcnt1);
  bucket_scan   <<<1, 256, 0, stream>>>(gcnt1, gbase1);
  scatter_kernel<<<NEB, 1024, 0, stream>>>(ei, gbase1, boffs, stage1);
  bucket_sort   <<<NBKT1, 1024, 0, stream>>>(stage1, gbase1, gcnt1, esrc1, deg1);
  node_prep<<<(N_NODES + 255) / 256, 256, 0, stream>>>(cluster, deg1, cntn, deg2);
  block_sums <<<NBT, 256, 0, stream>>>(deg1, cntn, deg2, bsum);
  scan_bsums <<<1, 256, 0, stream>>>(bsum, boff, rowptr1, rowptrn, rowptr2);
  scan_final <<<NBT, 256, 0, stream>>>(deg1, cntn, deg2, boff,
                                       rowptr1, dis1, rowptrn, curn, rowptr2, dis2);
  fill_n<<<(N_NODES + 255) / 256, 256, 0, stream>>>(cluster, curn, nidx);
  psrc_build<<<N_CLUST / 4, 256, 0, stream>>>(rowptrn, nidx, rowptr1, esrc1,
                                              cluster, rowptr2, psrcC);

  // conv1
  gemm_mfma<false><<<(N_NODES + 63) / 64, 256, 0, stream>>>(x, W1, dis1, Ts1, N_NODES);
  conv_csr<<<N_NODES / 4, 256, 0, stream>>>(Ts1, dis1, rowptr1, esrc1, b1, h1);

  // pre pools (gather over contiguous sorted-batch ranges)
  graph_bounds<<<1, 128, 0, stream>>>(batch, gstart);
  pre_pool_g<<<N_GRAPH * PRE_SPLIT, 256, 0, stream>>>(h1, gstart, pre_s, pre_m);

  // cluster mean pool + batch_p + cntp + graph->cluster CSR
  cluster_gather<<<N_CLUST / 4, 256, 0, stream>>>(h1, rowptrn, nidx, batch, hp, batchp);
  cntp_kernel<<<(N_CLUST + 255) / 256, 256, 0, stream>>>(batchp, cntp);
  scan_cntp<<<1, 64, 0, stream>>>(cntp, gbasep, curp);
  fill_c<<<(N_CLUST + 255) / 256, 256, 0, stream>>>(batchp, curp, cidx);

  // conv2
  gemm_mfma<true><<<(N_CLUST + 63) / 64, 256, 0, stream>>>(hp, W2, dis2, Ts2, N_CLUST);
  conv_csr<<<N_CLUST / 4, 256, 0, stream>>>(Ts2, dis2, rowptr2, psrcC, b2, hp2);

  // conv3
  gemm_mfma<true><<<(N_CLUST + 63) / 64, 256, 0, stream>>>(hp2, W3, dis2, Ts3, N_CLUST);
  conv_csr<<<N_CLUST / 4, 256, 0, stream>>>(Ts3, dis2, rowptr2, psrcC, b3, hp3);

  // post pools (gather via graph->cluster CSR) + head
  post_pool_g<<<N_GRAPH * POST_SPLIT, 256, 0, stream>>>(hp3, gbasep, cidx, post_s, post_m);
  head_kernel<<<N_GRAPH, 128, 0, stream>>>(pre_s, pre_m, post_s, post_m, gstart, cntp,
                                           l1w, l1b, l2w, l2b, out);
}